// Round 1
// baseline (582.775 us; speedup 1.0000x reference)
//
#include <hip/hip_runtime.h>
#include <math.h>

// GAE: two GCNConv layers + edge dot-product decode.
// Strategy: build CSR by target (count/scan/fill, int atomics only), then
// gather-based aggregation (wave per node, lanes = features). Features are
// pre-scaled by dinv so per-edge norm factors out; self-loop folded into
// the epilogue. All fp32.

static inline int divup(int a, int b) { return (a + b - 1) / b; }

// ---- CSR build ------------------------------------------------------------

__global__ void k_count(const int* __restrict__ tgt, int* __restrict__ cnt, int E) {
    int i = blockIdx.x * 256 + threadIdx.x;
    if (i < E) atomicAdd(&cnt[tgt[i]], 1);
}

__global__ void k_scan_a(const int* __restrict__ cnt, int* __restrict__ incl,
                         int* __restrict__ bsums, int n) {
    __shared__ int tmp[1024];
    int tid = threadIdx.x;
    int g = blockIdx.x * 1024 + tid;
    int v = (g < n) ? cnt[g] : 0;
    tmp[tid] = v;
    __syncthreads();
    for (int off = 1; off < 1024; off <<= 1) {
        int t = (tid >= off) ? tmp[tid - off] : 0;
        __syncthreads();
        tmp[tid] += t;
        __syncthreads();
    }
    if (g < n) incl[g] = tmp[tid];
    if (tid == 1023) bsums[blockIdx.x] = tmp[1023];
}

__global__ void k_scan_b(int* __restrict__ bsums, int nb) {
    __shared__ int tmp[256];
    int tid = threadIdx.x;
    int v = (tid < nb) ? bsums[tid] : 0;
    tmp[tid] = v;
    __syncthreads();
    for (int off = 1; off < 256; off <<= 1) {
        int t = (tid >= off) ? tmp[tid - off] : 0;
        __syncthreads();
        tmp[tid] += t;
        __syncthreads();
    }
    if (tid < nb) bsums[tid] = tmp[tid] - v;  // exclusive
}

__global__ void k_scan_c(int* __restrict__ incl_cursor, const int* __restrict__ cnt,
                         const int* __restrict__ bsums, int* __restrict__ rowptr, int n) {
    int tid = threadIdx.x;
    int g = blockIdx.x * 1024 + tid;
    if (g < n) {
        int inc = incl_cursor[g] + bsums[blockIdx.x];  // global inclusive
        rowptr[g + 1] = inc;
        incl_cursor[g] = inc - cnt[g];  // cursor = exclusive start
    }
    if (g == 0) rowptr[0] = 0;
}

__global__ void k_fill(const int* __restrict__ src, const int* __restrict__ tgt,
                       int* __restrict__ cursor, int* __restrict__ col, int E) {
    int i = blockIdx.x * 256 + threadIdx.x;
    if (i < E) {
        int t = tgt[i];
        int p = atomicAdd(&cursor[t], 1);
        col[p] = src[i];
    }
}

__global__ void k_dinv(const int* __restrict__ cnt, float* __restrict__ dinv, int n) {
    int i = blockIdx.x * 256 + threadIdx.x;
    if (i < n) dinv[i] = 1.0f / sqrtf((float)(cnt[i] + 1));  // +1 self-loop
}

// ---- matmul 1: hs[n][j] = (x[n] @ W1[:,j]) * dinv[n]   (K=128, M=64) -------
// block 256 = 32 nodes x 64 j. Each thread: 2 nodes x 4 consecutive j.

__global__ __launch_bounds__(256) void k_mm1(const float* __restrict__ x,
                                             const float* __restrict__ W1,
                                             const float* __restrict__ dinv,
                                             float* __restrict__ hs, int n) {
    __shared__ float Ws[128 * 64];   // [k][j]
    __shared__ float xs[32 * 132];   // [node][k], pitch 132 to break bank stride
    int tid = threadIdx.x;
    {
        const float4* W4 = (const float4*)W1;
        float4* Ws4 = (float4*)Ws;
        for (int i = tid; i < 2048; i += 256) Ws4[i] = W4[i];
    }
    int nbase = blockIdx.x * 32;
    {
        const float4* x4 = (const float4*)(x + (size_t)nbase * 128);
        for (int f = tid; f < 1024; f += 256) {
            int r = f >> 5, k4 = f & 31;
            float4 v = make_float4(0.f, 0.f, 0.f, 0.f);
            if (nbase + r < n) v = x4[f];
            *(float4*)&xs[r * 132 + k4 * 4] = v;
        }
    }
    __syncthreads();
    int jg = (tid & 15) * 4;
    int nl = (tid >> 4) * 2;
    float a00 = 0, a01 = 0, a02 = 0, a03 = 0;
    float a10 = 0, a11 = 0, a12 = 0, a13 = 0;
    const float* xr0 = &xs[nl * 132];
    const float* xr1 = &xs[(nl + 1) * 132];
#pragma unroll 8
    for (int k = 0; k < 128; k++) {
        float4 w = *(const float4*)&Ws[k * 64 + jg];
        float p0 = xr0[k], p1 = xr1[k];
        a00 += p0 * w.x; a01 += p0 * w.y; a02 += p0 * w.z; a03 += p0 * w.w;
        a10 += p1 * w.x; a11 += p1 * w.y; a12 += p1 * w.z; a13 += p1 * w.w;
    }
    int n0 = nbase + nl, n1 = n0 + 1;
    if (n0 < n) {
        float d0 = dinv[n0];
        float4 o0 = make_float4(a00 * d0, a01 * d0, a02 * d0, a03 * d0);
        *(float4*)&hs[(size_t)n0 * 64 + jg] = o0;
    }
    if (n1 < n) {
        float d1 = dinv[n1];
        float4 o1 = make_float4(a10 * d1, a11 * d1, a12 * d1, a13 * d1);
        *(float4*)&hs[(size_t)n1 * 64 + jg] = o1;
    }
}

// ---- conv1 gather: h2[t] = relu(dinv[t]*(hs[t] + sum_src hs[src]) + b1) ----
// one wave per node, lane = feature (64)

__global__ __launch_bounds__(256) void k_conv1(const float* __restrict__ hs,
                                               const int* __restrict__ rowptr,
                                               const int* __restrict__ col,
                                               const float* __restrict__ dinv,
                                               const float* __restrict__ b1,
                                               float* __restrict__ h2, int n) {
    int wid = (blockIdx.x * 256 + threadIdx.x) >> 6;
    int lane = threadIdx.x & 63;
    if (wid >= n) return;
    float acc = hs[(size_t)wid * 64 + lane];  // self-loop
    float acc2 = 0.f;
    int beg = rowptr[wid], end = rowptr[wid + 1];
    for (int e0 = beg; e0 < end; e0 += 64) {
        int m = min(64, end - e0);
        int sl = (lane < m) ? col[e0 + lane] : 0;
        int i = 0;
        for (; i + 1 < m; i += 2) {
            int s0 = __shfl(sl, i);
            int s1 = __shfl(sl, i + 1);
            acc += hs[(size_t)s0 * 64 + lane];
            acc2 += hs[(size_t)s1 * 64 + lane];
        }
        if (i < m) {
            int s0 = __shfl(sl, i);
            acc += hs[(size_t)s0 * 64 + lane];
        }
    }
    float v = dinv[wid] * (acc + acc2) + b1[lane];
    h2[(size_t)wid * 64 + lane] = fmaxf(v, 0.f);
}

// ---- matmul 2: zs[n][c] = (h2[n] @ W2[:,c]) * dinv[n]  (K=64, M=32) --------
// block 256 = 64 nodes x 32 c. Each thread: 2 nodes x 4 consecutive c.

__global__ __launch_bounds__(256) void k_mm2(const float* __restrict__ h2,
                                             const float* __restrict__ W2,
                                             const float* __restrict__ dinv,
                                             float* __restrict__ zs, int n) {
    __shared__ float Ws[64 * 32];  // [k][c]
    __shared__ float xs[64 * 68];  // [node][k], pitch 68
    int tid = threadIdx.x;
    {
        const float4* W4 = (const float4*)W2;
        float4* Ws4 = (float4*)Ws;
        for (int i = tid; i < 512; i += 256) Ws4[i] = W4[i];
    }
    int nbase = blockIdx.x * 64;
    for (int f = tid; f < 1024; f += 256) {
        int r = f >> 4, k4 = f & 15;
        int node = nbase + r;
        float4 v = make_float4(0.f, 0.f, 0.f, 0.f);
        if (node < n) v = *(const float4*)&h2[(size_t)node * 64 + k4 * 4];
        *(float4*)&xs[r * 68 + k4 * 4] = v;
    }
    __syncthreads();
    int jg = (tid & 7) * 4;
    int nl = (tid >> 3) * 2;
    float a00 = 0, a01 = 0, a02 = 0, a03 = 0;
    float a10 = 0, a11 = 0, a12 = 0, a13 = 0;
    const float* xr0 = &xs[nl * 68];
    const float* xr1 = &xs[(nl + 1) * 68];
#pragma unroll 8
    for (int k = 0; k < 64; k++) {
        float4 w = *(const float4*)&Ws[k * 32 + jg];
        float p0 = xr0[k], p1 = xr1[k];
        a00 += p0 * w.x; a01 += p0 * w.y; a02 += p0 * w.z; a03 += p0 * w.w;
        a10 += p1 * w.x; a11 += p1 * w.y; a12 += p1 * w.z; a13 += p1 * w.w;
    }
    int n0 = nbase + nl, n1 = n0 + 1;
    if (n0 < n) {
        float d0 = dinv[n0];
        float4 o0 = make_float4(a00 * d0, a01 * d0, a02 * d0, a03 * d0);
        *(float4*)&zs[(size_t)n0 * 32 + jg] = o0;
    }
    if (n1 < n) {
        float d1 = dinv[n1];
        float4 o1 = make_float4(a10 * d1, a11 * d1, a12 * d1, a13 * d1);
        *(float4*)&zs[(size_t)n1 * 32 + jg] = o1;
    }
}

// ---- conv2 gather: z[t] = dinv[t]*(zs[t] + sum_src zs[src]) + b2 -----------
// one wave per node; 32 features, two edges processed per step (halves)

__global__ __launch_bounds__(256) void k_conv2(const float* __restrict__ zs,
                                               const int* __restrict__ rowptr,
                                               const int* __restrict__ col,
                                               const float* __restrict__ dinv,
                                               const float* __restrict__ b2,
                                               float* __restrict__ zout, int n) {
    int wid = (blockIdx.x * 256 + threadIdx.x) >> 6;
    int lane = threadIdx.x & 63;
    if (wid >= n) return;
    int j = lane & 31, half = lane >> 5;
    float acc = half ? 0.f : zs[(size_t)wid * 32 + j];  // self-loop once
    int beg = rowptr[wid], end = rowptr[wid + 1];
    for (int e0 = beg; e0 < end; e0 += 64) {
        int m = min(64, end - e0);
        int sl = (lane < m) ? col[e0 + lane] : 0;
        for (int i = 0; i < m; i += 2) {
            int idx = i + half;
            int s = __shfl(sl, idx);
            bool valid = idx < m;
            float v = zs[(size_t)(valid ? s : 0) * 32 + j];
            acc += valid ? v : 0.f;
        }
    }
    acc += __shfl_xor(acc, 32);
    if (half == 0) {
        zout[(size_t)wid * 32 + j] = dinv[wid] * acc + b2[j];
    }
}

// ---- decode: recon[e] = dot(z[src[e]], z[tgt[e]]) (original edges) ---------
// half-wave (32 lanes) per edge

__global__ __launch_bounds__(256) void k_decode(const float* __restrict__ z,
                                                const int* __restrict__ src,
                                                const int* __restrict__ tgt,
                                                float* __restrict__ recon, int E) {
    int gw = (blockIdx.x * 256 + threadIdx.x) >> 5;
    int j = threadIdx.x & 31;
    if (gw >= E) return;
    int s = src[gw], t = tgt[gw];
    float v = z[(size_t)s * 32 + j] * z[(size_t)t * 32 + j];
    v += __shfl_xor(v, 16);
    v += __shfl_xor(v, 8);
    v += __shfl_xor(v, 4);
    v += __shfl_xor(v, 2);
    v += __shfl_xor(v, 1);
    if (j == 0) recon[gw] = v;
}

extern "C" void kernel_launch(void* const* d_in, const int* in_sizes, int n_in,
                              void* d_out, int out_size, void* d_ws, size_t ws_size,
                              hipStream_t stream) {
    const float* x = (const float*)d_in[0];
    const float* W1 = (const float*)d_in[1];
    const float* b1 = (const float*)d_in[2];
    const float* W2 = (const float*)d_in[3];
    const float* b2 = (const float*)d_in[4];
    const int* ei = (const int*)d_in[5];

    int N = in_sizes[0] / 128;
    int E = in_sizes[5] / 2;
    const int* src = ei;
    const int* tgt = ei + E;

    char* ws = (char*)d_ws;
    size_t off = 0;
    auto alloc = [&](size_t bytes) {
        size_t r = off;
        off += (bytes + 255) & ~(size_t)255;
        return r;
    };
    int* cnt = (int*)(ws + alloc((size_t)N * 4));
    int* rowptr = (int*)(ws + alloc((size_t)(N + 1) * 4));
    int* cursor = (int*)(ws + alloc((size_t)N * 4));
    int* bsums = (int*)(ws + alloc(1024 * 4));
    int* col = (int*)(ws + alloc((size_t)E * 4));
    float* dinv = (float*)(ws + alloc((size_t)N * 4));
    float* hs = (float*)(ws + alloc((size_t)N * 64 * 4));
    float* h2 = (float*)(ws + alloc((size_t)N * 64 * 4));
    float* zs = (float*)(ws + alloc((size_t)N * 32 * 4));

    float* zout = (float*)d_out;
    float* recon = zout + (size_t)N * 32;

    hipMemsetAsync(cnt, 0, (size_t)N * 4, stream);

    k_count<<<divup(E, 256), 256, 0, stream>>>(tgt, cnt, E);
    int nchunk = divup(N, 1024);
    k_scan_a<<<nchunk, 1024, 0, stream>>>(cnt, cursor, bsums, N);
    k_scan_b<<<1, 256, 0, stream>>>(bsums, nchunk);
    k_scan_c<<<nchunk, 1024, 0, stream>>>(cursor, cnt, bsums, rowptr, N);
    k_fill<<<divup(E, 256), 256, 0, stream>>>(src, tgt, cursor, col, E);
    k_dinv<<<divup(N, 256), 256, 0, stream>>>(cnt, dinv, N);

    k_mm1<<<divup(N, 32), 256, 0, stream>>>(x, W1, dinv, hs, N);
    k_conv1<<<divup(N, 4), 256, 0, stream>>>(hs, rowptr, col, dinv, b1, h2, N);
    k_mm2<<<divup(N, 64), 256, 0, stream>>>(h2, W2, dinv, zs, N);
    k_conv2<<<divup(N, 4), 256, 0, stream>>>(zs, rowptr, col, dinv, b2, zout, N);
    k_decode<<<divup(E, 8), 256, 0, stream>>>(zout, src, tgt, recon, E);
}

// Round 2
// 371.152 us; speedup vs baseline: 1.5702x; 1.5702x over previous
//
#include <hip/hip_runtime.h>
#include <hip/hip_fp16.h>
#include <math.h>

// GAE: 2x GCNConv + edge dot decode.
// R1 changes vs R0:
//  (a) CSR build via 196-way bucket partition (nodes>>9): LDS histograms +
//      LDS-cursor scatter into bucket-contiguous regions. Kills the 106MB
//      write-allocate storm of the old random k_fill (col lines now filled
//      while resident in one XCD's L2) and the 1.6M global-atomic k_count.
//  (b) All randomly-gathered feature tables (hs, zs, z-for-decode) in fp16:
//      halves random-row L2-miss traffic (rows 256B->128B, 128B->64B).
//      Values are small (|z|~0.05) so fp16 adds ~1e-4 absmax vs 3e-3 thr.

#define NBMAX 256   // max buckets (supports N <= 131072)
#define BSHIFT 9    // 512 nodes per bucket
#define BNODES 512
#define CH 4096     // edges per partition block

static inline int divup(int a, int b) { return (a + b - 1) / b; }

// ---- CSR build: bucket histogram --------------------------------------------

__global__ __launch_bounds__(256) void k_hist(const int* __restrict__ tgt,
                                              int* __restrict__ gcnt, int E, int NB) {
    __shared__ int h[NBMAX];
    int tid = threadIdx.x;
    for (int b = tid; b < NB; b += 256) h[b] = 0;
    __syncthreads();
    int e0 = blockIdx.x * CH;
#pragma unroll
    for (int r = 0; r < CH / 256; r++) {
        int e = e0 + r * 256 + tid;
        if (e < E) atomicAdd(&h[tgt[e] >> BSHIFT], 1);
    }
    __syncthreads();
    for (int b = tid; b < NB; b += 256) {
        int v = h[b];
        if (v) atomicAdd(&gcnt[b], v);
    }
}

// ---- bucket scan: exclusive prefix over <=256 buckets -----------------------

__global__ void k_bscan(const int* __restrict__ gcnt, int* __restrict__ bptr,
                        int* __restrict__ gcur, int NB) {
    __shared__ int tmp[256];
    int tid = threadIdx.x;
    int v = (tid < NB) ? gcnt[tid] : 0;
    tmp[tid] = v;
    __syncthreads();
    for (int off = 1; off < 256; off <<= 1) {
        int t = (tid >= off) ? tmp[tid - off] : 0;
        __syncthreads();
        tmp[tid] += t;
        __syncthreads();
    }
    if (tid == 0) bptr[0] = 0;
    if (tid < NB) {
        bptr[tid + 1] = tmp[tid];
        gcur[tid] = tmp[tid] - v;  // exclusive -> partition cursor
    }
}

// ---- partition edges into bucket-contiguous (src,tgt) buffer ----------------

__global__ __launch_bounds__(256) void k_part(const int* __restrict__ src,
                                              const int* __restrict__ tgt,
                                              int* __restrict__ gcur,
                                              uint2* __restrict__ ebuf, int E, int NB) {
    __shared__ int h[NBMAX];
    __shared__ int base[NBMAX];
    int tid = threadIdx.x;
    int e0 = blockIdx.x * CH;
    for (int b = tid; b < NB; b += 256) h[b] = 0;
    __syncthreads();
    int pk[CH / 256];
#pragma unroll
    for (int r = 0; r < CH / 256; r++) {
        int e = e0 + r * 256 + tid;
        if (e < E) {
            int b = tgt[e] >> BSHIFT;
            int l = atomicAdd(&h[b], 1);
            pk[r] = (b << 12) | l;  // l < 4096
        } else {
            pk[r] = -1;
        }
    }
    __syncthreads();
    for (int b = tid; b < NB; b += 256) {
        int c = h[b];
        base[b] = c ? atomicAdd(&gcur[b], c) : 0;
    }
    __syncthreads();
#pragma unroll
    for (int r = 0; r < CH / 256; r++) {
        if (pk[r] >= 0) {
            int e = e0 + r * 256 + tid;
            int b = pk[r] >> 12, l = pk[r] & 4095;
            ebuf[base[b] + l] = make_uint2((unsigned)src[e], (unsigned)tgt[e]);
        }
    }
}

// ---- per-bucket CSR fill: LDS count/scan/cursor, contiguous col region ------

__global__ __launch_bounds__(512) void k_bfill(const uint2* __restrict__ ebuf,
                                               const int* __restrict__ bptr,
                                               int* __restrict__ rowptr,
                                               int* __restrict__ col,
                                               float* __restrict__ dinv, int n, int NB) {
    __shared__ int s_cnt[BNODES];
    __shared__ int s_scan[BNODES];
    __shared__ int s_cur[BNODES];
    int b = blockIdx.x, tid = threadIdx.x;
    int nbase = b << BSHIFT;
    int ebase = bptr[b], eend = bptr[b + 1];
    s_cnt[tid] = 0;
    __syncthreads();
    for (int e = ebase + tid; e < eend; e += BNODES) {
        uint2 p = ebuf[e];
        atomicAdd(&s_cnt[(int)p.y - nbase], 1);
    }
    __syncthreads();
    s_scan[tid] = s_cnt[tid];
    __syncthreads();
    for (int off = 1; off < BNODES; off <<= 1) {
        int t = (tid >= off) ? s_scan[tid - off] : 0;
        __syncthreads();
        s_scan[tid] += t;
        __syncthreads();
    }
    int excl = s_scan[tid] - s_cnt[tid];
    s_cur[tid] = excl;
    int node = nbase + tid;
    if (node < n) {
        rowptr[node] = ebase + excl;
        dinv[node] = rsqrtf((float)(s_cnt[tid] + 1));  // +1 self-loop
    }
    if (b == NB - 1 && tid == 0) rowptr[n] = eend;
    __syncthreads();
    for (int e = ebase + tid; e < eend; e += BNODES) {
        uint2 p = ebuf[e];
        int pos = atomicAdd(&s_cur[(int)p.y - nbase], 1);
        col[ebase + pos] = (int)p.x;
    }
}

// ---- matmul 1: hs[n][j] = fp16((x[n] @ W1[:,j]) * dinv[n])  K=128, M=64 -----

__global__ __launch_bounds__(256) void k_mm1(const float* __restrict__ x,
                                             const float* __restrict__ W1,
                                             const float* __restrict__ dinv,
                                             __half* __restrict__ hs, int n) {
    __shared__ float Ws[128 * 64];   // [k][j]
    __shared__ float xs[32 * 132];   // [node][k], pitch 132
    int tid = threadIdx.x;
    {
        const float4* W4 = (const float4*)W1;
        float4* Ws4 = (float4*)Ws;
        for (int i = tid; i < 2048; i += 256) Ws4[i] = W4[i];
    }
    int nbase = blockIdx.x * 32;
    {
        const float4* x4 = (const float4*)(x + (size_t)nbase * 128);
        for (int f = tid; f < 1024; f += 256) {
            int r = f >> 5, k4 = f & 31;
            float4 v = make_float4(0.f, 0.f, 0.f, 0.f);
            if (nbase + r < n) v = x4[f];
            *(float4*)&xs[r * 132 + k4 * 4] = v;
        }
    }
    __syncthreads();
    int jg = (tid & 15) * 4;
    int nl = (tid >> 4) * 2;
    float a00 = 0, a01 = 0, a02 = 0, a03 = 0;
    float a10 = 0, a11 = 0, a12 = 0, a13 = 0;
    const float* xr0 = &xs[nl * 132];
    const float* xr1 = &xs[(nl + 1) * 132];
#pragma unroll 8
    for (int k = 0; k < 128; k++) {
        float4 w = *(const float4*)&Ws[k * 64 + jg];
        float p0 = xr0[k], p1 = xr1[k];
        a00 += p0 * w.x; a01 += p0 * w.y; a02 += p0 * w.z; a03 += p0 * w.w;
        a10 += p1 * w.x; a11 += p1 * w.y; a12 += p1 * w.z; a13 += p1 * w.w;
    }
    int n0 = nbase + nl, n1 = n0 + 1;
    union { uint2 u; __half2 h[2]; } pk;
    if (n0 < n) {
        float d = dinv[n0];
        pk.h[0] = __floats2half2_rn(a00 * d, a01 * d);
        pk.h[1] = __floats2half2_rn(a02 * d, a03 * d);
        *(uint2*)&hs[(size_t)n0 * 64 + jg] = pk.u;
    }
    if (n1 < n) {
        float d = dinv[n1];
        pk.h[0] = __floats2half2_rn(a10 * d, a11 * d);
        pk.h[1] = __floats2half2_rn(a12 * d, a13 * d);
        *(uint2*)&hs[(size_t)n1 * 64 + jg] = pk.u;
    }
}

// ---- conv1 gather (fp16 rows, 128B): h2[t]=relu(dinv*(sum)+b1), fp32 out ----

__global__ __launch_bounds__(256) void k_conv1(const __half2* __restrict__ hs2,
                                               const int* __restrict__ rowptr,
                                               const int* __restrict__ col,
                                               const float* __restrict__ dinv,
                                               const float2* __restrict__ b1,
                                               float2* __restrict__ h2, int n) {
    int wid = (blockIdx.x * 256 + threadIdx.x) >> 6;
    int lane = threadIdx.x & 63;
    if (wid >= n) return;
    int j2 = lane & 31, hf = lane >> 5;
    float ax = 0.f, ay = 0.f;
    if (hf == 0) {  // self-loop
        float2 s = __half22float2(hs2[(size_t)wid * 32 + j2]);
        ax = s.x; ay = s.y;
    }
    int beg = rowptr[wid], end = rowptr[wid + 1];
    for (int e0 = beg; e0 < end; e0 += 64) {
        int m = min(64, end - e0);
        int sl = (lane < m) ? col[e0 + lane] : 0;
        for (int i = 0; i < m; i += 2) {
            int idx = i + hf;
            int s = __shfl(sl, idx);
            bool valid = idx < m;
            float2 f = __half22float2(hs2[(size_t)(valid ? s : 0) * 32 + j2]);
            if (valid) { ax += f.x; ay += f.y; }
        }
    }
    ax += __shfl_xor(ax, 32);
    ay += __shfl_xor(ay, 32);
    if (hf == 0) {
        float d = dinv[wid];
        float2 bb = b1[j2];
        float2 o;
        o.x = fmaxf(ax * d + bb.x, 0.f);
        o.y = fmaxf(ay * d + bb.y, 0.f);
        h2[(size_t)wid * 32 + j2] = o;
    }
}

// ---- matmul 2: zs[n][c] = fp16((h2[n] @ W2[:,c]) * dinv[n])  K=64, M=32 -----

__global__ __launch_bounds__(256) void k_mm2(const float* __restrict__ h2,
                                             const float* __restrict__ W2,
                                             const float* __restrict__ dinv,
                                             __half* __restrict__ zs, int n) {
    __shared__ float Ws[64 * 32];  // [k][c]
    __shared__ float xs[64 * 68];  // [node][k], pitch 68
    int tid = threadIdx.x;
    {
        const float4* W4 = (const float4*)W2;
        float4* Ws4 = (float4*)Ws;
        for (int i = tid; i < 512; i += 256) Ws4[i] = W4[i];
    }
    int nbase = blockIdx.x * 64;
    for (int f = tid; f < 1024; f += 256) {
        int r = f >> 4, k4 = f & 15;
        int node = nbase + r;
        float4 v = make_float4(0.f, 0.f, 0.f, 0.f);
        if (node < n) v = *(const float4*)&h2[(size_t)node * 64 + k4 * 4];
        *(float4*)&xs[r * 68 + k4 * 4] = v;
    }
    __syncthreads();
    int jg = (tid & 7) * 4;
    int nl = (tid >> 3) * 2;
    float a00 = 0, a01 = 0, a02 = 0, a03 = 0;
    float a10 = 0, a11 = 0, a12 = 0, a13 = 0;
    const float* xr0 = &xs[nl * 68];
    const float* xr1 = &xs[(nl + 1) * 68];
#pragma unroll 8
    for (int k = 0; k < 64; k++) {
        float4 w = *(const float4*)&Ws[k * 32 + jg];
        float p0 = xr0[k], p1 = xr1[k];
        a00 += p0 * w.x; a01 += p0 * w.y; a02 += p0 * w.z; a03 += p0 * w.w;
        a10 += p1 * w.x; a11 += p1 * w.y; a12 += p1 * w.z; a13 += p1 * w.w;
    }
    int n0 = nbase + nl, n1 = n0 + 1;
    union { uint2 u; __half2 h[2]; } pk;
    if (n0 < n) {
        float d = dinv[n0];
        pk.h[0] = __floats2half2_rn(a00 * d, a01 * d);
        pk.h[1] = __floats2half2_rn(a02 * d, a03 * d);
        *(uint2*)&zs[(size_t)n0 * 32 + jg] = pk.u;
    }
    if (n1 < n) {
        float d = dinv[n1];
        pk.h[0] = __floats2half2_rn(a10 * d, a11 * d);
        pk.h[1] = __floats2half2_rn(a12 * d, a13 * d);
        *(uint2*)&zs[(size_t)n1 * 32 + jg] = pk.u;
    }
}

// ---- conv2 gather (fp16 rows, 64B): z fp32 to d_out + fp16 copy for decode --

__global__ __launch_bounds__(256) void k_conv2(const __half2* __restrict__ zs2,
                                               const int* __restrict__ rowptr,
                                               const int* __restrict__ col,
                                               const float* __restrict__ dinv,
                                               const float2* __restrict__ b2,
                                               float2* __restrict__ zout,
                                               __half2* __restrict__ zh, int n) {
    int wid = (blockIdx.x * 256 + threadIdx.x) >> 6;
    int lane = threadIdx.x & 63;
    if (wid >= n) return;
    int j2 = lane & 15, q = lane >> 4;
    float ax = 0.f, ay = 0.f;
    if (q == 0) {  // self-loop
        float2 s = __half22float2(zs2[(size_t)wid * 16 + j2]);
        ax = s.x; ay = s.y;
    }
    int beg = rowptr[wid], end = rowptr[wid + 1];
    for (int e0 = beg; e0 < end; e0 += 64) {
        int m = min(64, end - e0);
        int sl = (lane < m) ? col[e0 + lane] : 0;
        for (int i = 0; i < m; i += 4) {
            int idx = i + q;
            int s = __shfl(sl, idx);
            bool valid = idx < m;
            float2 f = __half22float2(zs2[(size_t)(valid ? s : 0) * 16 + j2]);
            if (valid) { ax += f.x; ay += f.y; }
        }
    }
    ax += __shfl_xor(ax, 16); ay += __shfl_xor(ay, 16);
    ax += __shfl_xor(ax, 32); ay += __shfl_xor(ay, 32);
    if (lane < 16) {
        float d = dinv[wid];
        float2 bb = b2[j2];
        float2 o;
        o.x = ax * d + bb.x;
        o.y = ay * d + bb.y;
        zout[(size_t)wid * 16 + j2] = o;
        zh[(size_t)wid * 16 + j2] = __floats2half2_rn(o.x, o.y);
    }
}

// ---- decode: recon[e] = dot(z[src], z[tgt]) — fp16 rows (64B), 16 lanes/edge

__global__ __launch_bounds__(256) void k_decode(const __half2* __restrict__ zh,
                                                const int* __restrict__ src,
                                                const int* __restrict__ tgt,
                                                float* __restrict__ recon, int E) {
    int e = (blockIdx.x * 256 + threadIdx.x) >> 4;
    if (e >= E) return;
    int j2 = threadIdx.x & 15;
    int s = src[e], t = tgt[e];
    float2 a = __half22float2(zh[(size_t)s * 16 + j2]);
    float2 b = __half22float2(zh[(size_t)t * 16 + j2]);
    float v = a.x * b.x + a.y * b.y;
    v += __shfl_xor(v, 8);
    v += __shfl_xor(v, 4);
    v += __shfl_xor(v, 2);
    v += __shfl_xor(v, 1);
    if (j2 == 0) recon[e] = v;
}

extern "C" void kernel_launch(void* const* d_in, const int* in_sizes, int n_in,
                              void* d_out, int out_size, void* d_ws, size_t ws_size,
                              hipStream_t stream) {
    const float* x = (const float*)d_in[0];
    const float* W1 = (const float*)d_in[1];
    const float* b1 = (const float*)d_in[2];
    const float* W2 = (const float*)d_in[3];
    const float* b2 = (const float*)d_in[4];
    const int* ei = (const int*)d_in[5];

    int N = in_sizes[0] / 128;
    int E = in_sizes[5] / 2;
    const int* src = ei;
    const int* tgt = ei + E;
    int NB = divup(N, BNODES);

    char* ws = (char*)d_ws;
    size_t off = 0;
    auto alloc = [&](size_t bytes) {
        size_t r = off;
        off += (bytes + 255) & ~(size_t)255;
        return r;
    };
    int* gcnt = (int*)(ws + alloc(NBMAX * 4));
    int* bptr = (int*)(ws + alloc((NBMAX + 1) * 4));
    int* gcur = (int*)(ws + alloc(NBMAX * 4));
    uint2* ebuf = (uint2*)(ws + alloc((size_t)E * 8));
    int* rowptr = (int*)(ws + alloc((size_t)(N + 1) * 4));
    int* col = (int*)(ws + alloc((size_t)E * 4));
    float* dinv = (float*)(ws + alloc((size_t)N * 4));
    __half* hs = (__half*)(ws + alloc((size_t)N * 64 * 2));
    float* h2 = (float*)(ws + alloc((size_t)N * 64 * 4));
    __half* zs = (__half*)(ws + alloc((size_t)N * 32 * 2));
    __half* zh = (__half*)(ws + alloc((size_t)N * 32 * 2));

    float* zout = (float*)d_out;
    float* recon = zout + (size_t)N * 32;

    hipMemsetAsync(gcnt, 0, NBMAX * 4, stream);

    int pblocks = divup(E, CH);
    k_hist<<<pblocks, 256, 0, stream>>>(tgt, gcnt, E, NB);
    k_bscan<<<1, 256, 0, stream>>>(gcnt, bptr, gcur, NB);
    k_part<<<pblocks, 256, 0, stream>>>(src, tgt, gcur, ebuf, E, NB);
    k_bfill<<<NB, BNODES, 0, stream>>>(ebuf, bptr, rowptr, col, dinv, N, NB);

    k_mm1<<<divup(N, 32), 256, 0, stream>>>(x, W1, dinv, hs, N);
    k_conv1<<<divup(N, 4), 256, 0, stream>>>((const __half2*)hs, rowptr, col, dinv,
                                             (const float2*)b1, (float2*)h2, N);
    k_mm2<<<divup(N, 64), 256, 0, stream>>>(h2, W2, dinv, zs, N);
    k_conv2<<<divup(N, 4), 256, 0, stream>>>((const __half2*)zs, rowptr, col, dinv,
                                             (const float2*)b2, (float2*)zout,
                                             (__half2*)zh, N);
    k_decode<<<divup(E, 16), 256, 0, stream>>>((const __half2*)zh, src, tgt, recon, E);
}

// Round 3
// 308.469 us; speedup vs baseline: 1.8893x; 1.2032x over previous
//
#include <hip/hip_runtime.h>
#include <hip/hip_fp16.h>
#include <math.h>

// GAE: 2x GCNConv + edge dot decode.
// R1: bucketed CSR build (LDS atomics, no global write-allocate storm),
//     fp16 gather tables (hs/zs/zh).
// R2: latency-bound gathers -> WIDE gathers. Each lane loads float4 (16B =
//     8 fp16 feats): conv1 = 8 edges/vmem-instr (was 2), conv2/decode = 16.
//     Cross-edge-slot shfl_xor reduce at the end (VALU was 64% idle).
//     ebuf packed to uint32 (local_tgt<<23|src), src kept in regs in k_part.

#define NBMAX 256   // max buckets (supports N <= 131072)
#define BSHIFT 9    // 512 nodes per bucket
#define BNODES 512
#define CH 4096     // edges per partition block

static inline int divup(int a, int b) { return (a + b - 1) / b; }

// ---- CSR build: bucket histogram (int4 reads) -------------------------------

__global__ __launch_bounds__(256) void k_hist(const int* __restrict__ tgt,
                                              int* __restrict__ gcnt, int E, int NB) {
    __shared__ int h[NBMAX];
    int tid = threadIdx.x;
    for (int b = tid; b < NB; b += 256) h[b] = 0;
    __syncthreads();
    int e0 = blockIdx.x * CH;
#pragma unroll
    for (int r = 0; r < CH / 1024; r++) {
        int e = e0 + (r * 256 + tid) * 4;
        if (e + 3 < E) {
            int4 t4 = *(const int4*)(tgt + e);
            atomicAdd(&h[t4.x >> BSHIFT], 1);
            atomicAdd(&h[t4.y >> BSHIFT], 1);
            atomicAdd(&h[t4.z >> BSHIFT], 1);
            atomicAdd(&h[t4.w >> BSHIFT], 1);
        } else {
            for (int j = 0; j < 4; j++)
                if (e + j < E) atomicAdd(&h[tgt[e + j] >> BSHIFT], 1);
        }
    }
    __syncthreads();
    for (int b = tid; b < NB; b += 256) {
        int v = h[b];
        if (v) atomicAdd(&gcnt[b], v);
    }
}

// ---- bucket scan: exclusive prefix over <=256 buckets -----------------------

__global__ void k_bscan(const int* __restrict__ gcnt, int* __restrict__ bptr,
                        int* __restrict__ gcur, int NB) {
    __shared__ int tmp[256];
    int tid = threadIdx.x;
    int v = (tid < NB) ? gcnt[tid] : 0;
    tmp[tid] = v;
    __syncthreads();
    for (int off = 1; off < 256; off <<= 1) {
        int t = (tid >= off) ? tmp[tid - off] : 0;
        __syncthreads();
        tmp[tid] += t;
        __syncthreads();
    }
    if (tid == 0) bptr[0] = 0;
    if (tid < NB) {
        bptr[tid + 1] = tmp[tid];
        gcur[tid] = tmp[tid] - v;  // exclusive -> partition cursor
    }
}

// ---- partition edges into bucket-contiguous packed buffer -------------------
// packed word: (local_tgt << 23) | src   (src < 2^17, local_tgt < 512)

__global__ __launch_bounds__(256) void k_part(const int* __restrict__ src,
                                              const int* __restrict__ tgt,
                                              int* __restrict__ gcur,
                                              unsigned* __restrict__ ebuf, int E, int NB) {
    __shared__ int h[NBMAX];
    __shared__ int base[NBMAX];
    int tid = threadIdx.x;
    int e0 = blockIdx.x * CH;
    for (int b = tid; b < NB; b += 256) h[b] = 0;
    __syncthreads();
    unsigned pk[CH / 256];
    int sv[CH / 256];
#pragma unroll
    for (int r = 0; r < CH / 256; r++) {
        int e = e0 + r * 256 + tid;
        if (e < E) {
            int t = tgt[e];
            int b = t >> BSHIFT;
            int l = atomicAdd(&h[b], 1);
            pk[r] = ((unsigned)b << 21) | ((unsigned)(t & (BNODES - 1)) << 12) | (unsigned)l;
            sv[r] = src[e];
        } else {
            pk[r] = 0xFFFFFFFFu;
        }
    }
    __syncthreads();
    for (int b = tid; b < NB; b += 256) {
        int c = h[b];
        base[b] = c ? atomicAdd(&gcur[b], c) : 0;
    }
    __syncthreads();
#pragma unroll
    for (int r = 0; r < CH / 256; r++) {
        if (pk[r] != 0xFFFFFFFFu) {
            int b = pk[r] >> 21;
            unsigned lt = (pk[r] >> 12) & (BNODES - 1);
            int l = pk[r] & 4095;
            ebuf[base[b] + l] = (lt << 23) | (unsigned)sv[r];
        }
    }
}

// ---- per-bucket CSR fill: LDS count/scan/cursor, contiguous col region ------

__global__ __launch_bounds__(512) void k_bfill(const unsigned* __restrict__ ebuf,
                                               const int* __restrict__ bptr,
                                               int* __restrict__ rowptr,
                                               int* __restrict__ col,
                                               float* __restrict__ dinv, int n, int NB) {
    __shared__ int s_cnt[BNODES];
    __shared__ int s_scan[BNODES];
    __shared__ int s_cur[BNODES];
    int b = blockIdx.x, tid = threadIdx.x;
    int nbase = b << BSHIFT;
    int ebase = bptr[b], eend = bptr[b + 1];
    s_cnt[tid] = 0;
    __syncthreads();
    for (int e = ebase + tid; e < eend; e += BNODES) {
        atomicAdd(&s_cnt[ebuf[e] >> 23], 1);
    }
    __syncthreads();
    s_scan[tid] = s_cnt[tid];
    __syncthreads();
    for (int off = 1; off < BNODES; off <<= 1) {
        int t = (tid >= off) ? s_scan[tid - off] : 0;
        __syncthreads();
        s_scan[tid] += t;
        __syncthreads();
    }
    int excl = s_scan[tid] - s_cnt[tid];
    s_cur[tid] = excl;
    int node = nbase + tid;
    if (node < n) {
        rowptr[node] = ebase + excl;
        dinv[node] = rsqrtf((float)(s_cnt[tid] + 1));  // +1 self-loop
    }
    if (b == NB - 1 && tid == 0) rowptr[n] = eend;
    __syncthreads();
    for (int e = ebase + tid; e < eend; e += BNODES) {
        unsigned p = ebuf[e];
        int pos = atomicAdd(&s_cur[p >> 23], 1);
        col[ebase + pos] = (int)(p & 0x7FFFFFu);
    }
}

// ---- matmul 1: hs[n][j] = fp16((x[n] @ W1[:,j]) * dinv[n])  K=128, M=64 -----

__global__ __launch_bounds__(256) void k_mm1(const float* __restrict__ x,
                                             const float* __restrict__ W1,
                                             const float* __restrict__ dinv,
                                             __half* __restrict__ hs, int n) {
    __shared__ float Ws[128 * 64];   // [k][j]
    __shared__ float xs[32 * 132];   // [node][k], pitch 132
    int tid = threadIdx.x;
    {
        const float4* W4 = (const float4*)W1;
        float4* Ws4 = (float4*)Ws;
        for (int i = tid; i < 2048; i += 256) Ws4[i] = W4[i];
    }
    int nbase = blockIdx.x * 32;
    {
        const float4* x4 = (const float4*)(x + (size_t)nbase * 128);
        for (int f = tid; f < 1024; f += 256) {
            int r = f >> 5, k4 = f & 31;
            float4 v = make_float4(0.f, 0.f, 0.f, 0.f);
            if (nbase + r < n) v = x4[f];
            *(float4*)&xs[r * 132 + k4 * 4] = v;
        }
    }
    __syncthreads();
    int jg = (tid & 15) * 4;
    int nl = (tid >> 4) * 2;
    float a00 = 0, a01 = 0, a02 = 0, a03 = 0;
    float a10 = 0, a11 = 0, a12 = 0, a13 = 0;
    const float* xr0 = &xs[nl * 132];
    const float* xr1 = &xs[(nl + 1) * 132];
#pragma unroll 8
    for (int k = 0; k < 128; k++) {
        float4 w = *(const float4*)&Ws[k * 64 + jg];
        float p0 = xr0[k], p1 = xr1[k];
        a00 += p0 * w.x; a01 += p0 * w.y; a02 += p0 * w.z; a03 += p0 * w.w;
        a10 += p1 * w.x; a11 += p1 * w.y; a12 += p1 * w.z; a13 += p1 * w.w;
    }
    int n0 = nbase + nl, n1 = n0 + 1;
    union { uint2 u; __half2 h[2]; } pk;
    if (n0 < n) {
        float d = dinv[n0];
        pk.h[0] = __floats2half2_rn(a00 * d, a01 * d);
        pk.h[1] = __floats2half2_rn(a02 * d, a03 * d);
        *(uint2*)&hs[(size_t)n0 * 64 + jg] = pk.u;
    }
    if (n1 < n) {
        float d = dinv[n1];
        pk.h[0] = __floats2half2_rn(a10 * d, a11 * d);
        pk.h[1] = __floats2half2_rn(a12 * d, a13 * d);
        *(uint2*)&hs[(size_t)n1 * 64 + jg] = pk.u;
    }
}

// ---- conv1 gather: wave/node, 8 lanes/row (float4 = 8 fp16), 8 edges/instr --

__global__ __launch_bounds__(256) void k_conv1(const __half* __restrict__ hs,
                                               const int* __restrict__ rowptr,
                                               const int* __restrict__ col,
                                               const float* __restrict__ dinv,
                                               const float* __restrict__ b1,
                                               float* __restrict__ h2, int n) {
    int wid = (blockIdx.x * 256 + threadIdx.x) >> 6;
    int lane = threadIdx.x & 63;
    if (wid >= n) return;
    int el = lane >> 3, fl = lane & 7;
    float a0 = 0, a1 = 0, a2 = 0, a3 = 0, a4 = 0, a5 = 0, a6 = 0, a7 = 0;
    if (el == 0) {  // self-loop in slot 0
        float4 v = *(const float4*)(hs + (size_t)wid * 64 + fl * 8);
        const __half2* h = (const __half2*)&v;
        float2 f0 = __half22float2(h[0]), f1 = __half22float2(h[1]);
        float2 f2 = __half22float2(h[2]), f3 = __half22float2(h[3]);
        a0 = f0.x; a1 = f0.y; a2 = f1.x; a3 = f1.y;
        a4 = f2.x; a5 = f2.y; a6 = f3.x; a7 = f3.y;
    }
    int beg = rowptr[wid], end = rowptr[wid + 1];
    for (int e0 = beg; e0 < end; e0 += 64) {
        int m = min(64, end - e0);
        int sl = (lane < m) ? col[e0 + lane] : 0;
        for (int i = 0; i < m; i += 8) {
            int idx = i + el;
            int s = __shfl(sl, idx);
            bool valid = idx < m;
            float4 v = *(const float4*)(hs + (size_t)(valid ? s : 0) * 64 + fl * 8);
            if (valid) {
                const __half2* h = (const __half2*)&v;
                float2 f0 = __half22float2(h[0]), f1 = __half22float2(h[1]);
                float2 f2 = __half22float2(h[2]), f3 = __half22float2(h[3]);
                a0 += f0.x; a1 += f0.y; a2 += f1.x; a3 += f1.y;
                a4 += f2.x; a5 += f2.y; a6 += f3.x; a7 += f3.y;
            }
        }
    }
    for (int d = 8; d < 64; d <<= 1) {
        a0 += __shfl_xor(a0, d); a1 += __shfl_xor(a1, d);
        a2 += __shfl_xor(a2, d); a3 += __shfl_xor(a3, d);
        a4 += __shfl_xor(a4, d); a5 += __shfl_xor(a5, d);
        a6 += __shfl_xor(a6, d); a7 += __shfl_xor(a7, d);
    }
    if (el == 0) {
        float d = dinv[wid];
        float4 bb0 = *(const float4*)(b1 + fl * 8);
        float4 bb1 = *(const float4*)(b1 + fl * 8 + 4);
        float4 o0, o1;
        o0.x = fmaxf(a0 * d + bb0.x, 0.f);
        o0.y = fmaxf(a1 * d + bb0.y, 0.f);
        o0.z = fmaxf(a2 * d + bb0.z, 0.f);
        o0.w = fmaxf(a3 * d + bb0.w, 0.f);
        o1.x = fmaxf(a4 * d + bb1.x, 0.f);
        o1.y = fmaxf(a5 * d + bb1.y, 0.f);
        o1.z = fmaxf(a6 * d + bb1.z, 0.f);
        o1.w = fmaxf(a7 * d + bb1.w, 0.f);
        *(float4*)(h2 + (size_t)wid * 64 + fl * 8) = o0;
        *(float4*)(h2 + (size_t)wid * 64 + fl * 8 + 4) = o1;
    }
}

// ---- matmul 2: zs[n][c] = fp16((h2[n] @ W2[:,c]) * dinv[n])  K=64, M=32 -----

__global__ __launch_bounds__(256) void k_mm2(const float* __restrict__ h2,
                                             const float* __restrict__ W2,
                                             const float* __restrict__ dinv,
                                             __half* __restrict__ zs, int n) {
    __shared__ float Ws[64 * 32];  // [k][c]
    __shared__ float xs[64 * 68];  // [node][k], pitch 68
    int tid = threadIdx.x;
    {
        const float4* W4 = (const float4*)W2;
        float4* Ws4 = (float4*)Ws;
        for (int i = tid; i < 512; i += 256) Ws4[i] = W4[i];
    }
    int nbase = blockIdx.x * 64;
    for (int f = tid; f < 1024; f += 256) {
        int r = f >> 4, k4 = f & 15;
        int node = nbase + r;
        float4 v = make_float4(0.f, 0.f, 0.f, 0.f);
        if (node < n) v = *(const float4*)&h2[(size_t)node * 64 + k4 * 4];
        *(float4*)&xs[r * 68 + k4 * 4] = v;
    }
    __syncthreads();
    int jg = (tid & 7) * 4;
    int nl = (tid >> 3) * 2;
    float a00 = 0, a01 = 0, a02 = 0, a03 = 0;
    float a10 = 0, a11 = 0, a12 = 0, a13 = 0;
    const float* xr0 = &xs[nl * 68];
    const float* xr1 = &xs[(nl + 1) * 68];
#pragma unroll 8
    for (int k = 0; k < 64; k++) {
        float4 w = *(const float4*)&Ws[k * 32 + jg];
        float p0 = xr0[k], p1 = xr1[k];
        a00 += p0 * w.x; a01 += p0 * w.y; a02 += p0 * w.z; a03 += p0 * w.w;
        a10 += p1 * w.x; a11 += p1 * w.y; a12 += p1 * w.z; a13 += p1 * w.w;
    }
    int n0 = nbase + nl, n1 = n0 + 1;
    union { uint2 u; __half2 h[2]; } pk;
    if (n0 < n) {
        float d = dinv[n0];
        pk.h[0] = __floats2half2_rn(a00 * d, a01 * d);
        pk.h[1] = __floats2half2_rn(a02 * d, a03 * d);
        *(uint2*)&zs[(size_t)n0 * 32 + jg] = pk.u;
    }
    if (n1 < n) {
        float d = dinv[n1];
        pk.h[0] = __floats2half2_rn(a10 * d, a11 * d);
        pk.h[1] = __floats2half2_rn(a12 * d, a13 * d);
        *(uint2*)&zs[(size_t)n1 * 32 + jg] = pk.u;
    }
}

// ---- conv2 gather: wave/node, 4 lanes/row (float4), 16 edges/instr ----------

__global__ __launch_bounds__(256) void k_conv2(const __half* __restrict__ zs,
                                               const int* __restrict__ rowptr,
                                               const int* __restrict__ col,
                                               const float* __restrict__ dinv,
                                               const float* __restrict__ b2,
                                               float* __restrict__ zout,
                                               __half* __restrict__ zh, int n) {
    int wid = (blockIdx.x * 256 + threadIdx.x) >> 6;
    int lane = threadIdx.x & 63;
    if (wid >= n) return;
    int el = lane >> 2, fl = lane & 3;
    float a0 = 0, a1 = 0, a2 = 0, a3 = 0, a4 = 0, a5 = 0, a6 = 0, a7 = 0;
    if (el == 0) {  // self-loop in slot 0
        float4 v = *(const float4*)(zs + (size_t)wid * 32 + fl * 8);
        const __half2* h = (const __half2*)&v;
        float2 f0 = __half22float2(h[0]), f1 = __half22float2(h[1]);
        float2 f2 = __half22float2(h[2]), f3 = __half22float2(h[3]);
        a0 = f0.x; a1 = f0.y; a2 = f1.x; a3 = f1.y;
        a4 = f2.x; a5 = f2.y; a6 = f3.x; a7 = f3.y;
    }
    int beg = rowptr[wid], end = rowptr[wid + 1];
    for (int e0 = beg; e0 < end; e0 += 64) {
        int m = min(64, end - e0);
        int sl = (lane < m) ? col[e0 + lane] : 0;
        for (int i = 0; i < m; i += 16) {
            int idx = i + el;
            int s = __shfl(sl, idx);
            bool valid = idx < m;
            float4 v = *(const float4*)(zs + (size_t)(valid ? s : 0) * 32 + fl * 8);
            if (valid) {
                const __half2* h = (const __half2*)&v;
                float2 f0 = __half22float2(h[0]), f1 = __half22float2(h[1]);
                float2 f2 = __half22float2(h[2]), f3 = __half22float2(h[3]);
                a0 += f0.x; a1 += f0.y; a2 += f1.x; a3 += f1.y;
                a4 += f2.x; a5 += f2.y; a6 += f3.x; a7 += f3.y;
            }
        }
    }
    for (int d = 4; d < 64; d <<= 1) {
        a0 += __shfl_xor(a0, d); a1 += __shfl_xor(a1, d);
        a2 += __shfl_xor(a2, d); a3 += __shfl_xor(a3, d);
        a4 += __shfl_xor(a4, d); a5 += __shfl_xor(a5, d);
        a6 += __shfl_xor(a6, d); a7 += __shfl_xor(a7, d);
    }
    if (el == 0) {
        float d = dinv[wid];
        float4 bb0 = *(const float4*)(b2 + fl * 8);
        float4 bb1 = *(const float4*)(b2 + fl * 8 + 4);
        float o0 = a0 * d + bb0.x, o1 = a1 * d + bb0.y;
        float o2 = a2 * d + bb0.z, o3 = a3 * d + bb0.w;
        float o4 = a4 * d + bb1.x, o5 = a5 * d + bb1.y;
        float o6 = a6 * d + bb1.z, o7 = a7 * d + bb1.w;
        *(float4*)(zout + (size_t)wid * 32 + fl * 8) = make_float4(o0, o1, o2, o3);
        *(float4*)(zout + (size_t)wid * 32 + fl * 8 + 4) = make_float4(o4, o5, o6, o7);
        union { float4 f; __half2 h[4]; } u;
        u.h[0] = __floats2half2_rn(o0, o1);
        u.h[1] = __floats2half2_rn(o2, o3);
        u.h[2] = __floats2half2_rn(o4, o5);
        u.h[3] = __floats2half2_rn(o6, o7);
        *(float4*)(zh + (size_t)wid * 32 + fl * 8) = u.f;
    }
}

// ---- decode: 4 lanes/edge, float4 fp16 rows, 16 edges per wave --------------

__global__ __launch_bounds__(256) void k_decode(const __half* __restrict__ zh,
                                                const int* __restrict__ src,
                                                const int* __restrict__ tgt,
                                                float* __restrict__ recon, int E) {
    int e = (blockIdx.x * 256 + threadIdx.x) >> 2;
    if (e >= E) return;
    int fl = threadIdx.x & 3;
    int s = src[e], t = tgt[e];
    float4 av = *(const float4*)(zh + (size_t)s * 32 + fl * 8);
    float4 bv = *(const float4*)(zh + (size_t)t * 32 + fl * 8);
    const __half2* ah = (const __half2*)&av;
    const __half2* bh = (const __half2*)&bv;
    float v = 0.f;
#pragma unroll
    for (int j = 0; j < 4; j++) {
        float2 fa = __half22float2(ah[j]);
        float2 fb = __half22float2(bh[j]);
        v += fa.x * fb.x + fa.y * fb.y;
    }
    v += __shfl_xor(v, 1);
    v += __shfl_xor(v, 2);
    if (fl == 0) recon[e] = v;
}

extern "C" void kernel_launch(void* const* d_in, const int* in_sizes, int n_in,
                              void* d_out, int out_size, void* d_ws, size_t ws_size,
                              hipStream_t stream) {
    const float* x = (const float*)d_in[0];
    const float* W1 = (const float*)d_in[1];
    const float* b1 = (const float*)d_in[2];
    const float* W2 = (const float*)d_in[3];
    const float* b2 = (const float*)d_in[4];
    const int* ei = (const int*)d_in[5];

    int N = in_sizes[0] / 128;
    int E = in_sizes[5] / 2;
    const int* src = ei;
    const int* tgt = ei + E;
    int NB = divup(N, BNODES);

    char* ws = (char*)d_ws;
    size_t off = 0;
    auto alloc = [&](size_t bytes) {
        size_t r = off;
        off += (bytes + 255) & ~(size_t)255;
        return r;
    };
    int* gcnt = (int*)(ws + alloc(NBMAX * 4));
    int* bptr = (int*)(ws + alloc((NBMAX + 1) * 4));
    int* gcur = (int*)(ws + alloc(NBMAX * 4));
    unsigned* ebuf = (unsigned*)(ws + alloc((size_t)E * 4));
    int* rowptr = (int*)(ws + alloc((size_t)(N + 1) * 4));
    int* col = (int*)(ws + alloc((size_t)E * 4));
    float* dinv = (float*)(ws + alloc((size_t)N * 4));
    __half* hs = (__half*)(ws + alloc((size_t)N * 64 * 2));
    float* h2 = (float*)(ws + alloc((size_t)N * 64 * 4));
    __half* zs = (__half*)(ws + alloc((size_t)N * 32 * 2));
    __half* zh = (__half*)(ws + alloc((size_t)N * 32 * 2));

    float* zout = (float*)d_out;
    float* recon = zout + (size_t)N * 32;

    hipMemsetAsync(gcnt, 0, NBMAX * 4, stream);

    int pblocks = divup(E, CH);
    k_hist<<<pblocks, 256, 0, stream>>>(tgt, gcnt, E, NB);
    k_bscan<<<1, 256, 0, stream>>>(gcnt, bptr, gcur, NB);
    k_part<<<pblocks, 256, 0, stream>>>(src, tgt, gcur, ebuf, E, NB);
    k_bfill<<<NB, BNODES, 0, stream>>>(ebuf, bptr, rowptr, col, dinv, N, NB);

    k_mm1<<<divup(N, 32), 256, 0, stream>>>(x, W1, dinv, hs, N);
    k_conv1<<<divup(N, 4), 256, 0, stream>>>(hs, rowptr, col, dinv, b1, h2, N);
    k_mm2<<<divup(N, 64), 256, 0, stream>>>(h2, W2, dinv, zs, N);
    k_conv2<<<divup(N, 4), 256, 0, stream>>>(zs, rowptr, col, dinv, b2, zout, zh, N);
    k_decode<<<divup(E, 64), 256, 0, stream>>>(zh, src, tgt, recon, E);
}

// Round 5
// 280.388 us; speedup vs baseline: 2.0785x; 1.1002x over previous
//
#include <hip/hip_runtime.h>
#include <hip/hip_fp16.h>
#include <math.h>

// GAE: 2x GCNConv + edge dot decode.
// R1: bucketed CSR build, fp16 gather tables.
// R2: wide gathers (float4/lane, 8-16 edges per vmem instr).
// R3/R4: (a) 2x-unrolled gather loops -> 2 loads in flight (latency fix);
//        (b) decode table zh in fp8-e4m3 (3.2MB, fits per-XCD L2), 2 edges
//            per 4-lane group in decode;
//        (c) fixed-capacity buckets (atomic append) -> k_hist/k_bscan gone.
//        R4 = R3 with the dead placeholder kernel removed (compile fix).

#define NBMAX 256    // max buckets (supports N <= 131072)
#define BSHIFT 9     // 512 nodes per bucket
#define BNODES 512
#define CH 4096      // edges per partition block
#define CAPSHIFT 14  // 16384 edge slots per bucket (mean 8192 at N=100k,E=1.6M)
#define CAP (1 << CAPSHIFT)

typedef float floatx2 __attribute__((ext_vector_type(2)));

static inline int divup(int a, int b) { return (a + b - 1) / b; }

// ---- init bucket cursors to fixed bases -------------------------------------

__global__ void k_init(int* __restrict__ gcur) {
    int b = threadIdx.x;
    gcur[b] = b << CAPSHIFT;
}

// ---- partition edges into fixed-capacity buckets (atomic append) ------------
// packed word: (local_tgt << 23) | src   (src < 2^17, local_tgt < 512)

__global__ __launch_bounds__(256) void k_part(const int* __restrict__ src,
                                              const int* __restrict__ tgt,
                                              int* __restrict__ gcur,
                                              unsigned* __restrict__ ebuf, int E, int NB) {
    __shared__ int h[NBMAX];
    __shared__ int base[NBMAX];
    int tid = threadIdx.x;
    int e0 = blockIdx.x * CH;
    for (int b = tid; b < NB; b += 256) h[b] = 0;
    __syncthreads();
    unsigned pk[CH / 256];
    int sv[CH / 256];
#pragma unroll
    for (int r = 0; r < CH / 256; r++) {
        int e = e0 + r * 256 + tid;
        if (e < E) {
            int t = tgt[e];
            int b = t >> BSHIFT;
            int l = atomicAdd(&h[b], 1);
            pk[r] = ((unsigned)b << 21) | ((unsigned)(t & (BNODES - 1)) << 12) | (unsigned)l;
            sv[r] = src[e];
        } else {
            pk[r] = 0xFFFFFFFFu;
        }
    }
    __syncthreads();
    for (int b = tid; b < NB; b += 256) {
        int c = h[b];
        base[b] = c ? atomicAdd(&gcur[b], c) : 0;
    }
    __syncthreads();
#pragma unroll
    for (int r = 0; r < CH / 256; r++) {
        if (pk[r] != 0xFFFFFFFFu) {
            int b = pk[r] >> 21;
            unsigned lt = (pk[r] >> 12) & (BNODES - 1);
            int l = pk[r] & 4095;
            ebuf[base[b] + l] = (lt << 23) | (unsigned)sv[r];
        }
    }
}

// ---- per-bucket CSR fill: LDS count/scan/cursor -----------------------------

__global__ __launch_bounds__(512) void k_bfill(const unsigned* __restrict__ ebuf,
                                               const int* __restrict__ gcur,
                                               int* __restrict__ rowbeg,
                                               int* __restrict__ rowend,
                                               int* __restrict__ col,
                                               float* __restrict__ dinv, int n) {
    __shared__ int s_cnt[BNODES];
    __shared__ int s_scan[BNODES];
    __shared__ int s_cur[BNODES];
    int b = blockIdx.x, tid = threadIdx.x;
    int nbase = b << BSHIFT;
    int ebase = b << CAPSHIFT;
    int eend = gcur[b];
    s_cnt[tid] = 0;
    __syncthreads();
    for (int e = ebase + tid; e < eend; e += BNODES) {
        atomicAdd(&s_cnt[ebuf[e] >> 23], 1);
    }
    __syncthreads();
    s_scan[tid] = s_cnt[tid];
    __syncthreads();
    for (int off = 1; off < BNODES; off <<= 1) {
        int t = (tid >= off) ? s_scan[tid - off] : 0;
        __syncthreads();
        s_scan[tid] += t;
        __syncthreads();
    }
    int excl = s_scan[tid] - s_cnt[tid];
    s_cur[tid] = excl;
    int node = nbase + tid;
    if (node < n) {
        rowbeg[node] = ebase + excl;
        rowend[node] = ebase + excl + s_cnt[tid];
        dinv[node] = rsqrtf((float)(s_cnt[tid] + 1));  // +1 self-loop
    }
    __syncthreads();
    for (int e = ebase + tid; e < eend; e += BNODES) {
        unsigned p = ebuf[e];
        int pos = atomicAdd(&s_cur[p >> 23], 1);
        col[ebase + pos] = (int)(p & 0x7FFFFFu);
    }
}

// ---- matmul 1: hs[n][j] = fp16((x[n] @ W1[:,j]) * dinv[n])  K=128, M=64 -----

__global__ __launch_bounds__(256) void k_mm1(const float* __restrict__ x,
                                             const float* __restrict__ W1,
                                             const float* __restrict__ dinv,
                                             __half* __restrict__ hs, int n) {
    __shared__ float Ws[128 * 64];   // [k][j]
    __shared__ float xs[32 * 132];   // [node][k], pitch 132
    int tid = threadIdx.x;
    {
        const float4* W4 = (const float4*)W1;
        float4* Ws4 = (float4*)Ws;
        for (int i = tid; i < 2048; i += 256) Ws4[i] = W4[i];
    }
    int nbase = blockIdx.x * 32;
    {
        const float4* x4 = (const float4*)(x + (size_t)nbase * 128);
        for (int f = tid; f < 1024; f += 256) {
            int r = f >> 5, k4 = f & 31;
            float4 v = make_float4(0.f, 0.f, 0.f, 0.f);
            if (nbase + r < n) v = x4[f];
            *(float4*)&xs[r * 132 + k4 * 4] = v;
        }
    }
    __syncthreads();
    int jg = (tid & 15) * 4;
    int nl = (tid >> 4) * 2;
    float a00 = 0, a01 = 0, a02 = 0, a03 = 0;
    float a10 = 0, a11 = 0, a12 = 0, a13 = 0;
    const float* xr0 = &xs[nl * 132];
    const float* xr1 = &xs[(nl + 1) * 132];
#pragma unroll 8
    for (int k = 0; k < 128; k++) {
        float4 w = *(const float4*)&Ws[k * 64 + jg];
        float p0 = xr0[k], p1 = xr1[k];
        a00 += p0 * w.x; a01 += p0 * w.y; a02 += p0 * w.z; a03 += p0 * w.w;
        a10 += p1 * w.x; a11 += p1 * w.y; a12 += p1 * w.z; a13 += p1 * w.w;
    }
    int n0 = nbase + nl, n1 = n0 + 1;
    union { uint2 u; __half2 h[2]; } pk;
    if (n0 < n) {
        float d = dinv[n0];
        pk.h[0] = __floats2half2_rn(a00 * d, a01 * d);
        pk.h[1] = __floats2half2_rn(a02 * d, a03 * d);
        *(uint2*)&hs[(size_t)n0 * 64 + jg] = pk.u;
    }
    if (n1 < n) {
        float d = dinv[n1];
        pk.h[0] = __floats2half2_rn(a10 * d, a11 * d);
        pk.h[1] = __floats2half2_rn(a12 * d, a13 * d);
        *(uint2*)&hs[(size_t)n1 * 64 + jg] = pk.u;
    }
}

// ---- conv1 gather: wave/node, 8 lanes/row, 2x unroll (2 loads in flight) ----

__global__ __launch_bounds__(256) void k_conv1(const __half* __restrict__ hs,
                                               const int* __restrict__ rowbeg,
                                               const int* __restrict__ rowend,
                                               const int* __restrict__ col,
                                               const float* __restrict__ dinv,
                                               const float* __restrict__ b1,
                                               float* __restrict__ h2, int n) {
    int wid = (blockIdx.x * 256 + threadIdx.x) >> 6;
    int lane = threadIdx.x & 63;
    if (wid >= n) return;
    int el = lane >> 3, fl = lane & 7;
    float a0 = 0, a1 = 0, a2 = 0, a3 = 0, a4 = 0, a5 = 0, a6 = 0, a7 = 0;
    if (el == 0) {  // self-loop
        float4 v = *(const float4*)(hs + (size_t)wid * 64 + fl * 8);
        const __half2* h = (const __half2*)&v;
        float2 f0 = __half22float2(h[0]), f1 = __half22float2(h[1]);
        float2 f2 = __half22float2(h[2]), f3 = __half22float2(h[3]);
        a0 = f0.x; a1 = f0.y; a2 = f1.x; a3 = f1.y;
        a4 = f2.x; a5 = f2.y; a6 = f3.x; a7 = f3.y;
    }
    int beg = rowbeg[wid], end = rowend[wid];
    for (int e0 = beg; e0 < end; e0 += 64) {
        int m = min(64, end - e0);
        int sl = (lane < m) ? col[e0 + lane] : 0;
        for (int i = 0; i < m; i += 16) {
            int i0 = i + el, i1 = i + 8 + el;
            int s0 = __shfl(sl, i0);
            int s1 = __shfl(sl, i1);
            bool v0 = i0 < m, v1 = i1 < m;
            float4 A = *(const float4*)(hs + (size_t)(v0 ? s0 : 0) * 64 + fl * 8);
            float4 B = *(const float4*)(hs + (size_t)(v1 ? s1 : 0) * 64 + fl * 8);
            if (v0) {
                const __half2* h = (const __half2*)&A;
                float2 f0 = __half22float2(h[0]), f1 = __half22float2(h[1]);
                float2 f2 = __half22float2(h[2]), f3 = __half22float2(h[3]);
                a0 += f0.x; a1 += f0.y; a2 += f1.x; a3 += f1.y;
                a4 += f2.x; a5 += f2.y; a6 += f3.x; a7 += f3.y;
            }
            if (v1) {
                const __half2* h = (const __half2*)&B;
                float2 f0 = __half22float2(h[0]), f1 = __half22float2(h[1]);
                float2 f2 = __half22float2(h[2]), f3 = __half22float2(h[3]);
                a0 += f0.x; a1 += f0.y; a2 += f1.x; a3 += f1.y;
                a4 += f2.x; a5 += f2.y; a6 += f3.x; a7 += f3.y;
            }
        }
    }
    for (int d = 8; d < 64; d <<= 1) {
        a0 += __shfl_xor(a0, d); a1 += __shfl_xor(a1, d);
        a2 += __shfl_xor(a2, d); a3 += __shfl_xor(a3, d);
        a4 += __shfl_xor(a4, d); a5 += __shfl_xor(a5, d);
        a6 += __shfl_xor(a6, d); a7 += __shfl_xor(a7, d);
    }
    if (el == 0) {
        float d = dinv[wid];
        float4 bb0 = *(const float4*)(b1 + fl * 8);
        float4 bb1 = *(const float4*)(b1 + fl * 8 + 4);
        float4 o0, o1;
        o0.x = fmaxf(a0 * d + bb0.x, 0.f);
        o0.y = fmaxf(a1 * d + bb0.y, 0.f);
        o0.z = fmaxf(a2 * d + bb0.z, 0.f);
        o0.w = fmaxf(a3 * d + bb0.w, 0.f);
        o1.x = fmaxf(a4 * d + bb1.x, 0.f);
        o1.y = fmaxf(a5 * d + bb1.y, 0.f);
        o1.z = fmaxf(a6 * d + bb1.z, 0.f);
        o1.w = fmaxf(a7 * d + bb1.w, 0.f);
        *(float4*)(h2 + (size_t)wid * 64 + fl * 8) = o0;
        *(float4*)(h2 + (size_t)wid * 64 + fl * 8 + 4) = o1;
    }
}

// ---- matmul 2: zs[n][c] = fp16((h2[n] @ W2[:,c]) * dinv[n])  K=64, M=32 -----

__global__ __launch_bounds__(256) void k_mm2(const float* __restrict__ h2,
                                             const float* __restrict__ W2,
                                             const float* __restrict__ dinv,
                                             __half* __restrict__ zs, int n) {
    __shared__ float Ws[64 * 32];  // [k][c]
    __shared__ float xs[64 * 68];  // [node][k], pitch 68
    int tid = threadIdx.x;
    {
        const float4* W4 = (const float4*)W2;
        float4* Ws4 = (float4*)Ws;
        for (int i = tid; i < 512; i += 256) Ws4[i] = W4[i];
    }
    int nbase = blockIdx.x * 64;
    for (int f = tid; f < 1024; f += 256) {
        int r = f >> 4, k4 = f & 15;
        int node = nbase + r;
        float4 v = make_float4(0.f, 0.f, 0.f, 0.f);
        if (node < n) v = *(const float4*)&h2[(size_t)node * 64 + k4 * 4];
        *(float4*)&xs[r * 68 + k4 * 4] = v;
    }
    __syncthreads();
    int jg = (tid & 7) * 4;
    int nl = (tid >> 3) * 2;
    float a00 = 0, a01 = 0, a02 = 0, a03 = 0;
    float a10 = 0, a11 = 0, a12 = 0, a13 = 0;
    const float* xr0 = &xs[nl * 68];
    const float* xr1 = &xs[(nl + 1) * 68];
#pragma unroll 8
    for (int k = 0; k < 64; k++) {
        float4 w = *(const float4*)&Ws[k * 32 + jg];
        float p0 = xr0[k], p1 = xr1[k];
        a00 += p0 * w.x; a01 += p0 * w.y; a02 += p0 * w.z; a03 += p0 * w.w;
        a10 += p1 * w.x; a11 += p1 * w.y; a12 += p1 * w.z; a13 += p1 * w.w;
    }
    int n0 = nbase + nl, n1 = n0 + 1;
    union { uint2 u; __half2 h[2]; } pk;
    if (n0 < n) {
        float d = dinv[n0];
        pk.h[0] = __floats2half2_rn(a00 * d, a01 * d);
        pk.h[1] = __floats2half2_rn(a02 * d, a03 * d);
        *(uint2*)&zs[(size_t)n0 * 32 + jg] = pk.u;
    }
    if (n1 < n) {
        float d = dinv[n1];
        pk.h[0] = __floats2half2_rn(a10 * d, a11 * d);
        pk.h[1] = __floats2half2_rn(a12 * d, a13 * d);
        *(uint2*)&zs[(size_t)n1 * 32 + jg] = pk.u;
    }
}

// ---- conv2 gather: wave/node, 4 lanes/row, 2x unroll; fp8 zh epilogue -------

__global__ __launch_bounds__(256) void k_conv2(const __half* __restrict__ zs,
                                               const int* __restrict__ rowbeg,
                                               const int* __restrict__ rowend,
                                               const int* __restrict__ col,
                                               const float* __restrict__ dinv,
                                               const float* __restrict__ b2,
                                               float* __restrict__ zout,
                                               unsigned char* __restrict__ zh8, int n) {
    int wid = (blockIdx.x * 256 + threadIdx.x) >> 6;
    int lane = threadIdx.x & 63;
    if (wid >= n) return;
    int el = lane >> 2, fl = lane & 3;
    float a0 = 0, a1 = 0, a2 = 0, a3 = 0, a4 = 0, a5 = 0, a6 = 0, a7 = 0;
    if (el == 0) {  // self-loop
        float4 v = *(const float4*)(zs + (size_t)wid * 32 + fl * 8);
        const __half2* h = (const __half2*)&v;
        float2 f0 = __half22float2(h[0]), f1 = __half22float2(h[1]);
        float2 f2 = __half22float2(h[2]), f3 = __half22float2(h[3]);
        a0 = f0.x; a1 = f0.y; a2 = f1.x; a3 = f1.y;
        a4 = f2.x; a5 = f2.y; a6 = f3.x; a7 = f3.y;
    }
    int beg = rowbeg[wid], end = rowend[wid];
    for (int e0 = beg; e0 < end; e0 += 64) {
        int m = min(64, end - e0);
        int sl = (lane < m) ? col[e0 + lane] : 0;
        for (int i = 0; i < m; i += 32) {
            int i0 = i + el, i1 = i + 16 + el;
            int s0 = __shfl(sl, i0);
            int s1 = __shfl(sl, i1);
            bool v0 = i0 < m, v1 = i1 < m;
            float4 A = *(const float4*)(zs + (size_t)(v0 ? s0 : 0) * 32 + fl * 8);
            float4 B = *(const float4*)(zs + (size_t)(v1 ? s1 : 0) * 32 + fl * 8);
            if (v0) {
                const __half2* h = (const __half2*)&A;
                float2 f0 = __half22float2(h[0]), f1 = __half22float2(h[1]);
                float2 f2 = __half22float2(h[2]), f3 = __half22float2(h[3]);
                a0 += f0.x; a1 += f0.y; a2 += f1.x; a3 += f1.y;
                a4 += f2.x; a5 += f2.y; a6 += f3.x; a7 += f3.y;
            }
            if (v1) {
                const __half2* h = (const __half2*)&B;
                float2 f0 = __half22float2(h[0]), f1 = __half22float2(h[1]);
                float2 f2 = __half22float2(h[2]), f3 = __half22float2(h[3]);
                a0 += f0.x; a1 += f0.y; a2 += f1.x; a3 += f1.y;
                a4 += f2.x; a5 += f2.y; a6 += f3.x; a7 += f3.y;
            }
        }
    }
    for (int d = 4; d < 64; d <<= 1) {
        a0 += __shfl_xor(a0, d); a1 += __shfl_xor(a1, d);
        a2 += __shfl_xor(a2, d); a3 += __shfl_xor(a3, d);
        a4 += __shfl_xor(a4, d); a5 += __shfl_xor(a5, d);
        a6 += __shfl_xor(a6, d); a7 += __shfl_xor(a7, d);
    }
    if (el == 0) {
        float d = dinv[wid];
        float4 bb0 = *(const float4*)(b2 + fl * 8);
        float4 bb1 = *(const float4*)(b2 + fl * 8 + 4);
        float o0 = a0 * d + bb0.x, o1 = a1 * d + bb0.y;
        float o2 = a2 * d + bb0.z, o3 = a3 * d + bb0.w;
        float o4 = a4 * d + bb1.x, o5 = a5 * d + bb1.y;
        float o6 = a6 * d + bb1.z, o7 = a7 * d + bb1.w;
        *(float4*)(zout + (size_t)wid * 32 + fl * 8) = make_float4(o0, o1, o2, o3);
        *(float4*)(zout + (size_t)wid * 32 + fl * 8 + 4) = make_float4(o4, o5, o6, o7);
        int w0 = __builtin_amdgcn_cvt_pk_fp8_f32(o0, o1, 0, false);
        w0 = __builtin_amdgcn_cvt_pk_fp8_f32(o2, o3, w0, true);
        int w1 = __builtin_amdgcn_cvt_pk_fp8_f32(o4, o5, 0, false);
        w1 = __builtin_amdgcn_cvt_pk_fp8_f32(o6, o7, w1, true);
        *(uint2*)(zh8 + (size_t)wid * 32 + fl * 8) = make_uint2((unsigned)w0, (unsigned)w1);
    }
}

// ---- decode: fp8 rows (32B), 4 lanes/edge, 2 edges per group ----------------

__device__ inline float fp8dot8(uint2 wa, uint2 wb) {
    floatx2 a, b;
    float v = 0.f;
    a = __builtin_amdgcn_cvt_pk_f32_fp8((int)wa.x, false);
    b = __builtin_amdgcn_cvt_pk_f32_fp8((int)wb.x, false);
    v += a.x * b.x + a.y * b.y;
    a = __builtin_amdgcn_cvt_pk_f32_fp8((int)wa.x, true);
    b = __builtin_amdgcn_cvt_pk_f32_fp8((int)wb.x, true);
    v += a.x * b.x + a.y * b.y;
    a = __builtin_amdgcn_cvt_pk_f32_fp8((int)wa.y, false);
    b = __builtin_amdgcn_cvt_pk_f32_fp8((int)wb.y, false);
    v += a.x * b.x + a.y * b.y;
    a = __builtin_amdgcn_cvt_pk_f32_fp8((int)wa.y, true);
    b = __builtin_amdgcn_cvt_pk_f32_fp8((int)wb.y, true);
    v += a.x * b.x + a.y * b.y;
    return v;
}

__global__ __launch_bounds__(256) void k_decode(const unsigned char* __restrict__ zh8,
                                                const int* __restrict__ src,
                                                const int* __restrict__ tgt,
                                                float* __restrict__ recon, int E) {
    int g = blockIdx.x * 64 + (threadIdx.x >> 2);
    int fl = threadIdx.x & 3;
    int e0 = g * 2, e1 = e0 + 1;
    if (e0 >= E) return;
    bool has1 = e1 < E;
    int s0 = src[e0], t0 = tgt[e0];
    int s1 = has1 ? src[e1] : 0, t1 = has1 ? tgt[e1] : 0;
    uint2 A0 = *(const uint2*)(zh8 + (size_t)s0 * 32 + fl * 8);
    uint2 B0 = *(const uint2*)(zh8 + (size_t)t0 * 32 + fl * 8);
    uint2 A1 = *(const uint2*)(zh8 + (size_t)s1 * 32 + fl * 8);
    uint2 B1 = *(const uint2*)(zh8 + (size_t)t1 * 32 + fl * 8);
    float v0 = fp8dot8(A0, B0);
    float v1 = fp8dot8(A1, B1);
    v0 += __shfl_xor(v0, 1); v0 += __shfl_xor(v0, 2);
    v1 += __shfl_xor(v1, 1); v1 += __shfl_xor(v1, 2);
    if (fl == 0) {
        if (has1) {
            *(float2*)(recon + e0) = make_float2(v0, v1);
        } else {
            recon[e0] = v0;
        }
    }
}

extern "C" void kernel_launch(void* const* d_in, const int* in_sizes, int n_in,
                              void* d_out, int out_size, void* d_ws, size_t ws_size,
                              hipStream_t stream) {
    const float* x = (const float*)d_in[0];
    const float* W1 = (const float*)d_in[1];
    const float* b1 = (const float*)d_in[2];
    const float* W2 = (const float*)d_in[3];
    const float* b2 = (const float*)d_in[4];
    const int* ei = (const int*)d_in[5];

    int N = in_sizes[0] / 128;
    int E = in_sizes[5] / 2;
    const int* src = ei;
    const int* tgt = ei + E;
    int NB = divup(N, BNODES);

    char* ws = (char*)d_ws;
    size_t off = 0;
    auto alloc = [&](size_t bytes) {
        size_t r = off;
        off += (bytes + 255) & ~(size_t)255;
        return r;
    };
    int* gcur = (int*)(ws + alloc(NBMAX * 4));
    unsigned* ebuf = (unsigned*)(ws + alloc((size_t)NB * CAP * 4));
    int* col = (int*)(ws + alloc((size_t)NB * CAP * 4));
    int* rowbeg = (int*)(ws + alloc((size_t)N * 4));
    int* rowend = (int*)(ws + alloc((size_t)N * 4));
    float* dinv = (float*)(ws + alloc((size_t)N * 4));
    __half* hs = (__half*)(ws + alloc((size_t)N * 64 * 2));
    float* h2 = (float*)(ws + alloc((size_t)N * 64 * 4));
    __half* zs = (__half*)(ws + alloc((size_t)N * 32 * 2));
    unsigned char* zh8 = (unsigned char*)(ws + alloc((size_t)N * 32));

    float* zout = (float*)d_out;
    float* recon = zout + (size_t)N * 32;

    k_init<<<1, NBMAX, 0, stream>>>(gcur);
    k_part<<<divup(E, CH), 256, 0, stream>>>(src, tgt, gcur, ebuf, E, NB);
    k_bfill<<<NB, BNODES, 0, stream>>>(ebuf, gcur, rowbeg, rowend, col, dinv, N);

    k_mm1<<<divup(N, 32), 256, 0, stream>>>(x, W1, dinv, hs, N);
    k_conv1<<<divup(N, 4), 256, 0, stream>>>(hs, rowbeg, rowend, col, dinv, b1, h2, N);
    k_mm2<<<divup(N, 64), 256, 0, stream>>>(h2, W2, dinv, zs, N);
    k_conv2<<<divup(N, 4), 256, 0, stream>>>(zs, rowbeg, rowend, col, dinv, b2, zout, zh8, N);
    k_decode<<<divup(E, 128), 256, 0, stream>>>(zh8, src, tgt, recon, E);
}

// Round 6
// 278.024 us; speedup vs baseline: 2.0961x; 1.0085x over previous
//
#include <hip/hip_runtime.h>
#include <hip/hip_fp16.h>
#include <math.h>

// GAE: 2x GCNConv + edge dot decode.
// R1: bucketed CSR build, fp16 gather tables.
// R2: wide gathers (float4/lane).
// R3-R5: unrolled gathers, fixed-capacity buckets, fp8 decode.
// R6: (a) convs batch 4 nodes/wave, 4x-peeled straight-line gather -> 16
//         loads in flight; (b) fp16 packed accumulation (v_pk_add_f16, 4
//         VALU/row) with zero-pad-row for predication-free adds; fp32
//         reduction tree; (c) decode table bf16 (fp8's 2.69e-3 absmax was
//         10% from threshold — restore margin); (d) h2 stored fp16.

#define NBMAX 256    // max buckets (supports N <= 131072)
#define BSHIFT 9     // 512 nodes per bucket
#define BNODES 512
#define CH 4096      // edges per partition block
#define CAPSHIFT 14  // 16384 edge slots per bucket (mean 8192 at N=100k,E=1.6M)
#define CAP (1 << CAPSHIFT)

static inline int divup(int a, int b) { return (a + b - 1) / b; }

__device__ inline void acc8(__half2* a, float4 v) {
    const __half2* h = (const __half2*)&v;
    a[0] = __hadd2(a[0], h[0]);
    a[1] = __hadd2(a[1], h[1]);
    a[2] = __hadd2(a[2], h[2]);
    a[3] = __hadd2(a[3], h[3]);
}
__device__ inline void acc4(__half2* a, float2 v) {
    const __half2* h = (const __half2*)&v;
    a[0] = __hadd2(a[0], h[0]);
    a[1] = __hadd2(a[1], h[1]);
}
__device__ inline unsigned short f2bf(float f) {
    unsigned u = __builtin_bit_cast(unsigned, f);
    u = (u + 0x7FFFu + ((u >> 16) & 1u)) >> 16;
    return (unsigned short)u;
}

// ---- init bucket cursors + zero pad rows ------------------------------------

__global__ void k_init(int* __restrict__ gcur, unsigned* __restrict__ hs_pad,
                       unsigned* __restrict__ zs_pad) {
    int t = threadIdx.x;
    if (t < NBMAX) gcur[t] = t << CAPSHIFT;
    if (t < 32) hs_pad[t] = 0;          // 128B zero row (64 fp16)
    else if (t < 48) zs_pad[t - 32] = 0;  // 64B zero row (32 fp16)
}

// ---- partition edges into fixed-capacity buckets (atomic append) ------------
// packed word: (local_tgt << 23) | src   (src < 2^17, local_tgt < 512)

__global__ __launch_bounds__(256) void k_part(const int* __restrict__ src,
                                              const int* __restrict__ tgt,
                                              int* __restrict__ gcur,
                                              unsigned* __restrict__ ebuf, int E, int NB) {
    __shared__ int h[NBMAX];
    __shared__ int base[NBMAX];
    int tid = threadIdx.x;
    int e0 = blockIdx.x * CH;
    for (int b = tid; b < NB; b += 256) h[b] = 0;
    __syncthreads();
    unsigned pk[CH / 256];
    int sv[CH / 256];
#pragma unroll
    for (int r = 0; r < CH / 256; r++) {
        int e = e0 + r * 256 + tid;
        if (e < E) {
            int t = tgt[e];
            int b = t >> BSHIFT;
            int l = atomicAdd(&h[b], 1);
            pk[r] = ((unsigned)b << 21) | ((unsigned)(t & (BNODES - 1)) << 12) | (unsigned)l;
            sv[r] = src[e];
        } else {
            pk[r] = 0xFFFFFFFFu;
        }
    }
    __syncthreads();
    for (int b = tid; b < NB; b += 256) {
        int c = h[b];
        base[b] = c ? atomicAdd(&gcur[b], c) : 0;
    }
    __syncthreads();
#pragma unroll
    for (int r = 0; r < CH / 256; r++) {
        if (pk[r] != 0xFFFFFFFFu) {
            int b = pk[r] >> 21;
            unsigned lt = (pk[r] >> 12) & (BNODES - 1);
            int l = pk[r] & 4095;
            ebuf[base[b] + l] = (lt << 23) | (unsigned)sv[r];
        }
    }
}

// ---- per-bucket CSR fill: LDS count/scan/cursor -----------------------------

__global__ __launch_bounds__(512) void k_bfill(const unsigned* __restrict__ ebuf,
                                               const int* __restrict__ gcur,
                                               int* __restrict__ rowbeg,
                                               int* __restrict__ rowend,
                                               int* __restrict__ col,
                                               float* __restrict__ dinv, int n) {
    __shared__ int s_cnt[BNODES];
    __shared__ int s_scan[BNODES];
    __shared__ int s_cur[BNODES];
    int b = blockIdx.x, tid = threadIdx.x;
    int nbase = b << BSHIFT;
    int ebase = b << CAPSHIFT;
    int eend = gcur[b];
    s_cnt[tid] = 0;
    __syncthreads();
    for (int e = ebase + tid; e < eend; e += BNODES) {
        atomicAdd(&s_cnt[ebuf[e] >> 23], 1);
    }
    __syncthreads();
    s_scan[tid] = s_cnt[tid];
    __syncthreads();
    for (int off = 1; off < BNODES; off <<= 1) {
        int t = (tid >= off) ? s_scan[tid - off] : 0;
        __syncthreads();
        s_scan[tid] += t;
        __syncthreads();
    }
    int excl = s_scan[tid] - s_cnt[tid];
    s_cur[tid] = excl;
    int node = nbase + tid;
    if (node < n) {
        rowbeg[node] = ebase + excl;
        rowend[node] = ebase + excl + s_cnt[tid];
        dinv[node] = rsqrtf((float)(s_cnt[tid] + 1));  // +1 self-loop
    }
    __syncthreads();
    for (int e = ebase + tid; e < eend; e += BNODES) {
        unsigned p = ebuf[e];
        int pos = atomicAdd(&s_cur[p >> 23], 1);
        col[ebase + pos] = (int)(p & 0x7FFFFFu);
    }
}

// ---- matmul 1: hs[n][j] = fp16((x[n] @ W1[:,j]) * dinv[n])  K=128, M=64 -----

__global__ __launch_bounds__(256) void k_mm1(const float* __restrict__ x,
                                             const float* __restrict__ W1,
                                             const float* __restrict__ dinv,
                                             __half* __restrict__ hs, int n) {
    __shared__ float Ws[128 * 64];   // [k][j]
    __shared__ float xs[32 * 132];   // [node][k], pitch 132
    int tid = threadIdx.x;
    {
        const float4* W4 = (const float4*)W1;
        float4* Ws4 = (float4*)Ws;
        for (int i = tid; i < 2048; i += 256) Ws4[i] = W4[i];
    }
    int nbase = blockIdx.x * 32;
    {
        const float4* x4 = (const float4*)(x + (size_t)nbase * 128);
        for (int f = tid; f < 1024; f += 256) {
            int r = f >> 5, k4 = f & 31;
            float4 v = make_float4(0.f, 0.f, 0.f, 0.f);
            if (nbase + r < n) v = x4[f];
            *(float4*)&xs[r * 132 + k4 * 4] = v;
        }
    }
    __syncthreads();
    int jg = (tid & 15) * 4;
    int nl = (tid >> 4) * 2;
    float a00 = 0, a01 = 0, a02 = 0, a03 = 0;
    float a10 = 0, a11 = 0, a12 = 0, a13 = 0;
    const float* xr0 = &xs[nl * 132];
    const float* xr1 = &xs[(nl + 1) * 132];
#pragma unroll 8
    for (int k = 0; k < 128; k++) {
        float4 w = *(const float4*)&Ws[k * 64 + jg];
        float p0 = xr0[k], p1 = xr1[k];
        a00 += p0 * w.x; a01 += p0 * w.y; a02 += p0 * w.z; a03 += p0 * w.w;
        a10 += p1 * w.x; a11 += p1 * w.y; a12 += p1 * w.z; a13 += p1 * w.w;
    }
    int n0 = nbase + nl, n1 = n0 + 1;
    union { uint2 u; __half2 h[2]; } pk;
    if (n0 < n) {
        float d = dinv[n0];
        pk.h[0] = __floats2half2_rn(a00 * d, a01 * d);
        pk.h[1] = __floats2half2_rn(a02 * d, a03 * d);
        *(uint2*)&hs[(size_t)n0 * 64 + jg] = pk.u;
    }
    if (n1 < n) {
        float d = dinv[n1];
        pk.h[0] = __floats2half2_rn(a10 * d, a11 * d);
        pk.h[1] = __floats2half2_rn(a12 * d, a13 * d);
        *(uint2*)&hs[(size_t)n1 * 64 + jg] = pk.u;
    }
}

// ---- conv1: 4 nodes/wave, 8 lanes/row, 4x peel (16 loads in flight) ---------
// hs has a zeroed pad row at index n; invalid slots load it unconditionally.

__global__ __launch_bounds__(256) void k_conv1(const __half* __restrict__ hs,
                                               const int* __restrict__ rowbeg,
                                               const int* __restrict__ rowend,
                                               const int* __restrict__ col,
                                               const float* __restrict__ dinv,
                                               const float* __restrict__ b1,
                                               __half* __restrict__ h2, int n) {
    int w = (blockIdx.x * 256 + threadIdx.x) >> 6;
    int lane = threadIdx.x & 63;
    int base = w * 4;
    if (base >= n) return;
    int el = lane >> 3, fl = lane & 7;
    __half2 a2[4][4];
#pragma unroll
    for (int k = 0; k < 4; k++)
#pragma unroll
        for (int j = 0; j < 4; j++) a2[k][j] = __half2half2(__float2half(0.f));

    int beg[4], end[4], sl[4], mm[4];
#pragma unroll
    for (int k = 0; k < 4; k++) {
        int node = base + k;
        bool v = node < n;
        beg[k] = v ? rowbeg[node] : 0;
        end[k] = v ? rowend[node] : 0;
        int m0 = min(64, end[k] - beg[k]);
        mm[k] = m0;
        sl[k] = (lane < m0) ? col[beg[k] + lane] : 0;
    }
    // self-loops (only el==0 group loads real row, others hit pad)
    float4 S[4];
#pragma unroll
    for (int k = 0; k < 4; k++) {
        int a = (el == 0 && base + k < n) ? base + k : n;
        S[k] = *(const float4*)(hs + (size_t)a * 64 + fl * 8);
    }
    // peeled 32 edge slots per node
    float4 A[4], B[4], C[4], D[4];
#pragma unroll
    for (int k = 0; k < 4; k++) {
        int s0 = __shfl(sl[k], el);
        int s1 = __shfl(sl[k], 8 + el);
        int i0 = (el < mm[k]) ? s0 : n;
        int i1 = (8 + el < mm[k]) ? s1 : n;
        A[k] = *(const float4*)(hs + (size_t)i0 * 64 + fl * 8);
        B[k] = *(const float4*)(hs + (size_t)i1 * 64 + fl * 8);
    }
#pragma unroll
    for (int k = 0; k < 4; k++) {
        int s2 = __shfl(sl[k], 16 + el);
        int s3 = __shfl(sl[k], 24 + el);
        int i2 = (16 + el < mm[k]) ? s2 : n;
        int i3 = (24 + el < mm[k]) ? s3 : n;
        C[k] = *(const float4*)(hs + (size_t)i2 * 64 + fl * 8);
        D[k] = *(const float4*)(hs + (size_t)i3 * 64 + fl * 8);
    }
#pragma unroll
    for (int k = 0; k < 4; k++) {
        acc8(a2[k], S[k]);
        acc8(a2[k], A[k]);
        acc8(a2[k], B[k]);
    }
#pragma unroll
    for (int k = 0; k < 4; k++) {
        acc8(a2[k], C[k]);
        acc8(a2[k], D[k]);
    }
    // rare leftovers (deg > 32), wave-uniform loops
#pragma unroll
    for (int k = 0; k < 4; k++) {
        if (end[k] - beg[k] > 32) {
            for (int i = 32; i < mm[k]; i += 8) {
                int idx = i + el;
                int s = __shfl(sl[k], idx & 63);
                int a = (idx < mm[k]) ? s : n;
                float4 v = *(const float4*)(hs + (size_t)a * 64 + fl * 8);
                acc8(a2[k], v);
            }
            for (int e0 = beg[k] + 64; e0 < end[k]; e0 += 64) {
                int m = min(64, end[k] - e0);
                int sl2 = (lane < m) ? col[e0 + lane] : 0;
                for (int i = 0; i < m; i += 8) {
                    int idx = i + el;
                    int s = __shfl(sl2, idx & 63);
                    int a = (idx < m) ? s : n;
                    float4 v = *(const float4*)(hs + (size_t)a * 64 + fl * 8);
                    acc8(a2[k], v);
                }
            }
        }
    }
    // fp32 reduction tree over the 8 el groups
    float r[4][8];
#pragma unroll
    for (int k = 0; k < 4; k++)
#pragma unroll
        for (int j = 0; j < 4; j++) {
            float2 f = __half22float2(a2[k][j]);
            r[k][2 * j] = f.x;
            r[k][2 * j + 1] = f.y;
        }
#pragma unroll
    for (int k = 0; k < 4; k++)
        for (int d = 8; d < 64; d <<= 1)
#pragma unroll
            for (int j = 0; j < 8; j++) r[k][j] += __shfl_xor(r[k][j], d);

    if (el == 0) {
        float4 bb0 = *(const float4*)(b1 + fl * 8);
        float4 bb1 = *(const float4*)(b1 + fl * 8 + 4);
#pragma unroll
        for (int k = 0; k < 4; k++) {
            int node = base + k;
            if (node < n) {
                float d = dinv[node];
                union { float4 f; __half2 h[4]; } u;
                u.h[0] = __floats2half2_rn(fmaxf(r[k][0] * d + bb0.x, 0.f),
                                           fmaxf(r[k][1] * d + bb0.y, 0.f));
                u.h[1] = __floats2half2_rn(fmaxf(r[k][2] * d + bb0.z, 0.f),
                                           fmaxf(r[k][3] * d + bb0.w, 0.f));
                u.h[2] = __floats2half2_rn(fmaxf(r[k][4] * d + bb1.x, 0.f),
                                           fmaxf(r[k][5] * d + bb1.y, 0.f));
                u.h[3] = __floats2half2_rn(fmaxf(r[k][6] * d + bb1.z, 0.f),
                                           fmaxf(r[k][7] * d + bb1.w, 0.f));
                *(float4*)(h2 + (size_t)node * 64 + fl * 8) = u.f;
            }
        }
    }
}

// ---- matmul 2: zs[n][c] = fp16((h2[n] @ W2[:,c]) * dinv[n])  K=64, M=32 -----
// h2 is fp16 now.

__global__ __launch_bounds__(256) void k_mm2(const __half* __restrict__ h2,
                                             const float* __restrict__ W2,
                                             const float* __restrict__ dinv,
                                             __half* __restrict__ zs, int n) {
    __shared__ float Ws[64 * 32];  // [k][c]
    __shared__ float xs[64 * 68];  // [node][k], pitch 68
    int tid = threadIdx.x;
    {
        const float4* W4 = (const float4*)W2;
        float4* Ws4 = (float4*)Ws;
        for (int i = tid; i < 512; i += 256) Ws4[i] = W4[i];
    }
    int nbase = blockIdx.x * 64;
    for (int f = tid; f < 1024; f += 256) {
        int r = f >> 4, k4 = f & 15;
        int node = nbase + r;
        float4 v = make_float4(0.f, 0.f, 0.f, 0.f);
        if (node < n) {
            uint2 u = *(const uint2*)(h2 + (size_t)node * 64 + k4 * 4);
            const __half2* hh = (const __half2*)&u;
            float2 a = __half22float2(hh[0]);
            float2 b = __half22float2(hh[1]);
            v = make_float4(a.x, a.y, b.x, b.y);
        }
        *(float4*)&xs[r * 68 + k4 * 4] = v;
    }
    __syncthreads();
    int jg = (tid & 7) * 4;
    int nl = (tid >> 3) * 2;
    float a00 = 0, a01 = 0, a02 = 0, a03 = 0;
    float a10 = 0, a11 = 0, a12 = 0, a13 = 0;
    const float* xr0 = &xs[nl * 68];
    const float* xr1 = &xs[(nl + 1) * 68];
#pragma unroll 8
    for (int k = 0; k < 64; k++) {
        float4 w = *(const float4*)&Ws[k * 32 + jg];
        float p0 = xr0[k], p1 = xr1[k];
        a00 += p0 * w.x; a01 += p0 * w.y; a02 += p0 * w.z; a03 += p0 * w.w;
        a10 += p1 * w.x; a11 += p1 * w.y; a12 += p1 * w.z; a13 += p1 * w.w;
    }
    int n0 = nbase + nl, n1 = n0 + 1;
    union { uint2 u; __half2 h[2]; } pk;
    if (n0 < n) {
        float d = dinv[n0];
        pk.h[0] = __floats2half2_rn(a00 * d, a01 * d);
        pk.h[1] = __floats2half2_rn(a02 * d, a03 * d);
        *(uint2*)&zs[(size_t)n0 * 32 + jg] = pk.u;
    }
    if (n1 < n) {
        float d = dinv[n1];
        pk.h[0] = __floats2half2_rn(a10 * d, a11 * d);
        pk.h[1] = __floats2half2_rn(a12 * d, a13 * d);
        *(uint2*)&zs[(size_t)n1 * 32 + jg] = pk.u;
    }
}

// ---- conv2: 4 nodes/wave, 8 lanes/row (float2), 4x peel; bf16 zh ------------
// zs has a zeroed pad row at index n.

__global__ __launch_bounds__(256) void k_conv2(const __half* __restrict__ zs,
                                               const int* __restrict__ rowbeg,
                                               const int* __restrict__ rowend,
                                               const int* __restrict__ col,
                                               const float* __restrict__ dinv,
                                               const float* __restrict__ b2,
                                               float* __restrict__ zout,
                                               unsigned short* __restrict__ zh, int n) {
    int w = (blockIdx.x * 256 + threadIdx.x) >> 6;
    int lane = threadIdx.x & 63;
    int base = w * 4;
    if (base >= n) return;
    int el = lane >> 3, fl = lane & 7;
    __half2 a2[4][2];
#pragma unroll
    for (int k = 0; k < 4; k++) {
        a2[k][0] = __half2half2(__float2half(0.f));
        a2[k][1] = __half2half2(__float2half(0.f));
    }
    int beg[4], end[4], sl[4], mm[4];
#pragma unroll
    for (int k = 0; k < 4; k++) {
        int node = base + k;
        bool v = node < n;
        beg[k] = v ? rowbeg[node] : 0;
        end[k] = v ? rowend[node] : 0;
        int m0 = min(64, end[k] - beg[k]);
        mm[k] = m0;
        sl[k] = (lane < m0) ? col[beg[k] + lane] : 0;
    }
    float2 S[4];
#pragma unroll
    for (int k = 0; k < 4; k++) {
        int a = (el == 0 && base + k < n) ? base + k : n;
        S[k] = *(const float2*)(zs + (size_t)a * 32 + fl * 4);
    }
    float2 A[4], B[4], C[4], D[4];
#pragma unroll
    for (int k = 0; k < 4; k++) {
        int s0 = __shfl(sl[k], el);
        int s1 = __shfl(sl[k], 8 + el);
        int i0 = (el < mm[k]) ? s0 : n;
        int i1 = (8 + el < mm[k]) ? s1 : n;
        A[k] = *(const float2*)(zs + (size_t)i0 * 32 + fl * 4);
        B[k] = *(const float2*)(zs + (size_t)i1 * 32 + fl * 4);
    }
#pragma unroll
    for (int k = 0; k < 4; k++) {
        int s2 = __shfl(sl[k], 16 + el);
        int s3 = __shfl(sl[k], 24 + el);
        int i2 = (16 + el < mm[k]) ? s2 : n;
        int i3 = (24 + el < mm[k]) ? s3 : n;
        C[k] = *(const float2*)(zs + (size_t)i2 * 32 + fl * 4);
        D[k] = *(const float2*)(zs + (size_t)i3 * 32 + fl * 4);
    }
#pragma unroll
    for (int k = 0; k < 4; k++) {
        acc4(a2[k], S[k]);
        acc4(a2[k], A[k]);
        acc4(a2[k], B[k]);
    }
#pragma unroll
    for (int k = 0; k < 4; k++) {
        acc4(a2[k], C[k]);
        acc4(a2[k], D[k]);
    }
#pragma unroll
    for (int k = 0; k < 4; k++) {
        if (end[k] - beg[k] > 32) {
            for (int i = 32; i < mm[k]; i += 8) {
                int idx = i + el;
                int s = __shfl(sl[k], idx & 63);
                int a = (idx < mm[k]) ? s : n;
                float2 v = *(const float2*)(zs + (size_t)a * 32 + fl * 4);
                acc4(a2[k], v);
            }
            for (int e0 = beg[k] + 64; e0 < end[k]; e0 += 64) {
                int m = min(64, end[k] - e0);
                int sl2 = (lane < m) ? col[e0 + lane] : 0;
                for (int i = 0; i < m; i += 8) {
                    int idx = i + el;
                    int s = __shfl(sl2, idx & 63);
                    int a = (idx < m) ? s : n;
                    float2 v = *(const float2*)(zs + (size_t)a * 32 + fl * 4);
                    acc4(a2[k], v);
                }
            }
        }
    }
    float r[4][4];
#pragma unroll
    for (int k = 0; k < 4; k++)
#pragma unroll
        for (int j = 0; j < 2; j++) {
            float2 f = __half22float2(a2[k][j]);
            r[k][2 * j] = f.x;
            r[k][2 * j + 1] = f.y;
        }
#pragma unroll
    for (int k = 0; k < 4; k++)
        for (int d = 8; d < 64; d <<= 1)
#pragma unroll
            for (int j = 0; j < 4; j++) r[k][j] += __shfl_xor(r[k][j], d);

    if (el == 0) {
        float4 bb = *(const float4*)(b2 + fl * 4);
#pragma unroll
        for (int k = 0; k < 4; k++) {
            int node = base + k;
            if (node < n) {
                float d = dinv[node];
                float o0 = r[k][0] * d + bb.x;
                float o1 = r[k][1] * d + bb.y;
                float o2 = r[k][2] * d + bb.z;
                float o3 = r[k][3] * d + bb.w;
                *(float4*)(zout + (size_t)node * 32 + fl * 4) = make_float4(o0, o1, o2, o3);
                unsigned p0 = (unsigned)f2bf(o0) | ((unsigned)f2bf(o1) << 16);
                unsigned p1 = (unsigned)f2bf(o2) | ((unsigned)f2bf(o3) << 16);
                *(uint2*)(zh + (size_t)node * 32 + fl * 4) = make_uint2(p0, p1);
            }
        }
    }
}

// ---- decode: bf16 rows (64B), 4 lanes/edge, 4 edges per group ---------------

__device__ inline float bfdot8(uint4 a, uint4 b) {
    const unsigned* pa = (const unsigned*)&a;
    const unsigned* pb = (const unsigned*)&b;
    float v = 0.f;
#pragma unroll
    for (int w = 0; w < 4; w++) {
        float alo = __builtin_bit_cast(float, pa[w] << 16);
        float ahi = __builtin_bit_cast(float, pa[w] & 0xFFFF0000u);
        float blo = __builtin_bit_cast(float, pb[w] << 16);
        float bhi = __builtin_bit_cast(float, pb[w] & 0xFFFF0000u);
        v += alo * blo + ahi * bhi;
    }
    return v;
}

__global__ __launch_bounds__(256) void k_decode(const unsigned short* __restrict__ zh,
                                                const int* __restrict__ src,
                                                const int* __restrict__ tgt,
                                                float* __restrict__ recon, int E) {
    int g = (blockIdx.x * 256 + threadIdx.x) >> 2;
    int fl = threadIdx.x & 3;
    int e0 = g * 4;
    if (e0 >= E) return;
    int cnt = min(4, E - e0);
    int s[4], t[4];
#pragma unroll
    for (int q = 0; q < 4; q++) {
        int e = (q < cnt) ? e0 + q : e0;
        s[q] = src[e];
        t[q] = tgt[e];
    }
    uint4 Za[4], Zb[4];
#pragma unroll
    for (int q = 0; q < 4; q++) {
        Za[q] = *(const uint4*)(zh + (size_t)s[q] * 32 + fl * 8);
        Zb[q] = *(const uint4*)(zh + (size_t)t[q] * 32 + fl * 8);
    }
    float v[4];
#pragma unroll
    for (int q = 0; q < 4; q++) {
        float x = bfdot8(Za[q], Zb[q]);
        x += __shfl_xor(x, 1);
        x += __shfl_xor(x, 2);
        v[q] = x;
    }
    if (fl == 0) {
        if (cnt == 4) {
            *(float4*)(recon + e0) = make_float4(v[0], v[1], v[2], v[3]);
        } else {
            for (int q = 0; q < cnt; q++) recon[e0 + q] = v[q];
        }
    }
}

extern "C" void kernel_launch(void* const* d_in, const int* in_sizes, int n_in,
                              void* d_out, int out_size, void* d_ws, size_t ws_size,
                              hipStream_t stream) {
    const float* x = (const float*)d_in[0];
    const float* W1 = (const float*)d_in[1];
    const float* b1 = (const float*)d_in[2];
    const float* W2 = (const float*)d_in[3];
    const float* b2 = (const float*)d_in[4];
    const int* ei = (const int*)d_in[5];

    int N = in_sizes[0] / 128;
    int E = in_sizes[5] / 2;
    const int* src = ei;
    const int* tgt = ei + E;
    int NB = divup(N, BNODES);

    char* ws = (char*)d_ws;
    size_t off = 0;
    auto alloc = [&](size_t bytes) {
        size_t r = off;
        off += (bytes + 255) & ~(size_t)255;
        return r;
    };
    int* gcur = (int*)(ws + alloc(NBMAX * 4));
    unsigned* ebuf = (unsigned*)(ws + alloc((size_t)NB * CAP * 4));
    int* col = (int*)(ws + alloc((size_t)NB * CAP * 4));
    int* rowbeg = (int*)(ws + alloc((size_t)N * 4));
    int* rowend = (int*)(ws + alloc((size_t)N * 4));
    float* dinv = (float*)(ws + alloc((size_t)N * 4));
    __half* hs = (__half*)(ws + alloc((size_t)(N + 1) * 64 * 2));   // +pad row n
    __half* h2 = (__half*)(ws + alloc((size_t)N * 64 * 2));
    __half* zs = (__half*)(ws + alloc((size_t)(N + 1) * 32 * 2));   // +pad row n
    unsigned short* zh = (unsigned short*)(ws + alloc((size_t)N * 32 * 2));

    float* zout = (float*)d_out;
    float* recon = zout + (size_t)N * 32;

    k_init<<<1, 256, 0, stream>>>(gcur, (unsigned*)(hs + (size_t)N * 64),
                                  (unsigned*)(zs + (size_t)N * 32));
    k_part<<<divup(E, CH), 256, 0, stream>>>(src, tgt, gcur, ebuf, E, NB);
    k_bfill<<<NB, BNODES, 0, stream>>>(ebuf, gcur, rowbeg, rowend, col, dinv, N);

    k_mm1<<<divup(N, 32), 256, 0, stream>>>(x, W1, dinv, hs, N);
    k_conv1<<<divup(N, 16), 256, 0, stream>>>(hs, rowbeg, rowend, col, dinv, b1, h2, N);
    k_mm2<<<divup(N, 64), 256, 0, stream>>>(h2, W2, dinv, zs, N);
    k_conv2<<<divup(N, 16), 256, 0, stream>>>(zs, rowbeg, rowend, col, dinv, b2, zout, zh, N);
    k_decode<<<divup(E, 256), 256, 0, stream>>>(zh, src, tgt, recon, E);
}

// Round 7
// 277.512 us; speedup vs baseline: 2.1000x; 1.0018x over previous
//
#include <hip/hip_runtime.h>
#include <hip/hip_fp16.h>
#include <math.h>

// GAE: 2x GCNConv + edge dot decode.
// R1: bucketed CSR build, fp16 gather tables.
// R2: wide gathers (float4/lane).
// R3-R5: unrolled gathers, fixed-capacity buckets.
// R6: fp16 packed accumulation, zero-pad row, bf16 decode (kept);
//     4-nodes/wave batching (REGRESSED: VGPR 64, occupancy 37% — reverted).
// R7: 1 node/wave + 4x-peeled straight-line gather (self + 4 rounds = 5
//     loads in flight) at low VGPR; conv2 uses 4 lanes/row (16 rows/instr).

#define NBMAX 256    // max buckets (supports N <= 131072)
#define BSHIFT 9     // 512 nodes per bucket
#define BNODES 512
#define CH 4096      // edges per partition block
#define CAPSHIFT 14  // 16384 edge slots per bucket (mean 8192 at N=100k,E=1.6M)
#define CAP (1 << CAPSHIFT)

static inline int divup(int a, int b) { return (a + b - 1) / b; }

__device__ inline void acc8(__half2* a, float4 v) {
    const __half2* h = (const __half2*)&v;
    a[0] = __hadd2(a[0], h[0]);
    a[1] = __hadd2(a[1], h[1]);
    a[2] = __hadd2(a[2], h[2]);
    a[3] = __hadd2(a[3], h[3]);
}
__device__ inline unsigned short f2bf(float f) {
    unsigned u = __builtin_bit_cast(unsigned, f);
    u = (u + 0x7FFFu + ((u >> 16) & 1u)) >> 16;
    return (unsigned short)u;
}

// ---- init bucket cursors + zero pad rows ------------------------------------

__global__ void k_init(int* __restrict__ gcur, unsigned* __restrict__ hs_pad,
                       unsigned* __restrict__ zs_pad) {
    int t = threadIdx.x;
    if (t < NBMAX) gcur[t] = t << CAPSHIFT;
    if (t < 32) hs_pad[t] = 0;            // 128B zero row (64 fp16)
    else if (t < 48) zs_pad[t - 32] = 0;  // 64B zero row (32 fp16)
}

// ---- partition edges into fixed-capacity buckets (atomic append) ------------
// packed word: (local_tgt << 23) | src   (src < 2^17, local_tgt < 512)

__global__ __launch_bounds__(256) void k_part(const int* __restrict__ src,
                                              const int* __restrict__ tgt,
                                              int* __restrict__ gcur,
                                              unsigned* __restrict__ ebuf, int E, int NB) {
    __shared__ int h[NBMAX];
    __shared__ int base[NBMAX];
    int tid = threadIdx.x;
    int e0 = blockIdx.x * CH;
    for (int b = tid; b < NB; b += 256) h[b] = 0;
    __syncthreads();
    unsigned pk[CH / 256];
    int sv[CH / 256];
#pragma unroll
    for (int r = 0; r < CH / 256; r++) {
        int e = e0 + r * 256 + tid;
        if (e < E) {
            int t = tgt[e];
            int b = t >> BSHIFT;
            int l = atomicAdd(&h[b], 1);
            pk[r] = ((unsigned)b << 21) | ((unsigned)(t & (BNODES - 1)) << 12) | (unsigned)l;
            sv[r] = src[e];
        } else {
            pk[r] = 0xFFFFFFFFu;
        }
    }
    __syncthreads();
    for (int b = tid; b < NB; b += 256) {
        int c = h[b];
        base[b] = c ? atomicAdd(&gcur[b], c) : 0;
    }
    __syncthreads();
#pragma unroll
    for (int r = 0; r < CH / 256; r++) {
        if (pk[r] != 0xFFFFFFFFu) {
            int b = pk[r] >> 21;
            unsigned lt = (pk[r] >> 12) & (BNODES - 1);
            int l = pk[r] & 4095;
            ebuf[base[b] + l] = (lt << 23) | (unsigned)sv[r];
        }
    }
}

// ---- per-bucket CSR fill: LDS count/scan/cursor -----------------------------

__global__ __launch_bounds__(512) void k_bfill(const unsigned* __restrict__ ebuf,
                                               const int* __restrict__ gcur,
                                               int* __restrict__ rowbeg,
                                               int* __restrict__ rowend,
                                               int* __restrict__ col,
                                               float* __restrict__ dinv, int n) {
    __shared__ int s_cnt[BNODES];
    __shared__ int s_scan[BNODES];
    __shared__ int s_cur[BNODES];
    int b = blockIdx.x, tid = threadIdx.x;
    int nbase = b << BSHIFT;
    int ebase = b << CAPSHIFT;
    int eend = gcur[b];
    s_cnt[tid] = 0;
    __syncthreads();
    for (int e = ebase + tid; e < eend; e += BNODES) {
        atomicAdd(&s_cnt[ebuf[e] >> 23], 1);
    }
    __syncthreads();
    s_scan[tid] = s_cnt[tid];
    __syncthreads();
    for (int off = 1; off < BNODES; off <<= 1) {
        int t = (tid >= off) ? s_scan[tid - off] : 0;
        __syncthreads();
        s_scan[tid] += t;
        __syncthreads();
    }
    int excl = s_scan[tid] - s_cnt[tid];
    s_cur[tid] = excl;
    int node = nbase + tid;
    if (node < n) {
        rowbeg[node] = ebase + excl;
        rowend[node] = ebase + excl + s_cnt[tid];
        dinv[node] = rsqrtf((float)(s_cnt[tid] + 1));  // +1 self-loop
    }
    __syncthreads();
    for (int e = ebase + tid; e < eend; e += BNODES) {
        unsigned p = ebuf[e];
        int pos = atomicAdd(&s_cur[p >> 23], 1);
        col[ebase + pos] = (int)(p & 0x7FFFFFu);
    }
}

// ---- matmul 1: hs[n][j] = fp16((x[n] @ W1[:,j]) * dinv[n])  K=128, M=64 -----

__global__ __launch_bounds__(256) void k_mm1(const float* __restrict__ x,
                                             const float* __restrict__ W1,
                                             const float* __restrict__ dinv,
                                             __half* __restrict__ hs, int n) {
    __shared__ float Ws[128 * 64];   // [k][j]
    __shared__ float xs[32 * 132];   // [node][k], pitch 132
    int tid = threadIdx.x;
    {
        const float4* W4 = (const float4*)W1;
        float4* Ws4 = (float4*)Ws;
        for (int i = tid; i < 2048; i += 256) Ws4[i] = W4[i];
    }
    int nbase = blockIdx.x * 32;
    {
        const float4* x4 = (const float4*)(x + (size_t)nbase * 128);
        for (int f = tid; f < 1024; f += 256) {
            int r = f >> 5, k4 = f & 31;
            float4 v = make_float4(0.f, 0.f, 0.f, 0.f);
            if (nbase + r < n) v = x4[f];
            *(float4*)&xs[r * 132 + k4 * 4] = v;
        }
    }
    __syncthreads();
    int jg = (tid & 15) * 4;
    int nl = (tid >> 4) * 2;
    float a00 = 0, a01 = 0, a02 = 0, a03 = 0;
    float a10 = 0, a11 = 0, a12 = 0, a13 = 0;
    const float* xr0 = &xs[nl * 132];
    const float* xr1 = &xs[(nl + 1) * 132];
#pragma unroll 8
    for (int k = 0; k < 128; k++) {
        float4 w = *(const float4*)&Ws[k * 64 + jg];
        float p0 = xr0[k], p1 = xr1[k];
        a00 += p0 * w.x; a01 += p0 * w.y; a02 += p0 * w.z; a03 += p0 * w.w;
        a10 += p1 * w.x; a11 += p1 * w.y; a12 += p1 * w.z; a13 += p1 * w.w;
    }
    int n0 = nbase + nl, n1 = n0 + 1;
    union { uint2 u; __half2 h[2]; } pk;
    if (n0 < n) {
        float d = dinv[n0];
        pk.h[0] = __floats2half2_rn(a00 * d, a01 * d);
        pk.h[1] = __floats2half2_rn(a02 * d, a03 * d);
        *(uint2*)&hs[(size_t)n0 * 64 + jg] = pk.u;
    }
    if (n1 < n) {
        float d = dinv[n1];
        pk.h[0] = __floats2half2_rn(a10 * d, a11 * d);
        pk.h[1] = __floats2half2_rn(a12 * d, a13 * d);
        *(uint2*)&hs[(size_t)n1 * 64 + jg] = pk.u;
    }
}

// ---- conv1: 1 node/wave, 8 lanes/row, 4x peel (5 loads in flight) -----------
// hs has a zeroed pad row at index n; invalid slots load it unconditionally.

__global__ __launch_bounds__(256) void k_conv1(const __half* __restrict__ hs,
                                               const int* __restrict__ rowbeg,
                                               const int* __restrict__ rowend,
                                               const int* __restrict__ col,
                                               const float* __restrict__ dinv,
                                               const float* __restrict__ b1,
                                               __half* __restrict__ h2, int n) {
    int w = (blockIdx.x * 256 + threadIdx.x) >> 6;
    int lane = threadIdx.x & 63;
    if (w >= n) return;
    int el = lane >> 3, fl = lane & 7;
    int beg = rowbeg[w], end = rowend[w];
    int deg = end - beg;
    int m = min(64, deg);
    int sl = (lane < m) ? col[beg + lane] : 0;
    int s0 = __shfl(sl, el);
    int s1 = __shfl(sl, 8 + el);
    int s2 = __shfl(sl, 16 + el);
    int s3 = __shfl(sl, 24 + el);
    int r0 = (el < m) ? s0 : n;
    int r1 = (8 + el < m) ? s1 : n;
    int r2 = (16 + el < m) ? s2 : n;
    int r3 = (24 + el < m) ? s3 : n;
    int rs = (el == 0) ? w : n;
    float4 S = *(const float4*)(hs + (size_t)rs * 64 + fl * 8);
    float4 A = *(const float4*)(hs + (size_t)r0 * 64 + fl * 8);
    float4 B = *(const float4*)(hs + (size_t)r1 * 64 + fl * 8);
    float4 C = *(const float4*)(hs + (size_t)r2 * 64 + fl * 8);
    float4 D = *(const float4*)(hs + (size_t)r3 * 64 + fl * 8);
    __half2 a2[4];
#pragma unroll
    for (int j = 0; j < 4; j++) a2[j] = __half2half2(__float2half(0.f));
    acc8(a2, S);
    acc8(a2, A);
    acc8(a2, B);
    acc8(a2, C);
    acc8(a2, D);
    if (deg > 32) {  // rare (Poisson mean 16), wave-uniform
        for (int i = 32; i < m; i += 8) {
            int idx = i + el;
            int s = __shfl(sl, idx & 63);
            int a = (idx < m) ? s : n;
            float4 v = *(const float4*)(hs + (size_t)a * 64 + fl * 8);
            acc8(a2, v);
        }
        for (int e0 = beg + 64; e0 < end; e0 += 64) {
            int mc = min(64, end - e0);
            int sl2 = (lane < mc) ? col[e0 + lane] : 0;
            for (int i = 0; i < mc; i += 8) {
                int idx = i + el;
                int s = __shfl(sl2, idx & 63);
                int a = (idx < mc) ? s : n;
                float4 v = *(const float4*)(hs + (size_t)a * 64 + fl * 8);
                acc8(a2, v);
            }
        }
    }
    // fp32 reduction tree over the 8 el groups
    float r[8];
#pragma unroll
    for (int j = 0; j < 4; j++) {
        float2 f = __half22float2(a2[j]);
        r[2 * j] = f.x;
        r[2 * j + 1] = f.y;
    }
    for (int d = 8; d < 64; d <<= 1)
#pragma unroll
        for (int j = 0; j < 8; j++) r[j] += __shfl_xor(r[j], d);

    if (el == 0) {
        float d = dinv[w];
        float4 bb0 = *(const float4*)(b1 + fl * 8);
        float4 bb1 = *(const float4*)(b1 + fl * 8 + 4);
        union { float4 f; __half2 h[4]; } u;
        u.h[0] = __floats2half2_rn(fmaxf(r[0] * d + bb0.x, 0.f),
                                   fmaxf(r[1] * d + bb0.y, 0.f));
        u.h[1] = __floats2half2_rn(fmaxf(r[2] * d + bb0.z, 0.f),
                                   fmaxf(r[3] * d + bb0.w, 0.f));
        u.h[2] = __floats2half2_rn(fmaxf(r[4] * d + bb1.x, 0.f),
                                   fmaxf(r[5] * d + bb1.y, 0.f));
        u.h[3] = __floats2half2_rn(fmaxf(r[6] * d + bb1.z, 0.f),
                                   fmaxf(r[7] * d + bb1.w, 0.f));
        *(float4*)(h2 + (size_t)w * 64 + fl * 8) = u.f;
    }
}

// ---- matmul 2: zs[n][c] = fp16((h2[n] @ W2[:,c]) * dinv[n])  K=64, M=32 -----

__global__ __launch_bounds__(256) void k_mm2(const __half* __restrict__ h2,
                                             const float* __restrict__ W2,
                                             const float* __restrict__ dinv,
                                             __half* __restrict__ zs, int n) {
    __shared__ float Ws[64 * 32];  // [k][c]
    __shared__ float xs[64 * 68];  // [node][k], pitch 68
    int tid = threadIdx.x;
    {
        const float4* W4 = (const float4*)W2;
        float4* Ws4 = (float4*)Ws;
        for (int i = tid; i < 512; i += 256) Ws4[i] = W4[i];
    }
    int nbase = blockIdx.x * 64;
    for (int f = tid; f < 1024; f += 256) {
        int r = f >> 4, k4 = f & 15;
        int node = nbase + r;
        float4 v = make_float4(0.f, 0.f, 0.f, 0.f);
        if (node < n) {
            uint2 u = *(const uint2*)(h2 + (size_t)node * 64 + k4 * 4);
            const __half2* hh = (const __half2*)&u;
            float2 a = __half22float2(hh[0]);
            float2 b = __half22float2(hh[1]);
            v = make_float4(a.x, a.y, b.x, b.y);
        }
        *(float4*)&xs[r * 68 + k4 * 4] = v;
    }
    __syncthreads();
    int jg = (tid & 7) * 4;
    int nl = (tid >> 3) * 2;
    float a00 = 0, a01 = 0, a02 = 0, a03 = 0;
    float a10 = 0, a11 = 0, a12 = 0, a13 = 0;
    const float* xr0 = &xs[nl * 68];
    const float* xr1 = &xs[(nl + 1) * 68];
#pragma unroll 8
    for (int k = 0; k < 64; k++) {
        float4 w = *(const float4*)&Ws[k * 32 + jg];
        float p0 = xr0[k], p1 = xr1[k];
        a00 += p0 * w.x; a01 += p0 * w.y; a02 += p0 * w.z; a03 += p0 * w.w;
        a10 += p1 * w.x; a11 += p1 * w.y; a12 += p1 * w.z; a13 += p1 * w.w;
    }
    int n0 = nbase + nl, n1 = n0 + 1;
    union { uint2 u; __half2 h[2]; } pk;
    if (n0 < n) {
        float d = dinv[n0];
        pk.h[0] = __floats2half2_rn(a00 * d, a01 * d);
        pk.h[1] = __floats2half2_rn(a02 * d, a03 * d);
        *(uint2*)&zs[(size_t)n0 * 32 + jg] = pk.u;
    }
    if (n1 < n) {
        float d = dinv[n1];
        pk.h[0] = __floats2half2_rn(a10 * d, a11 * d);
        pk.h[1] = __floats2half2_rn(a12 * d, a13 * d);
        *(uint2*)&zs[(size_t)n1 * 32 + jg] = pk.u;
    }
}

// ---- conv2: 1 node/wave, 4 lanes/row (16B), 16 rows/instr, peel -------------
// zs has a zeroed pad row at index n. bf16 zh epilogue for decode.

__global__ __launch_bounds__(256) void k_conv2(const __half* __restrict__ zs,
                                               const int* __restrict__ rowbeg,
                                               const int* __restrict__ rowend,
                                               const int* __restrict__ col,
                                               const float* __restrict__ dinv,
                                               const float* __restrict__ b2,
                                               float* __restrict__ zout,
                                               unsigned short* __restrict__ zh, int n) {
    int w = (blockIdx.x * 256 + threadIdx.x) >> 6;
    int lane = threadIdx.x & 63;
    if (w >= n) return;
    int el = lane >> 2, fl = lane & 3;  // 16 el groups x 4 lanes
    int beg = rowbeg[w], end = rowend[w];
    int deg = end - beg;
    int m = min(64, deg);
    int sl = (lane < m) ? col[beg + lane] : 0;
    int s0 = __shfl(sl, el);
    int s1 = __shfl(sl, 16 + el);
    int r0 = (el < m) ? s0 : n;
    int r1 = (16 + el < m) ? s1 : n;
    int rs = (el == 0) ? w : n;
    float4 S = *(const float4*)(zs + (size_t)rs * 32 + fl * 8);
    float4 A = *(const float4*)(zs + (size_t)r0 * 32 + fl * 8);
    float4 B = *(const float4*)(zs + (size_t)r1 * 32 + fl * 8);
    __half2 a2[4];
#pragma unroll
    for (int j = 0; j < 4; j++) a2[j] = __half2half2(__float2half(0.f));
    acc8(a2, S);
    acc8(a2, A);
    acc8(a2, B);
    if (deg > 32) {  // wave-uniform
        int s2 = __shfl(sl, 32 + el);
        int s3 = __shfl(sl, 48 + el);
        int r2 = (32 + el < m) ? s2 : n;
        int r3 = (48 + el < m) ? s3 : n;
        float4 C = *(const float4*)(zs + (size_t)r2 * 32 + fl * 8);
        float4 D = *(const float4*)(zs + (size_t)r3 * 32 + fl * 8);
        acc8(a2, C);
        acc8(a2, D);
        for (int e0 = beg + 64; e0 < end; e0 += 64) {
            int mc = min(64, end - e0);
            int sl2 = (lane < mc) ? col[e0 + lane] : 0;
            for (int i = 0; i < mc; i += 16) {
                int idx = i + el;
                int s = __shfl(sl2, idx & 63);
                int a = (idx < mc) ? s : n;
                float4 v = *(const float4*)(zs + (size_t)a * 32 + fl * 8);
                acc8(a2, v);
            }
        }
    }
    // fp32 reduction tree over the 16 el groups
    float r[8];
#pragma unroll
    for (int j = 0; j < 4; j++) {
        float2 f = __half22float2(a2[j]);
        r[2 * j] = f.x;
        r[2 * j + 1] = f.y;
    }
    for (int d = 4; d < 64; d <<= 1)
#pragma unroll
        for (int j = 0; j < 8; j++) r[j] += __shfl_xor(r[j], d);

    if (el == 0) {  // lanes 0-3 each hold feats fl*8..fl*8+7
        float d = dinv[w];
        float4 bb0 = *(const float4*)(b2 + fl * 8);
        float4 bb1 = *(const float4*)(b2 + fl * 8 + 4);
        float o0 = r[0] * d + bb0.x, o1 = r[1] * d + bb0.y;
        float o2 = r[2] * d + bb0.z, o3 = r[3] * d + bb0.w;
        float o4 = r[4] * d + bb1.x, o5 = r[5] * d + bb1.y;
        float o6 = r[6] * d + bb1.z, o7 = r[7] * d + bb1.w;
        *(float4*)(zout + (size_t)w * 32 + fl * 8) = make_float4(o0, o1, o2, o3);
        *(float4*)(zout + (size_t)w * 32 + fl * 8 + 4) = make_float4(o4, o5, o6, o7);
        uint4 p;
        p.x = (unsigned)f2bf(o0) | ((unsigned)f2bf(o1) << 16);
        p.y = (unsigned)f2bf(o2) | ((unsigned)f2bf(o3) << 16);
        p.z = (unsigned)f2bf(o4) | ((unsigned)f2bf(o5) << 16);
        p.w = (unsigned)f2bf(o6) | ((unsigned)f2bf(o7) << 16);
        *(uint4*)(zh + (size_t)w * 32 + fl * 8) = p;
    }
}

// ---- decode: bf16 rows (64B), 4 lanes/edge, 4 edges per group ---------------

__device__ inline float bfdot8(uint4 a, uint4 b) {
    const unsigned* pa = (const unsigned*)&a;
    const unsigned* pb = (const unsigned*)&b;
    float v = 0.f;
#pragma unroll
    for (int w = 0; w < 4; w++) {
        float alo = __builtin_bit_cast(float, pa[w] << 16);
        float ahi = __builtin_bit_cast(float, pa[w] & 0xFFFF0000u);
        float blo = __builtin_bit_cast(float, pb[w] << 16);
        float bhi = __builtin_bit_cast(float, pb[w] & 0xFFFF0000u);
        v += alo * blo + ahi * bhi;
    }
    return v;
}

__global__ __launch_bounds__(256) void k_decode(const unsigned short* __restrict__ zh,
                                                const int* __restrict__ src,
                                                const int* __restrict__ tgt,
                                                float* __restrict__ recon, int E) {
    int g = (blockIdx.x * 256 + threadIdx.x) >> 2;
    int fl = threadIdx.x & 3;
    int e0 = g * 4;
    if (e0 >= E) return;
    int cnt = min(4, E - e0);
    int s[4], t[4];
#pragma unroll
    for (int q = 0; q < 4; q++) {
        int e = (q < cnt) ? e0 + q : e0;
        s[q] = src[e];
        t[q] = tgt[e];
    }
    uint4 Za[4], Zb[4];
#pragma unroll
    for (int q = 0; q < 4; q++) {
        Za[q] = *(const uint4*)(zh + (size_t)s[q] * 32 + fl * 8);
        Zb[q] = *(const uint4*)(zh + (size_t)t[q] * 32 + fl * 8);
    }
    float v[4];
#pragma unroll
    for (int q = 0; q < 4; q++) {
        float x = bfdot8(Za[q], Zb[q]);
        x += __shfl_xor(x, 1);
        x += __shfl_xor(x, 2);
        v[q] = x;
    }
    if (fl == 0) {
        if (cnt == 4) {
            *(float4*)(recon + e0) = make_float4(v[0], v[1], v[2], v[3]);
        } else {
            for (int q = 0; q < cnt; q++) recon[e0 + q] = v[q];
        }
    }
}

extern "C" void kernel_launch(void* const* d_in, const int* in_sizes, int n_in,
                              void* d_out, int out_size, void* d_ws, size_t ws_size,
                              hipStream_t stream) {
    const float* x = (const float*)d_in[0];
    const float* W1 = (const float*)d_in[1];
    const float* b1 = (const float*)d_in[2];
    const float* W2 = (const float*)d_in[3];
    const float* b2 = (const float*)d_in[4];
    const int* ei = (const int*)d_in[5];

    int N = in_sizes[0] / 128;
    int E = in_sizes[5] / 2;
    const int* src = ei;
    const int* tgt = ei + E;
    int NB = divup(N, BNODES);

    char* ws = (char*)d_ws;
    size_t off = 0;
    auto alloc = [&](size_t bytes) {
        size_t r = off;
        off += (bytes + 255) & ~(size_t)255;
        return r;
    };
    int* gcur = (int*)(ws + alloc(NBMAX * 4));
    unsigned* ebuf = (unsigned*)(ws + alloc((size_t)NB * CAP * 4));
    int* col = (int*)(ws + alloc((size_t)NB * CAP * 4));
    int* rowbeg = (int*)(ws + alloc((size_t)N * 4));
    int* rowend = (int*)(ws + alloc((size_t)N * 4));
    float* dinv = (float*)(ws + alloc((size_t)N * 4));
    __half* hs = (__half*)(ws + alloc((size_t)(N + 1) * 64 * 2));   // +pad row n
    __half* h2 = (__half*)(ws + alloc((size_t)N * 64 * 2));
    __half* zs = (__half*)(ws + alloc((size_t)(N + 1) * 32 * 2));   // +pad row n
    unsigned short* zh = (unsigned short*)(ws + alloc((size_t)N * 32 * 2));

    float* zout = (float*)d_out;
    float* recon = zout + (size_t)N * 32;

    k_init<<<1, 256, 0, stream>>>(gcur, (unsigned*)(hs + (size_t)N * 64),
                                  (unsigned*)(zs + (size_t)N * 32));
    k_part<<<divup(E, CH), 256, 0, stream>>>(src, tgt, gcur, ebuf, E, NB);
    k_bfill<<<NB, BNODES, 0, stream>>>(ebuf, gcur, rowbeg, rowend, col, dinv, N);

    k_mm1<<<divup(N, 32), 256, 0, stream>>>(x, W1, dinv, hs, N);
    k_conv1<<<divup(N, 4), 256, 0, stream>>>(hs, rowbeg, rowend, col, dinv, b1, h2, N);
    k_mm2<<<divup(N, 64), 256, 0, stream>>>(h2, W2, dinv, zs, N);
    k_conv2<<<divup(N, 4), 256, 0, stream>>>(zs, rowbeg, rowend, col, dinv, b2, zout, zh, N);
    k_decode<<<divup(E, 256), 256, 0, stream>>>(zh, src, tgt, recon, E);
}

// Round 8
// 258.718 us; speedup vs baseline: 2.2525x; 1.0726x over previous
//
#include <hip/hip_runtime.h>
#include <hip/hip_fp16.h>
#include <math.h>

// GAE: 2x GCNConv + edge dot decode.
// R1: bucketed CSR build, fp16 gather tables.
// R2: wide gathers (float4/lane).
// R3-R5: unrolled gathers, fixed-capacity buckets.
// R6: fp16 packed accumulation, zero-pad row, bf16 decode.
// R7: 1 node/wave 4x-peeled gathers (conv1 <44us).
// R8: mm1/mm2 rewritten as MFMA f32_16x16x32_f16 (old mm1 was LDS-read-bound
//     fp32 vector matmul at 25% occupancy, 44.8us). fp16 inputs add ~1.4e-4.

#define NBMAX 256    // max buckets (supports N <= 131072)
#define BSHIFT 9     // 512 nodes per bucket
#define BNODES 512
#define CH 4096      // edges per partition block
#define CAPSHIFT 14  // 16384 edge slots per bucket (mean 8192 at N=100k,E=1.6M)
#define CAP (1 << CAPSHIFT)

typedef _Float16 half8 __attribute__((ext_vector_type(8)));
typedef float floatx4 __attribute__((ext_vector_type(4)));

static inline int divup(int a, int b) { return (a + b - 1) / b; }

__device__ inline void acc8(__half2* a, float4 v) {
    const __half2* h = (const __half2*)&v;
    a[0] = __hadd2(a[0], h[0]);
    a[1] = __hadd2(a[1], h[1]);
    a[2] = __hadd2(a[2], h[2]);
    a[3] = __hadd2(a[3], h[3]);
}
__device__ inline unsigned short f2bf(float f) {
    unsigned u = __builtin_bit_cast(unsigned, f);
    u = (u + 0x7FFFu + ((u >> 16) & 1u)) >> 16;
    return (unsigned short)u;
}

// ---- init bucket cursors + zero pad rows ------------------------------------

__global__ void k_init(int* __restrict__ gcur, unsigned* __restrict__ hs_pad,
                       unsigned* __restrict__ zs_pad) {
    int t = threadIdx.x;
    if (t < NBMAX) gcur[t] = t << CAPSHIFT;
    if (t < 32) hs_pad[t] = 0;            // 128B zero row (64 fp16)
    else if (t < 48) zs_pad[t - 32] = 0;  // 64B zero row (32 fp16)
}

// ---- partition edges into fixed-capacity buckets (atomic append) ------------
// packed word: (local_tgt << 23) | src   (src < 2^17, local_tgt < 512)

__global__ __launch_bounds__(256) void k_part(const int* __restrict__ src,
                                              const int* __restrict__ tgt,
                                              int* __restrict__ gcur,
                                              unsigned* __restrict__ ebuf, int E, int NB) {
    __shared__ int h[NBMAX];
    __shared__ int base[NBMAX];
    int tid = threadIdx.x;
    int e0 = blockIdx.x * CH;
    for (int b = tid; b < NB; b += 256) h[b] = 0;
    __syncthreads();
    unsigned pk[CH / 256];
    int sv[CH / 256];
#pragma unroll
    for (int r = 0; r < CH / 256; r++) {
        int e = e0 + r * 256 + tid;
        if (e < E) {
            int t = tgt[e];
            int b = t >> BSHIFT;
            int l = atomicAdd(&h[b], 1);
            pk[r] = ((unsigned)b << 21) | ((unsigned)(t & (BNODES - 1)) << 12) | (unsigned)l;
            sv[r] = src[e];
        } else {
            pk[r] = 0xFFFFFFFFu;
        }
    }
    __syncthreads();
    for (int b = tid; b < NB; b += 256) {
        int c = h[b];
        base[b] = c ? atomicAdd(&gcur[b], c) : 0;
    }
    __syncthreads();
#pragma unroll
    for (int r = 0; r < CH / 256; r++) {
        if (pk[r] != 0xFFFFFFFFu) {
            int b = pk[r] >> 21;
            unsigned lt = (pk[r] >> 12) & (BNODES - 1);
            int l = pk[r] & 4095;
            ebuf[base[b] + l] = (lt << 23) | (unsigned)sv[r];
        }
    }
}

// ---- per-bucket CSR fill: LDS count/scan/cursor -----------------------------

__global__ __launch_bounds__(512) void k_bfill(const unsigned* __restrict__ ebuf,
                                               const int* __restrict__ gcur,
                                               int* __restrict__ rowbeg,
                                               int* __restrict__ rowend,
                                               int* __restrict__ col,
                                               float* __restrict__ dinv, int n) {
    __shared__ int s_cnt[BNODES];
    __shared__ int s_scan[BNODES];
    __shared__ int s_cur[BNODES];
    int b = blockIdx.x, tid = threadIdx.x;
    int nbase = b << BSHIFT;
    int ebase = b << CAPSHIFT;
    int eend = gcur[b];
    s_cnt[tid] = 0;
    __syncthreads();
    for (int e = ebase + tid; e < eend; e += BNODES) {
        atomicAdd(&s_cnt[ebuf[e] >> 23], 1);
    }
    __syncthreads();
    s_scan[tid] = s_cnt[tid];
    __syncthreads();
    for (int off = 1; off < BNODES; off <<= 1) {
        int t = (tid >= off) ? s_scan[tid - off] : 0;
        __syncthreads();
        s_scan[tid] += t;
        __syncthreads();
    }
    int excl = s_scan[tid] - s_cnt[tid];
    s_cur[tid] = excl;
    int node = nbase + tid;
    if (node < n) {
        rowbeg[node] = ebase + excl;
        rowend[node] = ebase + excl + s_cnt[tid];
        dinv[node] = rsqrtf((float)(s_cnt[tid] + 1));  // +1 self-loop
    }
    __syncthreads();
    for (int e = ebase + tid; e < eend; e += BNODES) {
        unsigned p = ebuf[e];
        int pos = atomicAdd(&s_cur[p >> 23], 1);
        col[ebase + pos] = (int)(p & 0x7FFFFFu);
    }
}

// ---- matmul 1 (MFMA): hs[n][j] = fp16((x[n] @ W1[:,j]) * dinv[n]) -----------
// 64 nodes x 64 cols per block; fp16 LDS tiles, pitch 136 (2-way bank = free).

__global__ __launch_bounds__(256) void k_mm1(const float* __restrict__ x,
                                             const float* __restrict__ W1,
                                             const float* __restrict__ dinv,
                                             __half* __restrict__ hs, int n) {
    __shared__ _Float16 xh[64 * 136];  // [node][k]
    __shared__ _Float16 Wt[64 * 136];  // [col][k] (transposed)
    int tid = threadIdx.x;
    int nbase = blockIdx.x * 64;
    // stage x -> xh (fp32 -> fp16), 8 float4 per thread
#pragma unroll
    for (int i = 0; i < 8; i++) {
        int f = tid + i * 256;  // 0..2047
        int r = f >> 5, c4 = f & 31;
        int node = nbase + r;
        float4 v = make_float4(0.f, 0.f, 0.f, 0.f);
        if (node < n) v = *(const float4*)(x + (size_t)node * 128 + c4 * 4);
        union { uint2 u; __half2 h[2]; } pk;
        pk.h[0] = __floats2half2_rn(v.x, v.y);
        pk.h[1] = __floats2half2_rn(v.z, v.w);
        *(uint2*)&xh[r * 136 + c4 * 4] = pk.u;
    }
    // stage W1 (128x64) -> Wt[col][k] fp16
#pragma unroll
    for (int i = 0; i < 16; i++) {
        int f = tid + i * 256;          // 0..4095
        int c = f & 63, kp = f >> 6;    // kp 0..63 (pairs of k)
        float a = W1[(size_t)(2 * kp) * 64 + c];
        float b = W1[(size_t)(2 * kp + 1) * 64 + c];
        *(__half2*)&Wt[c * 136 + 2 * kp] = __floats2half2_rn(a, b);
    }
    __syncthreads();
    int w = tid >> 6, lane = tid & 63;
    int quad = lane >> 4, m = lane & 15;
    floatx4 acc[4] = {{0.f, 0.f, 0.f, 0.f}, {0.f, 0.f, 0.f, 0.f},
                      {0.f, 0.f, 0.f, 0.f}, {0.f, 0.f, 0.f, 0.f}};
#pragma unroll
    for (int kt = 0; kt < 4; kt++) {
        half8 a = *(const half8*)&xh[(w * 16 + m) * 136 + kt * 32 + quad * 8];
#pragma unroll
        for (int ct = 0; ct < 4; ct++) {
            half8 b = *(const half8*)&Wt[(ct * 16 + m) * 136 + kt * 32 + quad * 8];
            acc[ct] = __builtin_amdgcn_mfma_f32_16x16x32_f16(a, b, acc[ct], 0, 0, 0);
        }
    }
#pragma unroll
    for (int reg = 0; reg < 4; reg++) {
        int node = nbase + w * 16 + quad * 4 + reg;
        if (node < n) {
            float d = dinv[node];
#pragma unroll
            for (int ct = 0; ct < 4; ct++) {
                hs[(size_t)node * 64 + ct * 16 + m] = __float2half(acc[ct][reg] * d);
            }
        }
    }
}

// ---- conv1: 1 node/wave, 8 lanes/row, 4x peel (5 loads in flight) -----------
// hs has a zeroed pad row at index n; invalid slots load it unconditionally.

__global__ __launch_bounds__(256) void k_conv1(const __half* __restrict__ hs,
                                               const int* __restrict__ rowbeg,
                                               const int* __restrict__ rowend,
                                               const int* __restrict__ col,
                                               const float* __restrict__ dinv,
                                               const float* __restrict__ b1,
                                               __half* __restrict__ h2, int n) {
    int w = (blockIdx.x * 256 + threadIdx.x) >> 6;
    int lane = threadIdx.x & 63;
    if (w >= n) return;
    int el = lane >> 3, fl = lane & 7;
    int beg = rowbeg[w], end = rowend[w];
    int deg = end - beg;
    int m = min(64, deg);
    int sl = (lane < m) ? col[beg + lane] : 0;
    int s0 = __shfl(sl, el);
    int s1 = __shfl(sl, 8 + el);
    int s2 = __shfl(sl, 16 + el);
    int s3 = __shfl(sl, 24 + el);
    int r0 = (el < m) ? s0 : n;
    int r1 = (8 + el < m) ? s1 : n;
    int r2 = (16 + el < m) ? s2 : n;
    int r3 = (24 + el < m) ? s3 : n;
    int rs = (el == 0) ? w : n;
    float4 S = *(const float4*)(hs + (size_t)rs * 64 + fl * 8);
    float4 A = *(const float4*)(hs + (size_t)r0 * 64 + fl * 8);
    float4 B = *(const float4*)(hs + (size_t)r1 * 64 + fl * 8);
    float4 C = *(const float4*)(hs + (size_t)r2 * 64 + fl * 8);
    float4 D = *(const float4*)(hs + (size_t)r3 * 64 + fl * 8);
    __half2 a2[4];
#pragma unroll
    for (int j = 0; j < 4; j++) a2[j] = __half2half2(__float2half(0.f));
    acc8(a2, S);
    acc8(a2, A);
    acc8(a2, B);
    acc8(a2, C);
    acc8(a2, D);
    if (deg > 32) {  // rare (Poisson mean 16), wave-uniform
        for (int i = 32; i < m; i += 8) {
            int idx = i + el;
            int s = __shfl(sl, idx & 63);
            int a = (idx < m) ? s : n;
            float4 v = *(const float4*)(hs + (size_t)a * 64 + fl * 8);
            acc8(a2, v);
        }
        for (int e0 = beg + 64; e0 < end; e0 += 64) {
            int mc = min(64, end - e0);
            int sl2 = (lane < mc) ? col[e0 + lane] : 0;
            for (int i = 0; i < mc; i += 8) {
                int idx = i + el;
                int s = __shfl(sl2, idx & 63);
                int a = (idx < mc) ? s : n;
                float4 v = *(const float4*)(hs + (size_t)a * 64 + fl * 8);
                acc8(a2, v);
            }
        }
    }
    // fp32 reduction tree over the 8 el groups
    float r[8];
#pragma unroll
    for (int j = 0; j < 4; j++) {
        float2 f = __half22float2(a2[j]);
        r[2 * j] = f.x;
        r[2 * j + 1] = f.y;
    }
    for (int d = 8; d < 64; d <<= 1)
#pragma unroll
        for (int j = 0; j < 8; j++) r[j] += __shfl_xor(r[j], d);

    if (el == 0) {
        float d = dinv[w];
        float4 bb0 = *(const float4*)(b1 + fl * 8);
        float4 bb1 = *(const float4*)(b1 + fl * 8 + 4);
        union { float4 f; __half2 h[4]; } u;
        u.h[0] = __floats2half2_rn(fmaxf(r[0] * d + bb0.x, 0.f),
                                   fmaxf(r[1] * d + bb0.y, 0.f));
        u.h[1] = __floats2half2_rn(fmaxf(r[2] * d + bb0.z, 0.f),
                                   fmaxf(r[3] * d + bb0.w, 0.f));
        u.h[2] = __floats2half2_rn(fmaxf(r[4] * d + bb1.x, 0.f),
                                   fmaxf(r[5] * d + bb1.y, 0.f));
        u.h[3] = __floats2half2_rn(fmaxf(r[6] * d + bb1.z, 0.f),
                                   fmaxf(r[7] * d + bb1.w, 0.f));
        *(float4*)(h2 + (size_t)w * 64 + fl * 8) = u.f;
    }
}

// ---- matmul 2 (MFMA): zs[n][c] = fp16((h2[n] @ W2[:,c]) * dinv[n]) ----------
// 64 nodes per block; A-fragments straight from global h2 (fp16, 16B aligned).

__global__ __launch_bounds__(256) void k_mm2(const __half* __restrict__ h2,
                                             const float* __restrict__ W2,
                                             const float* __restrict__ dinv,
                                             __half* __restrict__ zs, int n) {
    __shared__ _Float16 Wt[32 * 72];  // [col][k] (transposed)
    int tid = threadIdx.x;
    int nbase = blockIdx.x * 64;
#pragma unroll
    for (int i = 0; i < 4; i++) {
        int f = tid + i * 256;          // 0..1023
        int c = f & 31, kp = f >> 5;    // kp 0..31
        float a = W2[(size_t)(2 * kp) * 32 + c];
        float b = W2[(size_t)(2 * kp + 1) * 32 + c];
        *(__half2*)&Wt[c * 72 + 2 * kp] = __floats2half2_rn(a, b);
    }
    __syncthreads();
    int w = tid >> 6, lane = tid & 63;
    int quad = lane >> 4, m = lane & 15;
    int arow = nbase + w * 16 + m;
    const __half* abase = h2 + (size_t)min(arow, n - 1) * 64;  // clamped rows
    floatx4 acc[2] = {{0.f, 0.f, 0.f, 0.f}, {0.f, 0.f, 0.f, 0.f}};
#pragma unroll
    for (int kt = 0; kt < 2; kt++) {
        half8 a = *(const half8*)(abase + kt * 32 + quad * 8);
#pragma unroll
        for (int ct = 0; ct < 2; ct++) {
            half8 b = *(const half8*)&Wt[(ct * 16 + m) * 72 + kt * 32 + quad * 8];
            acc[ct] = __builtin_amdgcn_mfma_f32_16x16x32_f16(a, b, acc[ct], 0, 0, 0);
        }
    }
#pragma unroll
    for (int reg = 0; reg < 4; reg++) {
        int node = nbase + w * 16 + quad * 4 + reg;
        if (node < n) {
            float d = dinv[node];
#pragma unroll
            for (int ct = 0; ct < 2; ct++) {
                zs[(size_t)node * 32 + ct * 16 + m] = __float2half(acc[ct][reg] * d);
            }
        }
    }
}

// ---- conv2: 1 node/wave, 4 lanes/row (16B), 16 rows/instr, peel -------------
// zs has a zeroed pad row at index n. bf16 zh epilogue for decode.

__global__ __launch_bounds__(256) void k_conv2(const __half* __restrict__ zs,
                                               const int* __restrict__ rowbeg,
                                               const int* __restrict__ rowend,
                                               const int* __restrict__ col,
                                               const float* __restrict__ dinv,
                                               const float* __restrict__ b2,
                                               float* __restrict__ zout,
                                               unsigned short* __restrict__ zh, int n) {
    int w = (blockIdx.x * 256 + threadIdx.x) >> 6;
    int lane = threadIdx.x & 63;
    if (w >= n) return;
    int el = lane >> 2, fl = lane & 3;  // 16 el groups x 4 lanes
    int beg = rowbeg[w], end = rowend[w];
    int deg = end - beg;
    int m = min(64, deg);
    int sl = (lane < m) ? col[beg + lane] : 0;
    int s0 = __shfl(sl, el);
    int s1 = __shfl(sl, 16 + el);
    int r0 = (el < m) ? s0 : n;
    int r1 = (16 + el < m) ? s1 : n;
    int rs = (el == 0) ? w : n;
    float4 S = *(const float4*)(zs + (size_t)rs * 32 + fl * 8);
    float4 A = *(const float4*)(zs + (size_t)r0 * 32 + fl * 8);
    float4 B = *(const float4*)(zs + (size_t)r1 * 32 + fl * 8);
    __half2 a2[4];
#pragma unroll
    for (int j = 0; j < 4; j++) a2[j] = __half2half2(__float2half(0.f));
    acc8(a2, S);
    acc8(a2, A);
    acc8(a2, B);
    if (deg > 32) {  // wave-uniform
        int s2 = __shfl(sl, 32 + el);
        int s3 = __shfl(sl, 48 + el);
        int r2 = (32 + el < m) ? s2 : n;
        int r3 = (48 + el < m) ? s3 : n;
        float4 C = *(const float4*)(zs + (size_t)r2 * 32 + fl * 8);
        float4 D = *(const float4*)(zs + (size_t)r3 * 32 + fl * 8);
        acc8(a2, C);
        acc8(a2, D);
        for (int e0 = beg + 64; e0 < end; e0 += 64) {
            int mc = min(64, end - e0);
            int sl2 = (lane < mc) ? col[e0 + lane] : 0;
            for (int i = 0; i < mc; i += 16) {
                int idx = i + el;
                int s = __shfl(sl2, idx & 63);
                int a = (idx < mc) ? s : n;
                float4 v = *(const float4*)(zs + (size_t)a * 32 + fl * 8);
                acc8(a2, v);
            }
        }
    }
    // fp32 reduction tree over the 16 el groups
    float r[8];
#pragma unroll
    for (int j = 0; j < 4; j++) {
        float2 f = __half22float2(a2[j]);
        r[2 * j] = f.x;
        r[2 * j + 1] = f.y;
    }
    for (int d = 4; d < 64; d <<= 1)
#pragma unroll
        for (int j = 0; j < 8; j++) r[j] += __shfl_xor(r[j], d);

    if (el == 0) {  // lanes 0-3 each hold feats fl*8..fl*8+7
        float d = dinv[w];
        float4 bb0 = *(const float4*)(b2 + fl * 8);
        float4 bb1 = *(const float4*)(b2 + fl * 8 + 4);
        float o0 = r[0] * d + bb0.x, o1 = r[1] * d + bb0.y;
        float o2 = r[2] * d + bb0.z, o3 = r[3] * d + bb0.w;
        float o4 = r[4] * d + bb1.x, o5 = r[5] * d + bb1.y;
        float o6 = r[6] * d + bb1.z, o7 = r[7] * d + bb1.w;
        *(float4*)(zout + (size_t)w * 32 + fl * 8) = make_float4(o0, o1, o2, o3);
        *(float4*)(zout + (size_t)w * 32 + fl * 8 + 4) = make_float4(o4, o5, o6, o7);
        uint4 p;
        p.x = (unsigned)f2bf(o0) | ((unsigned)f2bf(o1) << 16);
        p.y = (unsigned)f2bf(o2) | ((unsigned)f2bf(o3) << 16);
        p.z = (unsigned)f2bf(o4) | ((unsigned)f2bf(o5) << 16);
        p.w = (unsigned)f2bf(o6) | ((unsigned)f2bf(o7) << 16);
        *(uint4*)(zh + (size_t)w * 32 + fl * 8) = p;
    }
}

// ---- decode: bf16 rows (64B), 4 lanes/edge, 4 edges per group ---------------

__device__ inline float bfdot8(uint4 a, uint4 b) {
    const unsigned* pa = (const unsigned*)&a;
    const unsigned* pb = (const unsigned*)&b;
    float v = 0.f;
#pragma unroll
    for (int w = 0; w < 4; w++) {
        float alo = __builtin_bit_cast(float, pa[w] << 16);
        float ahi = __builtin_bit_cast(float, pa[w] & 0xFFFF0000u);
        float blo = __builtin_bit_cast(float, pb[w] << 16);
        float bhi = __builtin_bit_cast(float, pb[w] & 0xFFFF0000u);
        v += alo * blo + ahi * bhi;
    }
    return v;
}

__global__ __launch_bounds__(256) void k_decode(const unsigned short* __restrict__ zh,
                                                const int* __restrict__ src,
                                                const int* __restrict__ tgt,
                                                float* __restrict__ recon, int E) {
    int g = (blockIdx.x * 256 + threadIdx.x) >> 2;
    int fl = threadIdx.x & 3;
    int e0 = g * 4;
    if (e0 >= E) return;
    int cnt = min(4, E - e0);
    int s[4], t[4];
#pragma unroll
    for (int q = 0; q < 4; q++) {
        int e = (q < cnt) ? e0 + q : e0;
        s[q] = src[e];
        t[q] = tgt[e];
    }
    uint4 Za[4], Zb[4];
#pragma unroll
    for (int q = 0; q < 4; q++) {
        Za[q] = *(const uint4*)(zh + (size_t)s[q] * 32 + fl * 8);
        Zb[q] = *(const uint4*)(zh + (size_t)t[q] * 32 + fl * 8);
    }
    float v[4];
#pragma unroll
    for (int q = 0; q < 4; q++) {
        float x = bfdot8(Za[q], Zb[q]);
        x += __shfl_xor(x, 1);
        x += __shfl_xor(x, 2);
        v[q] = x;
    }
    if (fl == 0) {
        if (cnt == 4) {
            *(float4*)(recon + e0) = make_float4(v[0], v[1], v[2], v[3]);
        } else {
            for (int q = 0; q < cnt; q++) recon[e0 + q] = v[q];
        }
    }
}

extern "C" void kernel_launch(void* const* d_in, const int* in_sizes, int n_in,
                              void* d_out, int out_size, void* d_ws, size_t ws_size,
                              hipStream_t stream) {
    const float* x = (const float*)d_in[0];
    const float* W1 = (const float*)d_in[1];
    const float* b1 = (const float*)d_in[2];
    const float* W2 = (const float*)d_in[3];
    const float* b2 = (const float*)d_in[4];
    const int* ei = (const int*)d_in[5];

    int N = in_sizes[0] / 128;
    int E = in_sizes[5] / 2;
    const int* src = ei;
    const int* tgt = ei + E;
    int NB = divup(N, BNODES);

    char* ws = (char*)d_ws;
    size_t off = 0;
    auto alloc = [&](size_t bytes) {
        size_t r = off;
        off += (bytes + 255) & ~(size_t)255;
        return r;
    };
    int* gcur = (int*)(ws + alloc(NBMAX * 4));
    unsigned* ebuf = (unsigned*)(ws + alloc((size_t)NB * CAP * 4));
    int* col = (int*)(ws + alloc((size_t)NB * CAP * 4));
    int* rowbeg = (int*)(ws + alloc((size_t)N * 4));
    int* rowend = (int*)(ws + alloc((size_t)N * 4));
    float* dinv = (float*)(ws + alloc((size_t)N * 4));
    __half* hs = (__half*)(ws + alloc((size_t)(N + 1) * 64 * 2));   // +pad row n
    __half* h2 = (__half*)(ws + alloc((size_t)N * 64 * 2));
    __half* zs = (__half*)(ws + alloc((size_t)(N + 1) * 32 * 2));   // +pad row n
    unsigned short* zh = (unsigned short*)(ws + alloc((size_t)N * 32 * 2));

    float* zout = (float*)d_out;
    float* recon = zout + (size_t)N * 32;

    k_init<<<1, 256, 0, stream>>>(gcur, (unsigned*)(hs + (size_t)N * 64),
                                  (unsigned*)(zs + (size_t)N * 32));
    k_part<<<divup(E, CH), 256, 0, stream>>>(src, tgt, gcur, ebuf, E, NB);
    k_bfill<<<NB, BNODES, 0, stream>>>(ebuf, gcur, rowbeg, rowend, col, dinv, N);

    k_mm1<<<divup(N, 64), 256, 0, stream>>>(x, W1, dinv, hs, N);
    k_conv1<<<divup(N, 4), 256, 0, stream>>>(hs, rowbeg, rowend, col, dinv, b1, h2, N);
    k_mm2<<<divup(N, 64), 256, 0, stream>>>(h2, W2, dinv, zs, N);
    k_conv2<<<divup(N, 4), 256, 0, stream>>>(zs, rowbeg, rowend, col, dinv, b2, zout, zh, N);
    k_decode<<<divup(E, 256), 256, 0, stream>>>(zh, src, tgt, recon, E);
}

// Round 9
// 233.789 us; speedup vs baseline: 2.4927x; 1.1066x over previous
//
#include <hip/hip_runtime.h>
#include <hip/hip_fp16.h>
#include <math.h>

// GAE: 2x GCNConv + edge dot decode.
// R1: bucketed CSR build, fp16 gather tables.
// R2: wide gathers (float4/lane).
// R3-R5: unrolled gathers, fixed-capacity buckets.
// R6: fp16 packed accumulation, zero-pad row, bf16 decode.
// R7: 1 node/wave 4x-peeled gathers.
// R8: mm1/mm2 as MFMA f32_16x16x32_f16.
// R9: convs are wave-throughput-bound (100k waves x ~5800cyc latency each;
//     fabric far from limit) -> 2 nodes per wave as independent 32-lane
//     halves: wave count halves, per-wave overhead amortized, shorter
//     reduction trees, 2x MLP. VGPR stays low (lane-partition, not R6's
//     register-multiplying batch).

#define NBMAX 256    // max buckets (supports N <= 131072)
#define BSHIFT 9     // 512 nodes per bucket
#define BNODES 512
#define CH 4096      // edges per partition block
#define CAPSHIFT 14  // 16384 edge slots per bucket (mean 8192 at N=100k,E=1.6M)
#define CAP (1 << CAPSHIFT)

typedef _Float16 half8 __attribute__((ext_vector_type(8)));
typedef float floatx4 __attribute__((ext_vector_type(4)));

static inline int divup(int a, int b) { return (a + b - 1) / b; }

__device__ inline void acc8(__half2* a, float4 v) {
    const __half2* h = (const __half2*)&v;
    a[0] = __hadd2(a[0], h[0]);
    a[1] = __hadd2(a[1], h[1]);
    a[2] = __hadd2(a[2], h[2]);
    a[3] = __hadd2(a[3], h[3]);
}
__device__ inline unsigned short f2bf(float f) {
    unsigned u = __builtin_bit_cast(unsigned, f);
    u = (u + 0x7FFFu + ((u >> 16) & 1u)) >> 16;
    return (unsigned short)u;
}

// ---- init bucket cursors + zero pad rows ------------------------------------

__global__ void k_init(int* __restrict__ gcur, unsigned* __restrict__ hs_pad,
                       unsigned* __restrict__ zs_pad) {
    int t = threadIdx.x;
    if (t < NBMAX) gcur[t] = t << CAPSHIFT;
    if (t < 32) hs_pad[t] = 0;            // 128B zero row (64 fp16)
    else if (t < 48) zs_pad[t - 32] = 0;  // 64B zero row (32 fp16)
}

// ---- partition edges into fixed-capacity buckets (atomic append) ------------
// packed word: (local_tgt << 23) | src   (src < 2^17, local_tgt < 512)

__global__ __launch_bounds__(256) void k_part(const int* __restrict__ src,
                                              const int* __restrict__ tgt,
                                              int* __restrict__ gcur,
                                              unsigned* __restrict__ ebuf, int E, int NB) {
    __shared__ int h[NBMAX];
    __shared__ int base[NBMAX];
    int tid = threadIdx.x;
    int e0 = blockIdx.x * CH;
    for (int b = tid; b < NB; b += 256) h[b] = 0;
    __syncthreads();
    unsigned pk[CH / 256];
    int sv[CH / 256];
#pragma unroll
    for (int r = 0; r < CH / 256; r++) {
        int e = e0 + r * 256 + tid;
        if (e < E) {
            int t = tgt[e];
            int b = t >> BSHIFT;
            int l = atomicAdd(&h[b], 1);
            pk[r] = ((unsigned)b << 21) | ((unsigned)(t & (BNODES - 1)) << 12) | (unsigned)l;
            sv[r] = src[e];
        } else {
            pk[r] = 0xFFFFFFFFu;
        }
    }
    __syncthreads();
    for (int b = tid; b < NB; b += 256) {
        int c = h[b];
        base[b] = c ? atomicAdd(&gcur[b], c) : 0;
    }
    __syncthreads();
#pragma unroll
    for (int r = 0; r < CH / 256; r++) {
        if (pk[r] != 0xFFFFFFFFu) {
            int b = pk[r] >> 21;
            unsigned lt = (pk[r] >> 12) & (BNODES - 1);
            int l = pk[r] & 4095;
            ebuf[base[b] + l] = (lt << 23) | (unsigned)sv[r];
        }
    }
}

// ---- per-bucket CSR fill: LDS count/scan/cursor -----------------------------

__global__ __launch_bounds__(512) void k_bfill(const unsigned* __restrict__ ebuf,
                                               const int* __restrict__ gcur,
                                               int* __restrict__ rowbeg,
                                               int* __restrict__ rowend,
                                               int* __restrict__ col,
                                               float* __restrict__ dinv, int n) {
    __shared__ int s_cnt[BNODES];
    __shared__ int s_scan[BNODES];
    __shared__ int s_cur[BNODES];
    int b = blockIdx.x, tid = threadIdx.x;
    int nbase = b << BSHIFT;
    int ebase = b << CAPSHIFT;
    int eend = gcur[b];
    s_cnt[tid] = 0;
    __syncthreads();
    for (int e = ebase + tid; e < eend; e += BNODES) {
        atomicAdd(&s_cnt[ebuf[e] >> 23], 1);
    }
    __syncthreads();
    s_scan[tid] = s_cnt[tid];
    __syncthreads();
    for (int off = 1; off < BNODES; off <<= 1) {
        int t = (tid >= off) ? s_scan[tid - off] : 0;
        __syncthreads();
        s_scan[tid] += t;
        __syncthreads();
    }
    int excl = s_scan[tid] - s_cnt[tid];
    s_cur[tid] = excl;
    int node = nbase + tid;
    if (node < n) {
        rowbeg[node] = ebase + excl;
        rowend[node] = ebase + excl + s_cnt[tid];
        dinv[node] = rsqrtf((float)(s_cnt[tid] + 1));  // +1 self-loop
    }
    __syncthreads();
    for (int e = ebase + tid; e < eend; e += BNODES) {
        unsigned p = ebuf[e];
        int pos = atomicAdd(&s_cur[p >> 23], 1);
        col[ebase + pos] = (int)(p & 0x7FFFFFu);
    }
}

// ---- matmul 1 (MFMA): hs[n][j] = fp16((x[n] @ W1[:,j]) * dinv[n]) -----------
// 64 nodes x 64 cols per block; fp16 LDS tiles, pitch 136 (2-way bank = free).

__global__ __launch_bounds__(256) void k_mm1(const float* __restrict__ x,
                                             const float* __restrict__ W1,
                                             const float* __restrict__ dinv,
                                             __half* __restrict__ hs, int n) {
    __shared__ _Float16 xh[64 * 136];  // [node][k]
    __shared__ _Float16 Wt[64 * 136];  // [col][k] (transposed)
    int tid = threadIdx.x;
    int nbase = blockIdx.x * 64;
    // stage x -> xh (fp32 -> fp16), 8 float4 per thread
#pragma unroll
    for (int i = 0; i < 8; i++) {
        int f = tid + i * 256;  // 0..2047
        int r = f >> 5, c4 = f & 31;
        int node = nbase + r;
        float4 v = make_float4(0.f, 0.f, 0.f, 0.f);
        if (node < n) v = *(const float4*)(x + (size_t)node * 128 + c4 * 4);
        union { uint2 u; __half2 h[2]; } pk;
        pk.h[0] = __floats2half2_rn(v.x, v.y);
        pk.h[1] = __floats2half2_rn(v.z, v.w);
        *(uint2*)&xh[r * 136 + c4 * 4] = pk.u;
    }
    // stage W1 (128x64) -> Wt[col][k] fp16
#pragma unroll
    for (int i = 0; i < 16; i++) {
        int f = tid + i * 256;          // 0..4095
        int c = f & 63, kp = f >> 6;    // kp 0..63 (pairs of k)
        float a = W1[(size_t)(2 * kp) * 64 + c];
        float b = W1[(size_t)(2 * kp + 1) * 64 + c];
        *(__half2*)&Wt[c * 136 + 2 * kp] = __floats2half2_rn(a, b);
    }
    __syncthreads();
    int w = tid >> 6, lane = tid & 63;
    int quad = lane >> 4, m = lane & 15;
    floatx4 acc[4] = {{0.f, 0.f, 0.f, 0.f}, {0.f, 0.f, 0.f, 0.f},
                      {0.f, 0.f, 0.f, 0.f}, {0.f, 0.f, 0.f, 0.f}};
#pragma unroll
    for (int kt = 0; kt < 4; kt++) {
        half8 a = *(const half8*)&xh[(w * 16 + m) * 136 + kt * 32 + quad * 8];
#pragma unroll
        for (int ct = 0; ct < 4; ct++) {
            half8 b = *(const half8*)&Wt[(ct * 16 + m) * 136 + kt * 32 + quad * 8];
            acc[ct] = __builtin_amdgcn_mfma_f32_16x16x32_f16(a, b, acc[ct], 0, 0, 0);
        }
    }
#pragma unroll
    for (int reg = 0; reg < 4; reg++) {
        int node = nbase + w * 16 + quad * 4 + reg;
        if (node < n) {
            float d = dinv[node];
#pragma unroll
            for (int ct = 0; ct < 4; ct++) {
                hs[(size_t)node * 64 + ct * 16 + m] = __float2half(acc[ct][reg] * d);
            }
        }
    }
}

// ---- conv1: 2 nodes/wave (32-lane halves), 8 lanes/row, peel ----------------
// hs has a zeroed pad row at index n; invalid slots load it unconditionally.

__global__ __launch_bounds__(256) void k_conv1(const __half* __restrict__ hs,
                                               const int* __restrict__ rowbeg,
                                               const int* __restrict__ rowend,
                                               const int* __restrict__ col,
                                               const float* __restrict__ dinv,
                                               const float* __restrict__ b1,
                                               __half* __restrict__ h2, int n) {
    int gw = (blockIdx.x * 256 + threadIdx.x) >> 6;
    int lane = threadIdx.x & 63;
    int half = lane >> 5, ln = lane & 31;
    int w = gw * 2 + half;
    if (w >= n) return;  // whole half exits together; shfls stay intra-half
    int hbase = half << 5;
    int el = ln >> 3, fl = ln & 7;  // 4 el groups x 8 feat lanes
    int beg = rowbeg[w], end = rowend[w];
    int deg = end - beg;
    int m = min(32, deg);
    int sl = (ln < m) ? col[beg + ln] : 0;
    int s0 = __shfl(sl, hbase + el);
    int s1 = __shfl(sl, hbase + 4 + el);
    int s2 = __shfl(sl, hbase + 8 + el);
    int s3 = __shfl(sl, hbase + 12 + el);
    int r0 = (el < m) ? s0 : n;
    int r1 = (4 + el < m) ? s1 : n;
    int r2 = (8 + el < m) ? s2 : n;
    int r3 = (12 + el < m) ? s3 : n;
    int rs = (el == 0) ? w : n;
    float4 S = *(const float4*)(hs + (size_t)rs * 64 + fl * 8);
    float4 A = *(const float4*)(hs + (size_t)r0 * 64 + fl * 8);
    float4 B = *(const float4*)(hs + (size_t)r1 * 64 + fl * 8);
    float4 C = *(const float4*)(hs + (size_t)r2 * 64 + fl * 8);
    float4 D = *(const float4*)(hs + (size_t)r3 * 64 + fl * 8);
    __half2 a2[4];
#pragma unroll
    for (int j = 0; j < 4; j++) a2[j] = __half2half2(__float2half(0.f));
    acc8(a2, S);
    acc8(a2, A);
    acc8(a2, B);
    acc8(a2, C);
    acc8(a2, D);
    if (deg > 16) {  // ~46% of halves (Poisson 16)
        int t0 = __shfl(sl, hbase + 16 + el);
        int t1 = __shfl(sl, hbase + 20 + el);
        int t2 = __shfl(sl, hbase + 24 + el);
        int t3 = __shfl(sl, hbase + 28 + el);
        int q0 = (16 + el < m) ? t0 : n;
        int q1 = (20 + el < m) ? t1 : n;
        int q2 = (24 + el < m) ? t2 : n;
        int q3 = (28 + el < m) ? t3 : n;
        float4 E0 = *(const float4*)(hs + (size_t)q0 * 64 + fl * 8);
        float4 E1 = *(const float4*)(hs + (size_t)q1 * 64 + fl * 8);
        float4 E2 = *(const float4*)(hs + (size_t)q2 * 64 + fl * 8);
        float4 E3 = *(const float4*)(hs + (size_t)q3 * 64 + fl * 8);
        acc8(a2, E0);
        acc8(a2, E1);
        acc8(a2, E2);
        acc8(a2, E3);
    }
    if (deg > 32) {  // rare (~0.01%)
        for (int b0 = 32; b0 < deg; b0 += 32) {
            int mc = min(32, deg - b0);
            int sl2 = (ln < mc) ? col[beg + b0 + ln] : 0;
            for (int i = 0; i < mc; i += 4) {
                int idx = i + el;
                int s = __shfl(sl2, hbase + (idx & 31));
                int a = (idx < mc) ? s : n;
                float4 v = *(const float4*)(hs + (size_t)a * 64 + fl * 8);
                acc8(a2, v);
            }
        }
    }
    // fp32 reduction over the 4 el groups (intra-half: d=8,16)
    float r[8];
#pragma unroll
    for (int j = 0; j < 4; j++) {
        float2 f = __half22float2(a2[j]);
        r[2 * j] = f.x;
        r[2 * j + 1] = f.y;
    }
#pragma unroll
    for (int d = 8; d < 32; d <<= 1)
#pragma unroll
        for (int j = 0; j < 8; j++) r[j] += __shfl_xor(r[j], d);

    if (el == 0) {
        float d = dinv[w];
        float4 bb0 = *(const float4*)(b1 + fl * 8);
        float4 bb1 = *(const float4*)(b1 + fl * 8 + 4);
        union { float4 f; __half2 h[4]; } u;
        u.h[0] = __floats2half2_rn(fmaxf(r[0] * d + bb0.x, 0.f),
                                   fmaxf(r[1] * d + bb0.y, 0.f));
        u.h[1] = __floats2half2_rn(fmaxf(r[2] * d + bb0.z, 0.f),
                                   fmaxf(r[3] * d + bb0.w, 0.f));
        u.h[2] = __floats2half2_rn(fmaxf(r[4] * d + bb1.x, 0.f),
                                   fmaxf(r[5] * d + bb1.y, 0.f));
        u.h[3] = __floats2half2_rn(fmaxf(r[6] * d + bb1.z, 0.f),
                                   fmaxf(r[7] * d + bb1.w, 0.f));
        *(float4*)(h2 + (size_t)w * 64 + fl * 8) = u.f;
    }
}

// ---- matmul 2 (MFMA): zs[n][c] = fp16((h2[n] @ W2[:,c]) * dinv[n]) ----------
// 64 nodes per block; A-fragments straight from global h2 (fp16, 16B aligned).

__global__ __launch_bounds__(256) void k_mm2(const __half* __restrict__ h2,
                                             const float* __restrict__ W2,
                                             const float* __restrict__ dinv,
                                             __half* __restrict__ zs, int n) {
    __shared__ _Float16 Wt[32 * 72];  // [col][k] (transposed)
    int tid = threadIdx.x;
    int nbase = blockIdx.x * 64;
#pragma unroll
    for (int i = 0; i < 4; i++) {
        int f = tid + i * 256;          // 0..1023
        int c = f & 31, kp = f >> 5;    // kp 0..31
        float a = W2[(size_t)(2 * kp) * 32 + c];
        float b = W2[(size_t)(2 * kp + 1) * 32 + c];
        *(__half2*)&Wt[c * 72 + 2 * kp] = __floats2half2_rn(a, b);
    }
    __syncthreads();
    int w = tid >> 6, lane = tid & 63;
    int quad = lane >> 4, m = lane & 15;
    int arow = nbase + w * 16 + m;
    const __half* abase = h2 + (size_t)min(arow, n - 1) * 64;  // clamped rows
    floatx4 acc[2] = {{0.f, 0.f, 0.f, 0.f}, {0.f, 0.f, 0.f, 0.f}};
#pragma unroll
    for (int kt = 0; kt < 2; kt++) {
        half8 a = *(const half8*)(abase + kt * 32 + quad * 8);
#pragma unroll
        for (int ct = 0; ct < 2; ct++) {
            half8 b = *(const half8*)&Wt[(ct * 16 + m) * 72 + kt * 32 + quad * 8];
            acc[ct] = __builtin_amdgcn_mfma_f32_16x16x32_f16(a, b, acc[ct], 0, 0, 0);
        }
    }
#pragma unroll
    for (int reg = 0; reg < 4; reg++) {
        int node = nbase + w * 16 + quad * 4 + reg;
        if (node < n) {
            float d = dinv[node];
#pragma unroll
            for (int ct = 0; ct < 2; ct++) {
                zs[(size_t)node * 32 + ct * 16 + m] = __float2half(acc[ct][reg] * d);
            }
        }
    }
}

// ---- conv2: 2 nodes/wave (32-lane halves), 4 lanes/row, peel ----------------
// zs has a zeroed pad row at index n. bf16 zh epilogue for decode.

__global__ __launch_bounds__(256) void k_conv2(const __half* __restrict__ zs,
                                               const int* __restrict__ rowbeg,
                                               const int* __restrict__ rowend,
                                               const int* __restrict__ col,
                                               const float* __restrict__ dinv,
                                               const float* __restrict__ b2,
                                               float* __restrict__ zout,
                                               unsigned short* __restrict__ zh, int n) {
    int gw = (blockIdx.x * 256 + threadIdx.x) >> 6;
    int lane = threadIdx.x & 63;
    int half = lane >> 5, ln = lane & 31;
    int w = gw * 2 + half;
    if (w >= n) return;
    int hbase = half << 5;
    int el = ln >> 2, fl = ln & 3;  // 8 el groups x 4 feat lanes
    int beg = rowbeg[w], end = rowend[w];
    int deg = end - beg;
    int m = min(32, deg);
    int sl = (ln < m) ? col[beg + ln] : 0;
    int s0 = __shfl(sl, hbase + el);
    int s1 = __shfl(sl, hbase + 8 + el);
    int r0 = (el < m) ? s0 : n;
    int r1 = (8 + el < m) ? s1 : n;
    int rs = (el == 0) ? w : n;
    float4 S = *(const float4*)(zs + (size_t)rs * 32 + fl * 8);
    float4 A = *(const float4*)(zs + (size_t)r0 * 32 + fl * 8);
    float4 B = *(const float4*)(zs + (size_t)r1 * 32 + fl * 8);
    __half2 a2[4];
#pragma unroll
    for (int j = 0; j < 4; j++) a2[j] = __half2half2(__float2half(0.f));
    acc8(a2, S);
    acc8(a2, A);
    acc8(a2, B);
    if (deg > 16) {  // ~46% of halves
        int s2 = __shfl(sl, hbase + 16 + el);
        int s3 = __shfl(sl, hbase + 24 + el);
        int r2 = (16 + el < m) ? s2 : n;
        int r3 = (24 + el < m) ? s3 : n;
        float4 C = *(const float4*)(zs + (size_t)r2 * 32 + fl * 8);
        float4 D = *(const float4*)(zs + (size_t)r3 * 32 + fl * 8);
        acc8(a2, C);
        acc8(a2, D);
    }
    if (deg > 32) {  // rare
        for (int b0 = 32; b0 < deg; b0 += 32) {
            int mc = min(32, deg - b0);
            int sl2 = (ln < mc) ? col[beg + b0 + ln] : 0;
            for (int i = 0; i < mc; i += 8) {
                int idx = i + el;
                int s = __shfl(sl2, hbase + (idx & 31));
                int a = (idx < mc) ? s : n;
                float4 v = *(const float4*)(zs + (size_t)a * 32 + fl * 8);
                acc8(a2, v);
            }
        }
    }
    // fp32 reduction over the 8 el groups (intra-half: d=4,8,16)
    float r[8];
#pragma unroll
    for (int j = 0; j < 4; j++) {
        float2 f = __half22float2(a2[j]);
        r[2 * j] = f.x;
        r[2 * j + 1] = f.y;
    }
#pragma unroll
    for (int d = 4; d < 32; d <<= 1)
#pragma unroll
        for (int j = 0; j < 8; j++) r[j] += __shfl_xor(r[j], d);

    if (el == 0) {  // lanes fl=0..3 of each half, 8 feats each
        float d = dinv[w];
        float4 bb0 = *(const float4*)(b2 + fl * 8);
        float4 bb1 = *(const float4*)(b2 + fl * 8 + 4);
        float o0 = r[0] * d + bb0.x, o1 = r[1] * d + bb0.y;
        float o2 = r[2] * d + bb0.z, o3 = r[3] * d + bb0.w;
        float o4 = r[4] * d + bb1.x, o5 = r[5] * d + bb1.y;
        float o6 = r[6] * d + bb1.z, o7 = r[7] * d + bb1.w;
        *(float4*)(zout + (size_t)w * 32 + fl * 8) = make_float4(o0, o1, o2, o3);
        *(float4*)(zout + (size_t)w * 32 + fl * 8 + 4) = make_float4(o4, o5, o6, o7);
        uint4 p;
        p.x = (unsigned)f2bf(o0) | ((unsigned)f2bf(o1) << 16);
        p.y = (unsigned)f2bf(o2) | ((unsigned)f2bf(o3) << 16);
        p.z = (unsigned)f2bf(o4) | ((unsigned)f2bf(o5) << 16);
        p.w = (unsigned)f2bf(o6) | ((unsigned)f2bf(o7) << 16);
        *(uint4*)(zh + (size_t)w * 32 + fl * 8) = p;
    }
}

// ---- decode: bf16 rows (64B), 4 lanes/edge, 4 edges per group ---------------

__device__ inline float bfdot8(uint4 a, uint4 b) {
    const unsigned* pa = (const unsigned*)&a;
    const unsigned* pb = (const unsigned*)&b;
    float v = 0.f;
#pragma unroll
    for (int w = 0; w < 4; w++) {
        float alo = __builtin_bit_cast(float, pa[w] << 16);
        float ahi = __builtin_bit_cast(float, pa[w] & 0xFFFF0000u);
        float blo = __builtin_bit_cast(float, pb[w] << 16);
        float bhi = __builtin_bit_cast(float, pb[w] & 0xFFFF0000u);
        v += alo * blo + ahi * bhi;
    }
    return v;
}

__global__ __launch_bounds__(256) void k_decode(const unsigned short* __restrict__ zh,
                                                const int* __restrict__ src,
                                                const int* __restrict__ tgt,
                                                float* __restrict__ recon, int E) {
    int g = (blockIdx.x * 256 + threadIdx.x) >> 2;
    int fl = threadIdx.x & 3;
    int e0 = g * 4;
    if (e0 >= E) return;
    int cnt = min(4, E - e0);
    int s[4], t[4];
#pragma unroll
    for (int q = 0; q < 4; q++) {
        int e = (q < cnt) ? e0 + q : e0;
        s[q] = src[e];
        t[q] = tgt[e];
    }
    uint4 Za[4], Zb[4];
#pragma unroll
    for (int q = 0; q < 4; q++) {
        Za[q] = *(const uint4*)(zh + (size_t)s[q] * 32 + fl * 8);
        Zb[q] = *(const uint4*)(zh + (size_t)t[q] * 32 + fl * 8);
    }
    float v[4];
#pragma unroll
    for (int q = 0; q < 4; q++) {
        float x = bfdot8(Za[q], Zb[q]);
        x += __shfl_xor(x, 1);
        x += __shfl_xor(x, 2);
        v[q] = x;
    }
    if (fl == 0) {
        if (cnt == 4) {
            *(float4*)(recon + e0) = make_float4(v[0], v[1], v[2], v[3]);
        } else {
            for (int q = 0; q < cnt; q++) recon[e0 + q] = v[q];
        }
    }
}

extern "C" void kernel_launch(void* const* d_in, const int* in_sizes, int n_in,
                              void* d_out, int out_size, void* d_ws, size_t ws_size,
                              hipStream_t stream) {
    const float* x = (const float*)d_in[0];
    const float* W1 = (const float*)d_in[1];
    const float* b1 = (const float*)d_in[2];
    const float* W2 = (const float*)d_in[3];
    const float* b2 = (const float*)d_in[4];
    const int* ei = (const int*)d_in[5];

    int N = in_sizes[0] / 128;
    int E = in_sizes[5] / 2;
    const int* src = ei;
    const int* tgt = ei + E;
    int NB = divup(N, BNODES);

    char* ws = (char*)d_ws;
    size_t off = 0;
    auto alloc = [&](size_t bytes) {
        size_t r = off;
        off += (bytes + 255) & ~(size_t)255;
        return r;
    };
    int* gcur = (int*)(ws + alloc(NBMAX * 4));
    unsigned* ebuf = (unsigned*)(ws + alloc((size_t)NB * CAP * 4));
    int* col = (int*)(ws + alloc((size_t)NB * CAP * 4));
    int* rowbeg = (int*)(ws + alloc((size_t)N * 4));
    int* rowend = (int*)(ws + alloc((size_t)N * 4));
    float* dinv = (float*)(ws + alloc((size_t)N * 4));
    __half* hs = (__half*)(ws + alloc((size_t)(N + 1) * 64 * 2));   // +pad row n
    __half* h2 = (__half*)(ws + alloc((size_t)N * 64 * 2));
    __half* zs = (__half*)(ws + alloc((size_t)(N + 1) * 32 * 2));   // +pad row n
    unsigned short* zh = (unsigned short*)(ws + alloc((size_t)N * 32 * 2));

    float* zout = (float*)d_out;
    float* recon = zout + (size_t)N * 32;

    k_init<<<1, 256, 0, stream>>>(gcur, (unsigned*)(hs + (size_t)N * 64),
                                  (unsigned*)(zs + (size_t)N * 32));
    k_part<<<divup(E, CH), 256, 0, stream>>>(src, tgt, gcur, ebuf, E, NB);
    k_bfill<<<NB, BNODES, 0, stream>>>(ebuf, gcur, rowbeg, rowend, col, dinv, N);

    k_mm1<<<divup(N, 64), 256, 0, stream>>>(x, W1, dinv, hs, N);
    k_conv1<<<divup(N, 8), 256, 0, stream>>>(hs, rowbeg, rowend, col, dinv, b1, h2, N);
    k_mm2<<<divup(N, 64), 256, 0, stream>>>(h2, W2, dinv, zs, N);
    k_conv2<<<divup(N, 8), 256, 0, stream>>>(zs, rowbeg, rowend, col, dinv, b2, zout, zh, N);
    k_decode<<<divup(E, 256), 256, 0, stream>>>(zh, src, tgt, recon, E);
}

// Round 10
// 228.168 us; speedup vs baseline: 2.5541x; 1.0246x over previous
//
#include <hip/hip_runtime.h>
#include <hip/hip_fp16.h>
#include <math.h>

// GAE: 2x GCNConv + edge dot decode.
// R1: bucketed CSR build, fp16 gather tables.
// R2: wide gathers (float4/lane).
// R3-R5: unrolled gathers, fixed-capacity buckets.
// R6: fp16 packed accumulation, zero-pad row, bf16 decode.
// R7: 1 node/wave 4x-peeled gathers.  R8: mm1/mm2 as MFMA.
// R9: 2 nodes/wave (32-lane halves) -> 258->234us.
// R10: 4 nodes/wave (16-lane quarters): wave count halves again at ~same
//      VGPR; deg 17-32 served from a second pre-staged col register (sl2,
//      issued up-front -> no dependent col reload); k_part int4 loads.

#define NBMAX 256    // max buckets (supports N <= 131072)
#define BSHIFT 9     // 512 nodes per bucket
#define BNODES 512
#define CH 4096      // edges per partition block
#define CAPSHIFT 14  // 16384 edge slots per bucket (mean 8192 at N=100k,E=1.6M)
#define CAP (1 << CAPSHIFT)

typedef _Float16 half8 __attribute__((ext_vector_type(8)));
typedef float floatx4 __attribute__((ext_vector_type(4)));

static inline int divup(int a, int b) { return (a + b - 1) / b; }

__device__ inline void acc8(__half2* a, float4 v) {
    const __half2* h = (const __half2*)&v;
    a[0] = __hadd2(a[0], h[0]);
    a[1] = __hadd2(a[1], h[1]);
    a[2] = __hadd2(a[2], h[2]);
    a[3] = __hadd2(a[3], h[3]);
}
__device__ inline unsigned short f2bf(float f) {
    unsigned u = __builtin_bit_cast(unsigned, f);
    u = (u + 0x7FFFu + ((u >> 16) & 1u)) >> 16;
    return (unsigned short)u;
}

// ---- init bucket cursors + zero pad rows ------------------------------------

__global__ void k_init(int* __restrict__ gcur, unsigned* __restrict__ hs_pad,
                       unsigned* __restrict__ zs_pad) {
    int t = threadIdx.x;
    if (t < NBMAX) gcur[t] = t << CAPSHIFT;
    if (t < 32) hs_pad[t] = 0;            // 128B zero row (64 fp16)
    else if (t < 48) zs_pad[t - 32] = 0;  // 64B zero row (32 fp16)
}

// ---- partition edges into fixed-capacity buckets (atomic append) ------------
// packed word: (local_tgt << 23) | src   (src < 2^17, local_tgt < 512)

__global__ __launch_bounds__(256) void k_part(const int* __restrict__ src,
                                              const int* __restrict__ tgt,
                                              int* __restrict__ gcur,
                                              unsigned* __restrict__ ebuf, int E, int NB) {
    __shared__ int h[NBMAX];
    __shared__ int base[NBMAX];
    int tid = threadIdx.x;
    int e0 = blockIdx.x * CH;
    for (int b = tid; b < NB; b += 256) h[b] = 0;
    __syncthreads();
    unsigned pk[16];
    int sv[16];
#pragma unroll
    for (int r = 0; r < 4; r++) {
        int e = e0 + (r * 256 + tid) * 4;
        if (e + 3 < E) {
            int4 t4 = *(const int4*)(tgt + e);
            int4 s4 = *(const int4*)(src + e);
            int tv[4] = {t4.x, t4.y, t4.z, t4.w};
            int sw[4] = {s4.x, s4.y, s4.z, s4.w};
#pragma unroll
            for (int j = 0; j < 4; j++) {
                int t = tv[j];
                int b = t >> BSHIFT;
                int l = atomicAdd(&h[b], 1);
                pk[r * 4 + j] = ((unsigned)b << 21) |
                                ((unsigned)(t & (BNODES - 1)) << 12) | (unsigned)l;
                sv[r * 4 + j] = sw[j];
            }
        } else {
#pragma unroll
            for (int j = 0; j < 4; j++) {
                int ee = e + j;
                if (ee < E) {
                    int t = tgt[ee];
                    int b = t >> BSHIFT;
                    int l = atomicAdd(&h[b], 1);
                    pk[r * 4 + j] = ((unsigned)b << 21) |
                                    ((unsigned)(t & (BNODES - 1)) << 12) | (unsigned)l;
                    sv[r * 4 + j] = src[ee];
                } else {
                    pk[r * 4 + j] = 0xFFFFFFFFu;
                }
            }
        }
    }
    __syncthreads();
    for (int b = tid; b < NB; b += 256) {
        int c = h[b];
        base[b] = c ? atomicAdd(&gcur[b], c) : 0;
    }
    __syncthreads();
#pragma unroll
    for (int i = 0; i < 16; i++) {
        if (pk[i] != 0xFFFFFFFFu) {
            int b = pk[i] >> 21;
            unsigned lt = (pk[i] >> 12) & (BNODES - 1);
            int l = pk[i] & 4095;
            ebuf[base[b] + l] = (lt << 23) | (unsigned)sv[i];
        }
    }
}

// ---- per-bucket CSR fill: LDS count/scan/cursor -----------------------------

__global__ __launch_bounds__(512) void k_bfill(const unsigned* __restrict__ ebuf,
                                               const int* __restrict__ gcur,
                                               int* __restrict__ rowbeg,
                                               int* __restrict__ rowend,
                                               int* __restrict__ col,
                                               float* __restrict__ dinv, int n) {
    __shared__ int s_cnt[BNODES];
    __shared__ int s_scan[BNODES];
    __shared__ int s_cur[BNODES];
    int b = blockIdx.x, tid = threadIdx.x;
    int nbase = b << BSHIFT;
    int ebase = b << CAPSHIFT;
    int eend = gcur[b];
    s_cnt[tid] = 0;
    __syncthreads();
    for (int e = ebase + tid; e < eend; e += BNODES) {
        atomicAdd(&s_cnt[ebuf[e] >> 23], 1);
    }
    __syncthreads();
    s_scan[tid] = s_cnt[tid];
    __syncthreads();
    for (int off = 1; off < BNODES; off <<= 1) {
        int t = (tid >= off) ? s_scan[tid - off] : 0;
        __syncthreads();
        s_scan[tid] += t;
        __syncthreads();
    }
    int excl = s_scan[tid] - s_cnt[tid];
    s_cur[tid] = excl;
    int node = nbase + tid;
    if (node < n) {
        rowbeg[node] = ebase + excl;
        rowend[node] = ebase + excl + s_cnt[tid];
        dinv[node] = rsqrtf((float)(s_cnt[tid] + 1));  // +1 self-loop
    }
    __syncthreads();
    for (int e = ebase + tid; e < eend; e += BNODES) {
        unsigned p = ebuf[e];
        int pos = atomicAdd(&s_cur[p >> 23], 1);
        col[ebase + pos] = (int)(p & 0x7FFFFFu);
    }
}

// ---- matmul 1 (MFMA): hs[n][j] = fp16((x[n] @ W1[:,j]) * dinv[n]) -----------
// 64 nodes x 64 cols per block; fp16 LDS tiles, pitch 136 (2-way bank = free).

__global__ __launch_bounds__(256) void k_mm1(const float* __restrict__ x,
                                             const float* __restrict__ W1,
                                             const float* __restrict__ dinv,
                                             __half* __restrict__ hs, int n) {
    __shared__ _Float16 xh[64 * 136];  // [node][k]
    __shared__ _Float16 Wt[64 * 136];  // [col][k] (transposed)
    int tid = threadIdx.x;
    int nbase = blockIdx.x * 64;
#pragma unroll
    for (int i = 0; i < 8; i++) {
        int f = tid + i * 256;  // 0..2047
        int r = f >> 5, c4 = f & 31;
        int node = nbase + r;
        float4 v = make_float4(0.f, 0.f, 0.f, 0.f);
        if (node < n) v = *(const float4*)(x + (size_t)node * 128 + c4 * 4);
        union { uint2 u; __half2 h[2]; } pk;
        pk.h[0] = __floats2half2_rn(v.x, v.y);
        pk.h[1] = __floats2half2_rn(v.z, v.w);
        *(uint2*)&xh[r * 136 + c4 * 4] = pk.u;
    }
#pragma unroll
    for (int i = 0; i < 16; i++) {
        int f = tid + i * 256;          // 0..4095
        int c = f & 63, kp = f >> 6;    // kp 0..63 (pairs of k)
        float a = W1[(size_t)(2 * kp) * 64 + c];
        float b = W1[(size_t)(2 * kp + 1) * 64 + c];
        *(__half2*)&Wt[c * 136 + 2 * kp] = __floats2half2_rn(a, b);
    }
    __syncthreads();
    int w = tid >> 6, lane = tid & 63;
    int quad = lane >> 4, m = lane & 15;
    floatx4 acc[4] = {{0.f, 0.f, 0.f, 0.f}, {0.f, 0.f, 0.f, 0.f},
                      {0.f, 0.f, 0.f, 0.f}, {0.f, 0.f, 0.f, 0.f}};
#pragma unroll
    for (int kt = 0; kt < 4; kt++) {
        half8 a = *(const half8*)&xh[(w * 16 + m) * 136 + kt * 32 + quad * 8];
#pragma unroll
        for (int ct = 0; ct < 4; ct++) {
            half8 b = *(const half8*)&Wt[(ct * 16 + m) * 136 + kt * 32 + quad * 8];
            acc[ct] = __builtin_amdgcn_mfma_f32_16x16x32_f16(a, b, acc[ct], 0, 0, 0);
        }
    }
#pragma unroll
    for (int reg = 0; reg < 4; reg++) {
        int node = nbase + w * 16 + quad * 4 + reg;
        if (node < n) {
            float d = dinv[node];
#pragma unroll
            for (int ct = 0; ct < 4; ct++) {
                hs[(size_t)node * 64 + ct * 16 + m] = __float2half(acc[ct][reg] * d);
            }
        }
    }
}

// ---- conv1: 4 nodes/wave (16-lane quarters), 8 feat lanes x 2 edge slots ----
// hs has a zeroed pad row at index n; invalid slots load it unconditionally.
// col slots 0-15 in sl, 16-31 pre-staged in sl2 (independent load).

__global__ __launch_bounds__(256) void k_conv1(const __half* __restrict__ hs,
                                               const int* __restrict__ rowbeg,
                                               const int* __restrict__ rowend,
                                               const int* __restrict__ col,
                                               const float* __restrict__ dinv,
                                               const float* __restrict__ b1,
                                               __half* __restrict__ h2, int n) {
    int gw = (blockIdx.x * 256 + threadIdx.x) >> 6;
    int lane = threadIdx.x & 63;
    int q = lane >> 4, ln = lane & 15;
    int w = gw * 4 + q;
    if (w >= n) return;  // whole quarter exits together
    int qb = q << 4;
    int el = ln >> 3, fl = ln & 7;  // 2 edge slots x 8 feat lanes
    int beg = rowbeg[w], end = rowend[w];
    int deg = end - beg;
    int m = min(16, deg);
    int m2 = min(16, deg - 16);  // may be <=0
    int sl = (ln < m) ? col[beg + ln] : 0;
    int sl2 = (ln < m2) ? col[beg + 16 + ln] : 0;
    __half2 a2[4];
#pragma unroll
    for (int j = 0; j < 4; j++) a2[j] = __half2half2(__float2half(0.f));
    // self + rounds 0..3 (edges 0..7)
    int rs = (el == 0) ? w : n;
    float4 S = *(const float4*)(hs + (size_t)rs * 64 + fl * 8);
    float4 L[4];
#pragma unroll
    for (int r = 0; r < 4; r++) {
        int idx = 2 * r + el;
        int s = __shfl(sl, qb + idx);
        int a = (idx < m) ? s : n;
        L[r] = *(const float4*)(hs + (size_t)a * 64 + fl * 8);
    }
    acc8(a2, S);
#pragma unroll
    for (int r = 0; r < 4; r++) acc8(a2, L[r]);
    // rounds 4..7 (edges 8..15)
#pragma unroll
    for (int r = 0; r < 4; r++) {
        int idx = 8 + 2 * r + el;
        int s = __shfl(sl, qb + idx);
        int a = (idx < m) ? s : n;
        L[r] = *(const float4*)(hs + (size_t)a * 64 + fl * 8);
    }
#pragma unroll
    for (int r = 0; r < 4; r++) acc8(a2, L[r]);
    if (deg > 16) {  // edges 16..31 from sl2 (~43% of nodes)
#pragma unroll
        for (int r = 0; r < 4; r++) {
            int idx = 2 * r + el;
            int s = __shfl(sl2, qb + idx);
            int a = (idx < m2) ? s : n;
            L[r] = *(const float4*)(hs + (size_t)a * 64 + fl * 8);
        }
#pragma unroll
        for (int r = 0; r < 4; r++) acc8(a2, L[r]);
#pragma unroll
        for (int r = 0; r < 4; r++) {
            int idx = 8 + 2 * r + el;
            int s = __shfl(sl2, qb + idx);
            int a = (idx < m2) ? s : n;
            L[r] = *(const float4*)(hs + (size_t)a * 64 + fl * 8);
        }
#pragma unroll
        for (int r = 0; r < 4; r++) acc8(a2, L[r]);
    }
    if (deg > 32) {  // rare (~0.01%)
        for (int b0 = 32; b0 < deg; b0 += 16) {
            int mc = min(16, deg - b0);
            int sl3 = (ln < mc) ? col[beg + b0 + ln] : 0;
            for (int r = 0; r < 8; r++) {
                int idx = 2 * r + el;
                int s = __shfl(sl3, qb + idx);
                int a = (idx < mc) ? s : n;
                float4 v = *(const float4*)(hs + (size_t)a * 64 + fl * 8);
                acc8(a2, v);
            }
        }
    }
    // fp32 reduction over the 2 el groups (d=8, intra-quarter)
    float r[8];
#pragma unroll
    for (int j = 0; j < 4; j++) {
        float2 f = __half22float2(a2[j]);
        r[2 * j] = f.x;
        r[2 * j + 1] = f.y;
    }
#pragma unroll
    for (int j = 0; j < 8; j++) r[j] += __shfl_xor(r[j], 8);

    if (el == 0) {
        float d = dinv[w];
        float4 bb0 = *(const float4*)(b1 + fl * 8);
        float4 bb1 = *(const float4*)(b1 + fl * 8 + 4);
        union { float4 f; __half2 h[4]; } u;
        u.h[0] = __floats2half2_rn(fmaxf(r[0] * d + bb0.x, 0.f),
                                   fmaxf(r[1] * d + bb0.y, 0.f));
        u.h[1] = __floats2half2_rn(fmaxf(r[2] * d + bb0.z, 0.f),
                                   fmaxf(r[3] * d + bb0.w, 0.f));
        u.h[2] = __floats2half2_rn(fmaxf(r[4] * d + bb1.x, 0.f),
                                   fmaxf(r[5] * d + bb1.y, 0.f));
        u.h[3] = __floats2half2_rn(fmaxf(r[6] * d + bb1.z, 0.f),
                                   fmaxf(r[7] * d + bb1.w, 0.f));
        *(float4*)(h2 + (size_t)w * 64 + fl * 8) = u.f;
    }
}

// ---- matmul 2 (MFMA): zs[n][c] = fp16((h2[n] @ W2[:,c]) * dinv[n]) ----------

__global__ __launch_bounds__(256) void k_mm2(const __half* __restrict__ h2,
                                             const float* __restrict__ W2,
                                             const float* __restrict__ dinv,
                                             __half* __restrict__ zs, int n) {
    __shared__ _Float16 Wt[32 * 72];  // [col][k] (transposed)
    int tid = threadIdx.x;
    int nbase = blockIdx.x * 64;
#pragma unroll
    for (int i = 0; i < 4; i++) {
        int f = tid + i * 256;          // 0..1023
        int c = f & 31, kp = f >> 5;    // kp 0..31
        float a = W2[(size_t)(2 * kp) * 32 + c];
        float b = W2[(size_t)(2 * kp + 1) * 32 + c];
        *(__half2*)&Wt[c * 72 + 2 * kp] = __floats2half2_rn(a, b);
    }
    __syncthreads();
    int w = tid >> 6, lane = tid & 63;
    int quad = lane >> 4, m = lane & 15;
    int arow = nbase + w * 16 + m;
    const __half* abase = h2 + (size_t)min(arow, n - 1) * 64;  // clamped rows
    floatx4 acc[2] = {{0.f, 0.f, 0.f, 0.f}, {0.f, 0.f, 0.f, 0.f}};
#pragma unroll
    for (int kt = 0; kt < 2; kt++) {
        half8 a = *(const half8*)(abase + kt * 32 + quad * 8);
#pragma unroll
        for (int ct = 0; ct < 2; ct++) {
            half8 b = *(const half8*)&Wt[(ct * 16 + m) * 72 + kt * 32 + quad * 8];
            acc[ct] = __builtin_amdgcn_mfma_f32_16x16x32_f16(a, b, acc[ct], 0, 0, 0);
        }
    }
#pragma unroll
    for (int reg = 0; reg < 4; reg++) {
        int node = nbase + w * 16 + quad * 4 + reg;
        if (node < n) {
            float d = dinv[node];
#pragma unroll
            for (int ct = 0; ct < 2; ct++) {
                zs[(size_t)node * 32 + ct * 16 + m] = __float2half(acc[ct][reg] * d);
            }
        }
    }
}

// ---- conv2: 4 nodes/wave (16-lane quarters), 4 feat lanes x 4 edge slots ----
// zs has a zeroed pad row at index n. bf16 zh epilogue for decode.

__global__ __launch_bounds__(256) void k_conv2(const __half* __restrict__ zs,
                                               const int* __restrict__ rowbeg,
                                               const int* __restrict__ rowend,
                                               const int* __restrict__ col,
                                               const float* __restrict__ dinv,
                                               const float* __restrict__ b2,
                                               float* __restrict__ zout,
                                               unsigned short* __restrict__ zh, int n) {
    int gw = (blockIdx.x * 256 + threadIdx.x) >> 6;
    int lane = threadIdx.x & 63;
    int q = lane >> 4, ln = lane & 15;
    int w = gw * 4 + q;
    if (w >= n) return;
    int qb = q << 4;
    int el = ln >> 2, fl = ln & 3;  // 4 edge slots x 4 feat lanes
    int beg = rowbeg[w], end = rowend[w];
    int deg = end - beg;
    int m = min(16, deg);
    int m2 = min(16, deg - 16);
    int sl = (ln < m) ? col[beg + ln] : 0;
    int sl2 = (ln < m2) ? col[beg + 16 + ln] : 0;
    __half2 a2[4];
#pragma unroll
    for (int j = 0; j < 4; j++) a2[j] = __half2half2(__float2half(0.f));
    int rs = (el == 0) ? w : n;
    float4 S = *(const float4*)(zs + (size_t)rs * 32 + fl * 8);
    float4 L[4];
#pragma unroll
    for (int r = 0; r < 4; r++) {  // edges 0..15
        int idx = 4 * r + el;
        int s = __shfl(sl, qb + idx);
        int a = (idx < m) ? s : n;
        L[r] = *(const float4*)(zs + (size_t)a * 32 + fl * 8);
    }
    acc8(a2, S);
#pragma unroll
    for (int r = 0; r < 4; r++) acc8(a2, L[r]);
    if (deg > 16) {  // edges 16..31
#pragma unroll
        for (int r = 0; r < 4; r++) {
            int idx = 4 * r + el;
            int s = __shfl(sl2, qb + idx);
            int a = (idx < m2) ? s : n;
            L[r] = *(const float4*)(zs + (size_t)a * 32 + fl * 8);
        }
#pragma unroll
        for (int r = 0; r < 4; r++) acc8(a2, L[r]);
    }
    if (deg > 32) {  // rare
        for (int b0 = 32; b0 < deg; b0 += 16) {
            int mc = min(16, deg - b0);
            int sl3 = (ln < mc) ? col[beg + b0 + ln] : 0;
            for (int r = 0; r < 4; r++) {
                int idx = 4 * r + el;
                int s = __shfl(sl3, qb + idx);
                int a = (idx < mc) ? s : n;
                float4 v = *(const float4*)(zs + (size_t)a * 32 + fl * 8);
                acc8(a2, v);
            }
        }
    }
    // fp32 reduction over the 4 el groups (d=4,8 intra-quarter)
    float r[8];
#pragma unroll
    for (int j = 0; j < 4; j++) {
        float2 f = __half22float2(a2[j]);
        r[2 * j] = f.x;
        r[2 * j + 1] = f.y;
    }
#pragma unroll
    for (int d = 4; d < 16; d <<= 1)
#pragma unroll
        for (int j = 0; j < 8; j++) r[j] += __shfl_xor(r[j], d);

    if (el == 0) {  // lanes fl=0..3 of each quarter, 8 feats each
        float d = dinv[w];
        float4 bb0 = *(const float4*)(b2 + fl * 8);
        float4 bb1 = *(const float4*)(b2 + fl * 8 + 4);
        float o0 = r[0] * d + bb0.x, o1 = r[1] * d + bb0.y;
        float o2 = r[2] * d + bb0.z, o3 = r[3] * d + bb0.w;
        float o4 = r[4] * d + bb1.x, o5 = r[5] * d + bb1.y;
        float o6 = r[6] * d + bb1.z, o7 = r[7] * d + bb1.w;
        *(float4*)(zout + (size_t)w * 32 + fl * 8) = make_float4(o0, o1, o2, o3);
        *(float4*)(zout + (size_t)w * 32 + fl * 8 + 4) = make_float4(o4, o5, o6, o7);
        uint4 p;
        p.x = (unsigned)f2bf(o0) | ((unsigned)f2bf(o1) << 16);
        p.y = (unsigned)f2bf(o2) | ((unsigned)f2bf(o3) << 16);
        p.z = (unsigned)f2bf(o4) | ((unsigned)f2bf(o5) << 16);
        p.w = (unsigned)f2bf(o6) | ((unsigned)f2bf(o7) << 16);
        *(uint4*)(zh + (size_t)w * 32 + fl * 8) = p;
    }
}

// ---- decode: bf16 rows (64B), 4 lanes/edge, 4 edges per group ---------------

__device__ inline float bfdot8(uint4 a, uint4 b) {
    const unsigned* pa = (const unsigned*)&a;
    const unsigned* pb = (const unsigned*)&b;
    float v = 0.f;
#pragma unroll
    for (int w = 0; w < 4; w++) {
        float alo = __builtin_bit_cast(float, pa[w] << 16);
        float ahi = __builtin_bit_cast(float, pa[w] & 0xFFFF0000u);
        float blo = __builtin_bit_cast(float, pb[w] << 16);
        float bhi = __builtin_bit_cast(float, pb[w] & 0xFFFF0000u);
        v += alo * blo + ahi * bhi;
    }
    return v;
}

__global__ __launch_bounds__(256) void k_decode(const unsigned short* __restrict__ zh,
                                                const int* __restrict__ src,
                                                const int* __restrict__ tgt,
                                                float* __restrict__ recon, int E) {
    int g = (blockIdx.x * 256 + threadIdx.x) >> 2;
    int fl = threadIdx.x & 3;
    int e0 = g * 4;
    if (e0 >= E) return;
    int cnt = min(4, E - e0);
    int s[4], t[4];
#pragma unroll
    for (int q = 0; q < 4; q++) {
        int e = (q < cnt) ? e0 + q : e0;
        s[q] = src[e];
        t[q] = tgt[e];
    }
    uint4 Za[4], Zb[4];
#pragma unroll
    for (int q = 0; q < 4; q++) {
        Za[q] = *(const uint4*)(zh + (size_t)s[q] * 32 + fl * 8);
        Zb[q] = *(const uint4*)(zh + (size_t)t[q] * 32 + fl * 8);
    }
    float v[4];
#pragma unroll
    for (int q = 0; q < 4; q++) {
        float x = bfdot8(Za[q], Zb[q]);
        x += __shfl_xor(x, 1);
        x += __shfl_xor(x, 2);
        v[q] = x;
    }
    if (fl == 0) {
        if (cnt == 4) {
            *(float4*)(recon + e0) = make_float4(v[0], v[1], v[2], v[3]);
        } else {
            for (int q = 0; q < cnt; q++) recon[e0 + q] = v[q];
        }
    }
}

extern "C" void kernel_launch(void* const* d_in, const int* in_sizes, int n_in,
                              void* d_out, int out_size, void* d_ws, size_t ws_size,
                              hipStream_t stream) {
    const float* x = (const float*)d_in[0];
    const float* W1 = (const float*)d_in[1];
    const float* b1 = (const float*)d_in[2];
    const float* W2 = (const float*)d_in[3];
    const float* b2 = (const float*)d_in[4];
    const int* ei = (const int*)d_in[5];

    int N = in_sizes[0] / 128;
    int E = in_sizes[5] / 2;
    const int* src = ei;
    const int* tgt = ei + E;
    int NB = divup(N, BNODES);

    char* ws = (char*)d_ws;
    size_t off = 0;
    auto alloc = [&](size_t bytes) {
        size_t r = off;
        off += (bytes + 255) & ~(size_t)255;
        return r;
    };
    int* gcur = (int*)(ws + alloc(NBMAX * 4));
    unsigned* ebuf = (unsigned*)(ws + alloc((size_t)NB * CAP * 4));
    int* col = (int*)(ws + alloc((size_t)NB * CAP * 4));
    int* rowbeg = (int*)(ws + alloc((size_t)N * 4));
    int* rowend = (int*)(ws + alloc((size_t)N * 4));
    float* dinv = (float*)(ws + alloc((size_t)N * 4));
    __half* hs = (__half*)(ws + alloc((size_t)(N + 1) * 64 * 2));   // +pad row n
    __half* h2 = (__half*)(ws + alloc((size_t)N * 64 * 2));
    __half* zs = (__half*)(ws + alloc((size_t)(N + 1) * 32 * 2));   // +pad row n
    unsigned short* zh = (unsigned short*)(ws + alloc((size_t)N * 32 * 2));

    float* zout = (float*)d_out;
    float* recon = zout + (size_t)N * 32;

    k_init<<<1, 256, 0, stream>>>(gcur, (unsigned*)(hs + (size_t)N * 64),
                                  (unsigned*)(zs + (size_t)N * 32));
    k_part<<<divup(E, CH), 256, 0, stream>>>(src, tgt, gcur, ebuf, E, NB);
    k_bfill<<<NB, BNODES, 0, stream>>>(ebuf, gcur, rowbeg, rowend, col, dinv, N);

    k_mm1<<<divup(N, 64), 256, 0, stream>>>(x, W1, dinv, hs, N);
    k_conv1<<<divup(N, 16), 256, 0, stream>>>(hs, rowbeg, rowend, col, dinv, b1, h2, N);
    k_mm2<<<divup(N, 64), 256, 0, stream>>>(h2, W2, dinv, zs, N);
    k_conv2<<<divup(N, 16), 256, 0, stream>>>(zs, rowbeg, rowend, col, dinv, b2, zout, zh, N);
    k_decode<<<divup(E, 256), 256, 0, stream>>>(zh, src, tgt, recon, E);
}